// Round 9
// baseline (574.729 us; speedup 1.0000x reference)
//
#include <hip/hip_runtime.h>
#include <hip/hip_bf16.h>

// ---------------------------------------------------------------------------
// LeViT subsample attention (round 8).
//   = round 7 pipeline, plus:
//   (a) attn_mfma: V register prefetch one k-tile ahead, launch_bounds(512,4)
//   (b) gemm_mfma EPI=2: C-tile restaged via LDS -> coalesced 256B row stores
// ---------------------------------------------------------------------------

static constexpr int M1 = 25088, N1 = 3840, Kc = 384;
static constexpr int M2 = 6272, Dq = 768, OUTD = 512;
static constexpr int CH1 = 14, CH2 = 7;

static constexpr size_t OFF_K    = 0;
static constexpr size_t OFF_XBT  = 0;
static constexpr size_t OFF_XQT  = 19267584;
static constexpr size_t OFF_T1   = 24084480;
static constexpr size_t OFF_T2   = 29982720;
static constexpr size_t OFF_SXB1 = 31162368;
static constexpr size_t OFF_SXB2 = 31457280;
static constexpr size_t OFF_VT   = 38535168;
static constexpr size_t OFF_QN   = 192675840;
static constexpr size_t OFF_O    = 202309632;
static constexpr size_t OFF_XB   = OFF_O;
static constexpr size_t OFF_PS1  = 240844800;
static constexpr size_t OFF_WQKVT= 240844800;
static constexpr size_t OFF_WQT  = 243793920;
static constexpr size_t OFF_WOUTT= 244383744;
static constexpr size_t OFF_PS2  = 249123840;
static constexpr size_t OFF_SX1  = 253263360;
static constexpr size_t OFF_CS1  = 253853184;
static constexpr size_t OFF_SX2  = 253854720;
static constexpr size_t OFF_CS2  = 254444544;
static constexpr size_t OFF_A1   = 254446080;
static constexpr size_t OFF_B1   = 254461440;
static constexpr size_t OFF_A2   = 254476800;
static constexpr size_t OFF_B2   = 254479872;
static constexpr size_t WS_TOTAL = 254482944;

typedef __attribute__((ext_vector_type(8))) short bf16x8;
typedef __attribute__((ext_vector_type(4))) float f32x4;

static __device__ __forceinline__ f32x4 mfma16(bf16x8 a, bf16x8 b, f32x4 c) {
  return __builtin_amdgcn_mfma_f32_16x16x32_bf16(a, b, c, 0, 0, 0);
}

__device__ __forceinline__ void gload_lds16(const void* g, void* l) {
  __builtin_amdgcn_global_load_lds(
      (const __attribute__((address_space(1))) unsigned int*)g,
      (__attribute__((address_space(3))) unsigned int*)l, 16, 0, 0);
}

__device__ __forceinline__ float hswish(float x) {
  float t = fminf(fmaxf(x + 3.0f, 0.0f), 6.0f);
  return x * t * (1.0f / 6.0f);
}

// --------------------------- prep kernels ----------------------------------
__global__ __launch_bounds__(256) void convert_bf16(
    const float* __restrict__ in, unsigned short* __restrict__ out, long n8) {
  long i = (long)blockIdx.x * 256 + threadIdx.x;
  if (i >= n8) return;
  float4 a = ((const float4*)in)[i * 2];
  float4 b = ((const float4*)in)[i * 2 + 1];
  union { uint4 u; __hip_bfloat16 h[8]; } pk;
  pk.h[0] = __float2bfloat16(a.x); pk.h[1] = __float2bfloat16(a.y);
  pk.h[2] = __float2bfloat16(a.z); pk.h[3] = __float2bfloat16(a.w);
  pk.h[4] = __float2bfloat16(b.x); pk.h[5] = __float2bfloat16(b.y);
  pk.h[6] = __float2bfloat16(b.z); pk.h[7] = __float2bfloat16(b.w);
  ((uint4*)out)[i] = pk.u;
}

__global__ __launch_bounds__(256) void transpose_bf16(
    const float* __restrict__ in, unsigned short* __restrict__ out, int R, int C) {
  __shared__ float t[32][33];
  const int c0 = blockIdx.x * 32, r0 = blockIdx.y * 32;
  const int x = threadIdx.x & 31, y = threadIdx.x >> 5;
  #pragma unroll
  for (int i = y; i < 32; i += 8) t[i][x] = in[(long)(r0 + i) * C + c0 + x];
  __syncthreads();
  #pragma unroll
  for (int i = y; i < 32; i += 8) {
    __hip_bfloat16 v = __float2bfloat16(t[x][i]);
    out[(long)(c0 + i) * R + r0 + x] = *(unsigned short*)&v;
  }
}

__global__ __launch_bounds__(256) void transpose_gather_bf16(
    const float* __restrict__ in, unsigned short* __restrict__ out) {
  __shared__ float t[32][33];
  const int c0 = blockIdx.x * 32, r0 = blockIdx.y * 32;
  const int x = threadIdx.x & 31, y = threadIdx.x >> 5;
  #pragma unroll
  for (int i = y; i < 32; i += 8) {
    int m2 = r0 + i;
    int bb = m2 / 196, tt = m2 - bb * 196;
    int h2 = tt / 14, w2 = tt - h2 * 14;
    long grow = (long)(bb * 784 + h2 * 56 + w2 * 2);
    t[i][x] = in[grow * 384 + c0 + x];
  }
  __syncthreads();
  #pragma unroll
  for (int i = y; i < 32; i += 8) {
    __hip_bfloat16 v = __float2bfloat16(t[x][i]);
    out[(long)(c0 + i) * 6272 + r0 + x] = *(unsigned short*)&v;
  }
}

__global__ __launch_bounds__(256) void rowsum_bf16(
    const unsigned short* __restrict__ src, float* __restrict__ dst, int ncols) {
  const long base = (long)blockIdx.x * ncols;
  float s = 0.f;
  for (int c = threadIdx.x * 8; c < ncols; c += 2048) {
    bf16x8 v = *(const bf16x8*)(src + base + c);
    #pragma unroll
    for (int j = 0; j < 8; ++j)
      s += __uint_as_float(((unsigned)(unsigned short)v[j]) << 16);
  }
  __shared__ float red[256];
  red[threadIdx.x] = s;
  __syncthreads();
  for (int st = 128; st > 0; st >>= 1) {
    if (threadIdx.x < st) red[threadIdx.x] += red[threadIdx.x + st];
    __syncthreads();
  }
  if (threadIdx.x == 0) dst[blockIdx.x] = red[0];
}

__global__ __launch_bounds__(256) void reduce_chunks(
    const float* __restrict__ src, float* __restrict__ dst, int nelem, int nchunks) {
  int i = blockIdx.x * 256 + threadIdx.x;
  if (i >= nelem) return;
  float s = 0.f;
  for (int c = 0; c < nchunks; ++c) s += src[(long)c * nelem + i];
  dst[i] = s;
}

// --------------------------- BN finalize -----------------------------------
__global__ __launch_bounds__(256) void bnfinal(
    const float* __restrict__ W, const float* __restrict__ T, const float* __restrict__ cs,
    const float* __restrict__ scale, float* __restrict__ a, float* __restrict__ b,
    int N, float invM) {
  const int j = blockIdx.x * 64 + (threadIdx.x & 63);
  const int rq = threadIdx.x >> 6;
  float yy = 0.f, mu = 0.f;
  for (int k = rq * 96; k < rq * 96 + 96; ++k) {
    float w = W[(long)k * N + j];
    yy += w * T[(long)k * N + j];
    mu += cs[k] * w;
  }
  __shared__ float r1[256], r2[256];
  r1[threadIdx.x] = yy; r2[threadIdx.x] = mu;
  __syncthreads();
  if (threadIdx.x < 64) {
    int t = threadIdx.x;
    yy = r1[t] + r1[t + 64] + r1[t + 128] + r1[t + 192];
    mu = r2[t] + r2[t + 64] + r2[t + 128] + r2[t + 192];
    float mean = mu * invM;
    float var = yy * invM - mean * mean;
    float ai = rsqrtf(var + 1e-5f) * scale[j];
    a[j] = ai;
    b[j] = -mean * ai;
  }
}

// ---------------------------------------------------------------------------
// split-K MFMA X @ X^T (unchanged)
// ---------------------------------------------------------------------------
__global__ __launch_bounds__(256) void sx_mfma(
    const unsigned short* __restrict__ X, float* __restrict__ Cpart,
    int Kfull, int Kchunk) {
  __shared__ __align__(16) char As[16384];
  __shared__ __align__(16) char Bs[16384];
  const int tid = threadIdx.x;
  const int lane = tid & 63;
  const int wv = tid >> 6;
  const int wm = (wv >> 1) * 64, wn = (wv & 1) * 64;
  const int m0 = blockIdx.y * 128, n0 = blockIdx.x * 128;
  const int cl = lane & 15, kg = lane >> 4;
  const int srow = tid >> 3;
  const int swz = ((tid & 7) * 16) ^ ((srow & 7) << 4);
  const int ldsb = wv * 1024;
  const long zbase = (long)blockIdx.z * Kchunk;

  long arow[4], brow[4];
  #pragma unroll
  for (int is = 0; is < 4; ++is) {
    arow[is] = (long)(m0 + is * 32 + srow) * Kfull + zbase;
    brow[is] = (long)(n0 + is * 32 + srow) * Kfull + zbase;
  }

  f32x4 acc[4][4];
  const f32x4 zf = {0.f, 0.f, 0.f, 0.f};
  #pragma unroll
  for (int i = 0; i < 4; ++i)
    #pragma unroll
    for (int j = 0; j < 4; ++j) acc[i][j] = zf;

  for (int k0 = 0; k0 < Kchunk; k0 += 64) {
    #pragma unroll
    for (int is = 0; is < 4; ++is) {
      gload_lds16((const char*)X + (arow[is] + k0) * 2 + swz, As + is * 4096 + ldsb);
      gload_lds16((const char*)X + (brow[is] + k0) * 2 + swz, Bs + is * 4096 + ldsb);
    }
    __syncthreads();
    bf16x8 afr[4][2], bfr[4][2];
    #pragma unroll
    for (int t = 0; t < 4; ++t) {
      const int ar = wm + t * 16 + cl;
      const int br = wn + t * 16 + cl;
      const int sa = (ar & 7) << 4, sb = (br & 7) << 4;
      afr[t][0] = *(const bf16x8*)(As + ar * 128 + ((kg * 16) ^ sa));
      afr[t][1] = *(const bf16x8*)(As + ar * 128 + ((64 + kg * 16) ^ sa));
      bfr[t][0] = *(const bf16x8*)(Bs + br * 128 + ((kg * 16) ^ sb));
      bfr[t][1] = *(const bf16x8*)(Bs + br * 128 + ((64 + kg * 16) ^ sb));
    }
    #pragma unroll
    for (int mt = 0; mt < 4; ++mt)
      #pragma unroll
      for (int nt = 0; nt < 4; ++nt) {
        acc[mt][nt] = mfma16(bfr[nt][0], afr[mt][0], acc[mt][nt]);
        acc[mt][nt] = mfma16(bfr[nt][1], afr[mt][1], acc[mt][nt]);
      }
    __syncthreads();
  }

  float* Cp = Cpart + (long)blockIdx.z * 384 * 384;
  #pragma unroll
  for (int mt = 0; mt < 4; ++mt) {
    const int gm = m0 + wm + mt * 16 + cl;
    #pragma unroll
    for (int nt = 0; nt < 4; ++nt) {
      const int gn = n0 + wn + nt * 16 + kg * 4;
      *(float4*)(Cp + (long)gm * 384 + gn) =
          make_float4(acc[mt][nt][0], acc[mt][nt][1], acc[mt][nt][2], acc[mt][nt][3]);
    }
  }
}

// ---------------------------------------------------------------------------
// bf16 MFMA GEMM: C = A[M,K] @ Bt[N,K]^T.
// EPI: 0 f32 row store; 1 BN->bf16 row store; 2 BN->bf16 transposed store
//      into Vt[b][h][dv][784] via LDS restage (coalesced 256B row writes).
// ---------------------------------------------------------------------------
template<int AMODE, int EPI>
__global__ __launch_bounds__(256) void gemm_mfma(
    const unsigned short* __restrict__ A, const unsigned short* __restrict__ Bt,
    void* __restrict__ Cout, const float* __restrict__ ea, const float* __restrict__ eb,
    int N, int K) {
  constexpr int SMEM_BYTES = (EPI == 2) ? 34816 : 32768;  // Cs[128] rows * 272B
  __shared__ __align__(16) char smem[SMEM_BYTES];
  char* As = smem;
  char* Bs = smem + 16384;
  const int tid = threadIdx.x;
  const int lane = tid & 63;
  const int wv = tid >> 6;
  const int wm = (wv >> 1) * 64, wn = (wv & 1) * 64;
  const int m0 = blockIdx.y * 128, n0 = blockIdx.x * 128;
  const int cl = lane & 15, kg = lane >> 4;

  const int srow = tid >> 3;
  const int swz = ((tid & 7) * 16) ^ ((srow & 7) << 4);
  const int ldsb = wv * 1024;

  long arow[4], brow[4];
  #pragma unroll
  for (int is = 0; is < 4; ++is) {
    int gm = m0 + is * 32 + srow;
    long grow;
    if constexpr (AMODE == 1) {
      int bb = gm / 196, t = gm - bb * 196;
      int h2 = t / 14, w2 = t - h2 * 14;
      grow = (long)(bb * 784 + h2 * 56 + w2 * 2);
    } else {
      grow = gm;
    }
    arow[is] = grow * (long)K;
    brow[is] = (long)(n0 + is * 32 + srow) * (long)K;
  }

  f32x4 acc[4][4];
  const f32x4 zf = {0.f, 0.f, 0.f, 0.f};
  #pragma unroll
  for (int i = 0; i < 4; ++i)
    #pragma unroll
    for (int j = 0; j < 4; ++j) acc[i][j] = zf;

  for (int k0 = 0; k0 < K; k0 += 64) {
    #pragma unroll
    for (int is = 0; is < 4; ++is) {
      gload_lds16((const char*)A  + (arow[is] + k0) * 2 + swz, As + is * 4096 + ldsb);
      gload_lds16((const char*)Bt + (brow[is] + k0) * 2 + swz, Bs + is * 4096 + ldsb);
    }
    __syncthreads();
    bf16x8 afr[4][2], bfr[4][2];
    #pragma unroll
    for (int t = 0; t < 4; ++t) {
      const int ar = wm + t * 16 + cl;
      const int br = wn + t * 16 + cl;
      const int sa = (ar & 7) << 4, sb = (br & 7) << 4;
      afr[t][0] = *(const bf16x8*)(As + ar * 128 + ((kg * 16) ^ sa));
      afr[t][1] = *(const bf16x8*)(As + ar * 128 + ((64 + kg * 16) ^ sa));
      bfr[t][0] = *(const bf16x8*)(Bs + br * 128 + ((kg * 16) ^ sb));
      bfr[t][1] = *(const bf16x8*)(Bs + br * 128 + ((64 + kg * 16) ^ sb));
    }
    #pragma unroll
    for (int mt = 0; mt < 4; ++mt)
      #pragma unroll
      for (int nt = 0; nt < 4; ++nt) {
        if constexpr (EPI == 2) {
          acc[mt][nt] = mfma16(afr[mt][0], bfr[nt][0], acc[mt][nt]);
          acc[mt][nt] = mfma16(afr[mt][1], bfr[nt][1], acc[mt][nt]);
        } else {
          acc[mt][nt] = mfma16(bfr[nt][0], afr[mt][0], acc[mt][nt]);
          acc[mt][nt] = mfma16(bfr[nt][1], afr[mt][1], acc[mt][nt]);
        }
      }
    __syncthreads();
  }

  if constexpr (EPI == 2) {
    // stage BN'd bf16 C-tile into Cs[dv 128][k 128] (row stride 272B), then
    // write coalesced: 16 lanes = one 256B dv-row segment.
    char* Cs = smem;
    #pragma unroll
    for (int mt = 0; mt < 4; ++mt) {
      const int kl = wm + mt * 16 + kg * 4;
      #pragma unroll
      for (int nt = 0; nt < 4; ++nt) {
        const int dvl = wn + nt * 16 + cl;
        const int gn = n0 + dvl;
        const float av = ea[gn], bv = eb[gn];
        union { ushort4 u; __hip_bfloat16 h[4]; } pk;
        pk.h[0] = __float2bfloat16(acc[mt][nt][0] * av + bv);
        pk.h[1] = __float2bfloat16(acc[mt][nt][1] * av + bv);
        pk.h[2] = __float2bfloat16(acc[mt][nt][2] * av + bv);
        pk.h[3] = __float2bfloat16(acc[mt][nt][3] * av + bv);
        *(ushort4*)(Cs + dvl * 272 + kl * 2) = pk.u;
      }
    }
    __syncthreads();
    const int hh = n0 >> 8;
    #pragma unroll
    for (int l = 0; l < 8; ++l) {
      const int row = l * 16 + (tid >> 4);       // dv local 0..127
      const int seg = tid & 15;                  // 16B segment within row
      const int gm = m0 + seg * 8;
      const int bb = gm / 784, kk = gm - bb * 784;
      const int dvl = (n0 + row) & 255;
      uint4 v = *(const uint4*)(Cs + row * 272 + seg * 16);
      *(uint4*)((unsigned short*)Cout + ((long)(bb * 12 + hh) * 256 + dvl) * 784 + kk) = v;
    }
  } else {
    #pragma unroll
    for (int mt = 0; mt < 4; ++mt) {
      #pragma unroll
      for (int nt = 0; nt < 4; ++nt) {
        const int gm = m0 + wm + mt * 16 + cl;
        const int gn = n0 + wn + nt * 16 + kg * 4;
        if constexpr (EPI == 1) {
          float4 a4 = *(const float4*)(ea + gn);
          float4 b4 = *(const float4*)(eb + gn);
          union { ushort4 u; __hip_bfloat16 h[4]; } pk;
          pk.h[0] = __float2bfloat16(acc[mt][nt][0] * a4.x + b4.x);
          pk.h[1] = __float2bfloat16(acc[mt][nt][1] * a4.y + b4.y);
          pk.h[2] = __float2bfloat16(acc[mt][nt][2] * a4.z + b4.z);
          pk.h[3] = __float2bfloat16(acc[mt][nt][3] * a4.w + b4.w);
          *(ushort4*)((unsigned short*)Cout + (long)gm * N + gn) = pk.u;
        } else {
          *(float4*)((float*)Cout + (long)gm * N + gn) =
              make_float4(acc[mt][nt][0], acc[mt][nt][1], acc[mt][nt][2], acc[mt][nt][3]);
        }
      }
    }
  }
}

// ---------------------------------------------------------------------------
// Single-pass MFMA flash attention + V register prefetch one tile ahead.
// Identical to round-7 structure otherwise; launch_bounds(512,4).
// ---------------------------------------------------------------------------
#define LOAD_VF(KT, V0, V1, V2, V3) { \
    const int kvo_ = (KT) * 64 + kb; \
    V0 = *(const bf16x8*)(vt + vr0 + kvo_); \
    V1 = *(const bf16x8*)(vt + vr0 + kvo_ + 32); \
    V2 = *(const bf16x8*)(vt + vr1 + kvo_); \
    V3 = *(const bf16x8*)(vt + vr1 + kvo_ + 32); }

#define ATTN_STEP(KT, CUR, VC0, VC1, VC2, VC3, VN0, VN1, VN2, VN3) { \
    const int k0_ = (KT) * 64; \
    if ((KT) < 12) { \
      int kk_ = tid >> 3, d8_ = tid & 7; \
      bf16x8 v_ = zero8; \
      if (k0_ + 64 + kk_ < 784) \
        v_ = *(const bf16x8*)(kbuf + ((long)b * 784 + k0_ + 64 + kk_) * 768 + h * 64 + d8_ * 8); \
      *(bf16x8*)&Ks[(CUR) ^ 1][kk_][d8_ * 8] = v_; \
    } \
    if ((KT) + 1 < 13) { LOAD_VF((KT) + 1, VN0, VN1, VN2, VN3); } \
    _Pragma("unroll") \
    for (int i_ = 0; i_ < 4; ++i_) { \
      int mt_ = mt0 + 2 * i_; \
      if (mt_ >= 7) break; \
      bf16x8 q0_ = *(const bf16x8*)&Qs[mt_ * 16 + cl][kb]; \
      bf16x8 q1_ = *(const bf16x8*)&Qs[mt_ * 16 + cl][32 + kb]; \
      bf16x8 kf0_ = *(const bf16x8*)&Ks[CUR][snt * 16 + cl][kb]; \
      bf16x8 kf1_ = *(const bf16x8*)&Ks[CUR][snt * 16 + cl][32 + kb]; \
      f32x4 s_ = mfma16(kf1_, q1_, mfma16(kf0_, q0_, zerof)); \
      const int rowl_ = mt_ * 16 + cl; \
      const int key0_ = k0_ + snt * 16 + kg * 4; \
      const bool ok_ = (rowl_ < valid) && (key0_ < 784); \
      float4 b4_ = make_float4(0.f, 0.f, 0.f, 0.f); \
      if (ok_) b4_ = *(const float4*)(bias + (long)(qbase + rowl_) * 784 + key0_); \
      float p0_ = ok_ ? __expf(s_[0] * 0.125f + b4_.x) : 0.f; \
      float p1_ = ok_ ? __expf(s_[1] * 0.125f + b4_.y) : 0.f; \
      float p2_ = ok_ ? __expf(s_[2] * 0.125f + b4_.z) : 0.f; \
      float p3_ = ok_ ? __expf(s_[3] * 0.125f + b4_.w) : 0.f; \
      lpart[i_] += (p0_ + p1_) + (p2_ + p3_); \
      union { ushort4 u; __hip_bfloat16 hh_[4]; } pk_; \
      pk_.hh_[0] = __float2bfloat16(p0_); pk_.hh_[1] = __float2bfloat16(p1_); \
      pk_.hh_[2] = __float2bfloat16(p2_); pk_.hh_[3] = __float2bfloat16(p3_); \
      *(ushort4*)&pPs[rowl_][snt * 16 + kg * 4] = pk_.u; \
    } \
    __syncthreads(); \
    _Pragma("unroll") \
    for (int mt_ = 0; mt_ < 7; ++mt_) { \
      bf16x8 pa0_ = *(const bf16x8*)&pPs[mt_ * 16 + cl][kb]; \
      bf16x8 pa1_ = *(const bf16x8*)&pPs[mt_ * 16 + cl][32 + kb]; \
      acc[mt_][0] = mfma16(pa0_, VC0, acc[mt_][0]); \
      acc[mt_][0] = mfma16(pa1_, VC1, acc[mt_][0]); \
      acc[mt_][1] = mfma16(pa0_, VC2, acc[mt_][1]); \
      acc[mt_][1] = mfma16(pa1_, VC3, acc[mt_][1]); \
    } \
    __syncthreads(); }

__global__ __launch_bounds__(512, 4) void attn_mfma(
    const unsigned short* __restrict__ kbuf, const unsigned short* __restrict__ vt,
    const unsigned short* __restrict__ qn, const float* __restrict__ bias,
    unsigned short* __restrict__ O) {
  const int qt = blockIdx.x, h = blockIdx.y, b = blockIdx.z;
  const int tid = threadIdx.x;
  const int w = tid >> 6;
  const int lane = tid & 63;
  const int cl = lane & 15;
  const int kg = lane >> 4;
  const int kb = kg * 8;
  const int qbase = qt * 112;
  const int valid = 196 - qbase > 112 ? 112 : 196 - qbase;
  const int bh = b * 12 + h;

  __shared__ __align__(16) short Qs[112][72];
  __shared__ __align__(16) short Ks[2][64][72];
  __shared__ __align__(16) short pPs[112][72];
  __shared__ float pred[4][112];
  __shared__ float lsum[112];

  const bf16x8 zero8 = {0,0,0,0,0,0,0,0};
  const f32x4 zerof = {0.f,0.f,0.f,0.f};

  for (int f = tid; f < 896; f += 512) {
    int row = f >> 3, d8 = f & 7;
    bf16x8 v = zero8;
    if (row < valid)
      v = *(const bf16x8*)(qn + (long)(b * 196 + qbase + row) * 768 + h * 64 + d8 * 8);
    *(bf16x8*)&Qs[row][d8 * 8] = v;
  }
  {
    int kk = tid >> 3, d8 = tid & 7;
    bf16x8 v = *(const bf16x8*)(kbuf + ((long)b * 784 + kk) * 768 + h * 64 + d8 * 8);
    *(bf16x8*)&Ks[0][kk][d8 * 8] = v;
  }

  const int mt0 = w >> 2, snt = w & 3;
  const long vr0 = ((long)bh * 256 + w * 32 + cl) * 784;
  const long vr1 = vr0 + (long)16 * 784;

  // prefetch V tile 0
  bf16x8 vA0, vA1, vA2, vA3;
  bf16x8 vB0 = zero8, vB1 = zero8, vB2 = zero8, vB3 = zero8;
  LOAD_VF(0, vA0, vA1, vA2, vA3);
  __syncthreads();

  f32x4 acc[7][2];
  #pragma unroll
  for (int mt = 0; mt < 7; ++mt) { acc[mt][0] = zerof; acc[mt][1] = zerof; }
  float lpart[4] = {0.f, 0.f, 0.f, 0.f};

  for (int kt2 = 0; kt2 < 13; kt2 += 2) {
    ATTN_STEP(kt2, 0, vA0, vA1, vA2, vA3, vB0, vB1, vB2, vB3);
    if (kt2 + 1 < 13) {
      ATTN_STEP(kt2 + 1, 1, vB0, vB1, vB2, vB3, vA0, vA1, vA2, vA3);
    }
  }

  #pragma unroll
  for (int i = 0; i < 4; ++i) {
    int mt = mt0 + 2 * i;
    if (mt >= 7) break;
    float v = lpart[i];
    v += __shfl_xor(v, 16);
    v += __shfl_xor(v, 32);
    if (kg == 0) pred[snt][mt * 16 + cl] = v;
  }
  __syncthreads();
  if (tid < 112)
    lsum[tid] = (pred[0][tid] + pred[1][tid]) + (pred[2][tid] + pred[3][tid]);
  __syncthreads();

  #pragma unroll
  for (int mt = 0; mt < 7; ++mt) {
    #pragma unroll
    for (int r = 0; r < 4; ++r) {
      const int rl = mt * 16 + kg * 4 + r;
      if (rl < valid) {
        const float inv = 1.0f / lsum[rl];
        #pragma unroll
        for (int nt2 = 0; nt2 < 2; ++nt2) {
          float ov = hswish(acc[mt][nt2][r] * inv);
          __hip_bfloat16 hv = __float2bfloat16(ov);
          O[(long)(b * 196 + qbase + rl) * 3072 + h * 256 + w * 32 + nt2 * 16 + cl] =
              *(unsigned short*)&hv;
        }
      }
    }
  }
}

// ---------------------------------------------------------------------------
extern "C" void kernel_launch(void* const* d_in, const int* in_sizes, int n_in,
                              void* d_out, int out_size, void* d_ws, size_t ws_size,
                              hipStream_t stream) {
  if (ws_size < WS_TOTAL) return;

  const float* x    = (const float*)d_in[0];
  const float* Wqkv = (const float*)d_in[1];
  const float* bn1s = (const float*)d_in[2];
  const float* Wq   = (const float*)d_in[3];
  const float* bn2s = (const float*)d_in[4];
  const float* bias = (const float*)d_in[5];
  const float* Wout = (const float*)d_in[6];

  char* ws = (char*)d_ws;
  unsigned short* kb   = (unsigned short*)(ws + OFF_K);
  unsigned short* xbT  = (unsigned short*)(ws + OFF_XBT);
  unsigned short* xqT  = (unsigned short*)(ws + OFF_XQT);
  float* t1            = (float*)(ws + OFF_T1);
  float* t2            = (float*)(ws + OFF_T2);
  unsigned short* sxb1 = (unsigned short*)(ws + OFF_SXB1);
  unsigned short* sxb2 = (unsigned short*)(ws + OFF_SXB2);
  unsigned short* vtb  = (unsigned short*)(ws + OFF_VT);
  unsigned short* qnb  = (unsigned short*)(ws + OFF_QN);
  unsigned short* xb   = (unsigned short*)(ws + OFF_XB);
  unsigned short* Ob   = (unsigned short*)(ws + OFF_O);
  unsigned short* wqkvt= (unsigned short*)(ws + OFF_WQKVT);
  unsigned short* wqt  = (unsigned short*)(ws + OFF_WQT);
  unsigned short* woutt= (unsigned short*)(ws + OFF_WOUTT);
  float* ps1  = (float*)(ws + OFF_PS1);
  float* ps2  = (float*)(ws + OFF_PS2);
  float* sx1  = (float*)(ws + OFF_SX1);
  float* cs1  = (float*)(ws + OFF_CS1);
  float* sx2  = (float*)(ws + OFF_SX2);
  float* cs2  = (float*)(ws + OFF_CS2);
  float* a1w  = (float*)(ws + OFF_A1);
  float* b1w  = (float*)(ws + OFF_B1);
  float* a2w  = (float*)(ws + OFF_A2);
  float* b2w  = (float*)(ws + OFF_B2);
  float* out  = (float*)d_out;

  // prep: bf16 copies / transposes of x
  convert_bf16<<<dim3(4704), 256, 0, stream>>>(x, xb, (long)M1 * Kc / 8);
  transpose_bf16<<<dim3(12, 784), 256, 0, stream>>>(x, xbT, M1, Kc);
  transpose_gather_bf16<<<dim3(12, 196), 256, 0, stream>>>(x, xqT);
  rowsum_bf16<<<dim3(384), 256, 0, stream>>>(xbT, cs1, M1);
  rowsum_bf16<<<dim3(384), 256, 0, stream>>>(xqT, cs2, M2);

  // Sx via split-K MFMA
  sx_mfma<<<dim3(3, 3, CH1), 256, 0, stream>>>(xbT, ps1, M1, M1 / CH1);
  sx_mfma<<<dim3(3, 3, CH2), 256, 0, stream>>>(xqT, ps2, M2, M2 / CH2);
  reduce_chunks<<<dim3(576), 256, 0, stream>>>(ps1, sx1, 384 * 384, CH1);
  reduce_chunks<<<dim3(576), 256, 0, stream>>>(ps2, sx2, 384 * 384, CH2);
  convert_bf16<<<dim3(72), 256, 0, stream>>>(sx1, sxb1, 384 * 384 / 8);
  convert_bf16<<<dim3(72), 256, 0, stream>>>(sx2, sxb2, 384 * 384 / 8);

  // weight transposes (overwrite ps1 region - dead after reduce)
  transpose_bf16<<<dim3(120, 12), 256, 0, stream>>>(Wqkv, wqkvt, Kc, N1);
  transpose_bf16<<<dim3(24, 12),  256, 0, stream>>>(Wq,   wqt,   Kc, Dq);
  transpose_bf16<<<dim3(16, 96),  256, 0, stream>>>(Wout, woutt, 4 * Dq, OUTD);

  // BN coefficients: T = Sx @ W via MFMA, then column reduce
  gemm_mfma<0, 0><<<dim3(30, 3), 256, 0, stream>>>(sxb1, wqkvt, t1, nullptr, nullptr, N1, Kc);
  gemm_mfma<0, 0><<<dim3(6, 3),  256, 0, stream>>>(sxb2, wqt,   t2, nullptr, nullptr, Dq, Kc);
  bnfinal<<<dim3(60), 256, 0, stream>>>(Wqkv, t1, cs1, bn1s, a1w, b1w, N1, 1.f / (float)M1);
  bnfinal<<<dim3(12), 256, 0, stream>>>(Wq,   t2, cs2, bn2s, a2w, b2w, Dq, 1.f / (float)M2);

  // projections
  gemm_mfma<0, 1><<<dim3(6, 196), 256, 0, stream>>>(xb, wqkvt, kb, a1w, b1w, 768, Kc);
  gemm_mfma<0, 2><<<dim3(24, 196), 256, 0, stream>>>(
      xb, wqkvt + (long)768 * Kc, vtb, a1w + 768, b1w + 768, 3072, Kc);
  gemm_mfma<1, 1><<<dim3(6, 49), 256, 0, stream>>>(xb, wqt, qnb, a2w, b2w, Dq, Kc);

  // attention -> hswish(O)
  attn_mfma<<<dim3(2, 12, 32), 512, 0, stream>>>(kb, vtb, qnb, bias, Ob);

  // out = O @ Wout^T
  gemm_mfma<0, 0><<<dim3(4, 49), 256, 0, stream>>>(Ob, woutt, out, nullptr, nullptr, OUTD, 4 * Dq);
}

// Round 10
// 499.531 us; speedup vs baseline: 1.1505x; 1.1505x over previous
//
#include <hip/hip_runtime.h>
#include <hip/hip_bf16.h>

// ---------------------------------------------------------------------------
// LeViT subsample attention (round 9).
//   = round 8 pipeline with:
//   (a) attn_mfma: V-prefetch REVERTED (spilled, round-8 post-mortem);
//       K-tile staging via global_load_lds w/ pre-swizzled source + XOR reads
//       (kills the 8-way ds_write bank conflicts; frees VALU/VGPR)
//   (b) reduce_conv: fused chunk-reduce + bf16 convert for Sx (-2 launches)
//   (c) EPI=2 LDS-restaged coalesced Vt stores (kept from round 8)
// ---------------------------------------------------------------------------

static constexpr int M1 = 25088, N1 = 3840, Kc = 384;
static constexpr int M2 = 6272, Dq = 768, OUTD = 512;
static constexpr int CH1 = 14, CH2 = 7;

static constexpr size_t OFF_K    = 0;
static constexpr size_t OFF_XBT  = 0;
static constexpr size_t OFF_XQT  = 19267584;
static constexpr size_t OFF_T1   = 24084480;
static constexpr size_t OFF_T2   = 29982720;
static constexpr size_t OFF_SXB1 = 31162368;
static constexpr size_t OFF_SXB2 = 31457280;
static constexpr size_t OFF_VT   = 38535168;
static constexpr size_t OFF_QN   = 192675840;
static constexpr size_t OFF_O    = 202309632;
static constexpr size_t OFF_XB   = OFF_O;
static constexpr size_t OFF_PS1  = 240844800;
static constexpr size_t OFF_WQKVT= 240844800;
static constexpr size_t OFF_WQT  = 243793920;
static constexpr size_t OFF_WOUTT= 244383744;
static constexpr size_t OFF_PS2  = 249123840;
static constexpr size_t OFF_SX1  = 253263360;
static constexpr size_t OFF_CS1  = 253853184;
static constexpr size_t OFF_SX2  = 253854720;
static constexpr size_t OFF_CS2  = 254444544;
static constexpr size_t OFF_A1   = 254446080;
static constexpr size_t OFF_B1   = 254461440;
static constexpr size_t OFF_A2   = 254476800;
static constexpr size_t OFF_B2   = 254479872;
static constexpr size_t WS_TOTAL = 254482944;

typedef __attribute__((ext_vector_type(8))) short bf16x8;
typedef __attribute__((ext_vector_type(4))) float f32x4;

static __device__ __forceinline__ f32x4 mfma16(bf16x8 a, bf16x8 b, f32x4 c) {
  return __builtin_amdgcn_mfma_f32_16x16x32_bf16(a, b, c, 0, 0, 0);
}

__device__ __forceinline__ void gload_lds16(const void* g, void* l) {
  __builtin_amdgcn_global_load_lds(
      (const __attribute__((address_space(1))) unsigned int*)g,
      (__attribute__((address_space(3))) unsigned int*)l, 16, 0, 0);
}

__device__ __forceinline__ float hswish(float x) {
  float t = fminf(fmaxf(x + 3.0f, 0.0f), 6.0f);
  return x * t * (1.0f / 6.0f);
}

// --------------------------- prep kernels ----------------------------------
__global__ __launch_bounds__(256) void convert_bf16(
    const float* __restrict__ in, unsigned short* __restrict__ out, long n8) {
  long i = (long)blockIdx.x * 256 + threadIdx.x;
  if (i >= n8) return;
  float4 a = ((const float4*)in)[i * 2];
  float4 b = ((const float4*)in)[i * 2 + 1];
  union { uint4 u; __hip_bfloat16 h[8]; } pk;
  pk.h[0] = __float2bfloat16(a.x); pk.h[1] = __float2bfloat16(a.y);
  pk.h[2] = __float2bfloat16(a.z); pk.h[3] = __float2bfloat16(a.w);
  pk.h[4] = __float2bfloat16(b.x); pk.h[5] = __float2bfloat16(b.y);
  pk.h[6] = __float2bfloat16(b.z); pk.h[7] = __float2bfloat16(b.w);
  ((uint4*)out)[i] = pk.u;
}

__global__ __launch_bounds__(256) void transpose_bf16(
    const float* __restrict__ in, unsigned short* __restrict__ out, int R, int C) {
  __shared__ float t[32][33];
  const int c0 = blockIdx.x * 32, r0 = blockIdx.y * 32;
  const int x = threadIdx.x & 31, y = threadIdx.x >> 5;
  #pragma unroll
  for (int i = y; i < 32; i += 8) t[i][x] = in[(long)(r0 + i) * C + c0 + x];
  __syncthreads();
  #pragma unroll
  for (int i = y; i < 32; i += 8) {
    __hip_bfloat16 v = __float2bfloat16(t[x][i]);
    out[(long)(c0 + i) * R + r0 + x] = *(unsigned short*)&v;
  }
}

__global__ __launch_bounds__(256) void transpose_gather_bf16(
    const float* __restrict__ in, unsigned short* __restrict__ out) {
  __shared__ float t[32][33];
  const int c0 = blockIdx.x * 32, r0 = blockIdx.y * 32;
  const int x = threadIdx.x & 31, y = threadIdx.x >> 5;
  #pragma unroll
  for (int i = y; i < 32; i += 8) {
    int m2 = r0 + i;
    int bb = m2 / 196, tt = m2 - bb * 196;
    int h2 = tt / 14, w2 = tt - h2 * 14;
    long grow = (long)(bb * 784 + h2 * 56 + w2 * 2);
    t[i][x] = in[grow * 384 + c0 + x];
  }
  __syncthreads();
  #pragma unroll
  for (int i = y; i < 32; i += 8) {
    __hip_bfloat16 v = __float2bfloat16(t[x][i]);
    out[(long)(c0 + i) * 6272 + r0 + x] = *(unsigned short*)&v;
  }
}

__global__ __launch_bounds__(256) void rowsum_bf16(
    const unsigned short* __restrict__ src, float* __restrict__ dst, int ncols) {
  const long base = (long)blockIdx.x * ncols;
  float s = 0.f;
  for (int c = threadIdx.x * 8; c < ncols; c += 2048) {
    bf16x8 v = *(const bf16x8*)(src + base + c);
    #pragma unroll
    for (int j = 0; j < 8; ++j)
      s += __uint_as_float(((unsigned)(unsigned short)v[j]) << 16);
  }
  __shared__ float red[256];
  red[threadIdx.x] = s;
  __syncthreads();
  for (int st = 128; st > 0; st >>= 1) {
    if (threadIdx.x < st) red[threadIdx.x] += red[threadIdx.x + st];
    __syncthreads();
  }
  if (threadIdx.x == 0) dst[blockIdx.x] = red[0];
}

// fused chunk-reduce + bf16 convert
__global__ __launch_bounds__(256) void reduce_conv(
    const float* __restrict__ src, float* __restrict__ dst,
    unsigned short* __restrict__ dstb, int nelem, int nchunks) {
  int i = blockIdx.x * 256 + threadIdx.x;
  if (i >= nelem) return;
  float s = 0.f;
  for (int c = 0; c < nchunks; ++c) s += src[(long)c * nelem + i];
  dst[i] = s;
  __hip_bfloat16 hv = __float2bfloat16(s);
  dstb[i] = *(unsigned short*)&hv;
}

// --------------------------- BN finalize -----------------------------------
__global__ __launch_bounds__(256) void bnfinal(
    const float* __restrict__ W, const float* __restrict__ T, const float* __restrict__ cs,
    const float* __restrict__ scale, float* __restrict__ a, float* __restrict__ b,
    int N, float invM) {
  const int j = blockIdx.x * 64 + (threadIdx.x & 63);
  const int rq = threadIdx.x >> 6;
  float yy = 0.f, mu = 0.f;
  for (int k = rq * 96; k < rq * 96 + 96; ++k) {
    float w = W[(long)k * N + j];
    yy += w * T[(long)k * N + j];
    mu += cs[k] * w;
  }
  __shared__ float r1[256], r2[256];
  r1[threadIdx.x] = yy; r2[threadIdx.x] = mu;
  __syncthreads();
  if (threadIdx.x < 64) {
    int t = threadIdx.x;
    yy = r1[t] + r1[t + 64] + r1[t + 128] + r1[t + 192];
    mu = r2[t] + r2[t + 64] + r2[t + 128] + r2[t + 192];
    float mean = mu * invM;
    float var = yy * invM - mean * mean;
    float ai = rsqrtf(var + 1e-5f) * scale[j];
    a[j] = ai;
    b[j] = -mean * ai;
  }
}

// ---------------------------------------------------------------------------
// split-K MFMA X @ X^T (unchanged)
// ---------------------------------------------------------------------------
__global__ __launch_bounds__(256) void sx_mfma(
    const unsigned short* __restrict__ X, float* __restrict__ Cpart,
    int Kfull, int Kchunk) {
  __shared__ __align__(16) char As[16384];
  __shared__ __align__(16) char Bs[16384];
  const int tid = threadIdx.x;
  const int lane = tid & 63;
  const int wv = tid >> 6;
  const int wm = (wv >> 1) * 64, wn = (wv & 1) * 64;
  const int m0 = blockIdx.y * 128, n0 = blockIdx.x * 128;
  const int cl = lane & 15, kg = lane >> 4;
  const int srow = tid >> 3;
  const int swz = ((tid & 7) * 16) ^ ((srow & 7) << 4);
  const int ldsb = wv * 1024;
  const long zbase = (long)blockIdx.z * Kchunk;

  long arow[4], brow[4];
  #pragma unroll
  for (int is = 0; is < 4; ++is) {
    arow[is] = (long)(m0 + is * 32 + srow) * Kfull + zbase;
    brow[is] = (long)(n0 + is * 32 + srow) * Kfull + zbase;
  }

  f32x4 acc[4][4];
  const f32x4 zf = {0.f, 0.f, 0.f, 0.f};
  #pragma unroll
  for (int i = 0; i < 4; ++i)
    #pragma unroll
    for (int j = 0; j < 4; ++j) acc[i][j] = zf;

  for (int k0 = 0; k0 < Kchunk; k0 += 64) {
    #pragma unroll
    for (int is = 0; is < 4; ++is) {
      gload_lds16((const char*)X + (arow[is] + k0) * 2 + swz, As + is * 4096 + ldsb);
      gload_lds16((const char*)X + (brow[is] + k0) * 2 + swz, Bs + is * 4096 + ldsb);
    }
    __syncthreads();
    bf16x8 afr[4][2], bfr[4][2];
    #pragma unroll
    for (int t = 0; t < 4; ++t) {
      const int ar = wm + t * 16 + cl;
      const int br = wn + t * 16 + cl;
      const int sa = (ar & 7) << 4, sb = (br & 7) << 4;
      afr[t][0] = *(const bf16x8*)(As + ar * 128 + ((kg * 16) ^ sa));
      afr[t][1] = *(const bf16x8*)(As + ar * 128 + ((64 + kg * 16) ^ sa));
      bfr[t][0] = *(const bf16x8*)(Bs + br * 128 + ((kg * 16) ^ sb));
      bfr[t][1] = *(const bf16x8*)(Bs + br * 128 + ((64 + kg * 16) ^ sb));
    }
    #pragma unroll
    for (int mt = 0; mt < 4; ++mt)
      #pragma unroll
      for (int nt = 0; nt < 4; ++nt) {
        acc[mt][nt] = mfma16(bfr[nt][0], afr[mt][0], acc[mt][nt]);
        acc[mt][nt] = mfma16(bfr[nt][1], afr[mt][1], acc[mt][nt]);
      }
    __syncthreads();
  }

  float* Cp = Cpart + (long)blockIdx.z * 384 * 384;
  #pragma unroll
  for (int mt = 0; mt < 4; ++mt) {
    const int gm = m0 + wm + mt * 16 + cl;
    #pragma unroll
    for (int nt = 0; nt < 4; ++nt) {
      const int gn = n0 + wn + nt * 16 + kg * 4;
      *(float4*)(Cp + (long)gm * 384 + gn) =
          make_float4(acc[mt][nt][0], acc[mt][nt][1], acc[mt][nt][2], acc[mt][nt][3]);
    }
  }
}

// ---------------------------------------------------------------------------
// bf16 MFMA GEMM: C = A[M,K] @ Bt[N,K]^T.
// EPI: 0 f32 row store; 1 BN->bf16 row store; 2 BN->bf16 transposed store
//      into Vt[b][h][dv][784] via LDS restage (coalesced 256B row writes).
// ---------------------------------------------------------------------------
template<int AMODE, int EPI>
__global__ __launch_bounds__(256) void gemm_mfma(
    const unsigned short* __restrict__ A, const unsigned short* __restrict__ Bt,
    void* __restrict__ Cout, const float* __restrict__ ea, const float* __restrict__ eb,
    int N, int K) {
  constexpr int SMEM_BYTES = (EPI == 2) ? 34816 : 32768;
  __shared__ __align__(16) char smem[SMEM_BYTES];
  char* As = smem;
  char* Bs = smem + 16384;
  const int tid = threadIdx.x;
  const int lane = tid & 63;
  const int wv = tid >> 6;
  const int wm = (wv >> 1) * 64, wn = (wv & 1) * 64;
  const int m0 = blockIdx.y * 128, n0 = blockIdx.x * 128;
  const int cl = lane & 15, kg = lane >> 4;

  const int srow = tid >> 3;
  const int swz = ((tid & 7) * 16) ^ ((srow & 7) << 4);
  const int ldsb = wv * 1024;

  long arow[4], brow[4];
  #pragma unroll
  for (int is = 0; is < 4; ++is) {
    int gm = m0 + is * 32 + srow;
    long grow;
    if constexpr (AMODE == 1) {
      int bb = gm / 196, t = gm - bb * 196;
      int h2 = t / 14, w2 = t - h2 * 14;
      grow = (long)(bb * 784 + h2 * 56 + w2 * 2);
    } else {
      grow = gm;
    }
    arow[is] = grow * (long)K;
    brow[is] = (long)(n0 + is * 32 + srow) * (long)K;
  }

  f32x4 acc[4][4];
  const f32x4 zf = {0.f, 0.f, 0.f, 0.f};
  #pragma unroll
  for (int i = 0; i < 4; ++i)
    #pragma unroll
    for (int j = 0; j < 4; ++j) acc[i][j] = zf;

  for (int k0 = 0; k0 < K; k0 += 64) {
    #pragma unroll
    for (int is = 0; is < 4; ++is) {
      gload_lds16((const char*)A  + (arow[is] + k0) * 2 + swz, As + is * 4096 + ldsb);
      gload_lds16((const char*)Bt + (brow[is] + k0) * 2 + swz, Bs + is * 4096 + ldsb);
    }
    __syncthreads();
    bf16x8 afr[4][2], bfr[4][2];
    #pragma unroll
    for (int t = 0; t < 4; ++t) {
      const int ar = wm + t * 16 + cl;
      const int br = wn + t * 16 + cl;
      const int sa = (ar & 7) << 4, sb = (br & 7) << 4;
      afr[t][0] = *(const bf16x8*)(As + ar * 128 + ((kg * 16) ^ sa));
      afr[t][1] = *(const bf16x8*)(As + ar * 128 + ((64 + kg * 16) ^ sa));
      bfr[t][0] = *(const bf16x8*)(Bs + br * 128 + ((kg * 16) ^ sb));
      bfr[t][1] = *(const bf16x8*)(Bs + br * 128 + ((64 + kg * 16) ^ sb));
    }
    #pragma unroll
    for (int mt = 0; mt < 4; ++mt)
      #pragma unroll
      for (int nt = 0; nt < 4; ++nt) {
        if constexpr (EPI == 2) {
          acc[mt][nt] = mfma16(afr[mt][0], bfr[nt][0], acc[mt][nt]);
          acc[mt][nt] = mfma16(afr[mt][1], bfr[nt][1], acc[mt][nt]);
        } else {
          acc[mt][nt] = mfma16(bfr[nt][0], afr[mt][0], acc[mt][nt]);
          acc[mt][nt] = mfma16(bfr[nt][1], afr[mt][1], acc[mt][nt]);
        }
      }
    __syncthreads();
  }

  if constexpr (EPI == 2) {
    char* Cs = smem;
    #pragma unroll
    for (int mt = 0; mt < 4; ++mt) {
      const int kl = wm + mt * 16 + kg * 4;
      #pragma unroll
      for (int nt = 0; nt < 4; ++nt) {
        const int dvl = wn + nt * 16 + cl;
        const int gn = n0 + dvl;
        const float av = ea[gn], bv = eb[gn];
        union { ushort4 u; __hip_bfloat16 h[4]; } pk;
        pk.h[0] = __float2bfloat16(acc[mt][nt][0] * av + bv);
        pk.h[1] = __float2bfloat16(acc[mt][nt][1] * av + bv);
        pk.h[2] = __float2bfloat16(acc[mt][nt][2] * av + bv);
        pk.h[3] = __float2bfloat16(acc[mt][nt][3] * av + bv);
        *(ushort4*)(Cs + dvl * 272 + kl * 2) = pk.u;
      }
    }
    __syncthreads();
    const int hh = n0 >> 8;
    #pragma unroll
    for (int l = 0; l < 8; ++l) {
      const int row = l * 16 + (tid >> 4);
      const int seg = tid & 15;
      const int gm = m0 + seg * 8;
      const int bb = gm / 784, kk = gm - bb * 784;
      const int dvl = (n0 + row) & 255;
      uint4 v = *(const uint4*)(Cs + row * 272 + seg * 16);
      *(uint4*)((unsigned short*)Cout + ((long)(bb * 12 + hh) * 256 + dvl) * 784 + kk) = v;
    }
  } else {
    #pragma unroll
    for (int mt = 0; mt < 4; ++mt) {
      #pragma unroll
      for (int nt = 0; nt < 4; ++nt) {
        const int gm = m0 + wm + mt * 16 + cl;
        const int gn = n0 + wn + nt * 16 + kg * 4;
        if constexpr (EPI == 1) {
          float4 a4 = *(const float4*)(ea + gn);
          float4 b4 = *(const float4*)(eb + gn);
          union { ushort4 u; __hip_bfloat16 h[4]; } pk;
          pk.h[0] = __float2bfloat16(acc[mt][nt][0] * a4.x + b4.x);
          pk.h[1] = __float2bfloat16(acc[mt][nt][1] * a4.y + b4.y);
          pk.h[2] = __float2bfloat16(acc[mt][nt][2] * a4.z + b4.z);
          pk.h[3] = __float2bfloat16(acc[mt][nt][3] * a4.w + b4.w);
          *(ushort4*)((unsigned short*)Cout + (long)gm * N + gn) = pk.u;
        } else {
          *(float4*)((float*)Cout + (long)gm * N + gn) =
              make_float4(acc[mt][nt][0], acc[mt][nt][1], acc[mt][nt][2], acc[mt][nt][3]);
        }
      }
    }
  }
}

// ---------------------------------------------------------------------------
// Single-pass MFMA flash attention (round-7 structure).
// K tiles staged via global_load_lds: pre-swizzled per-lane SOURCE address,
// linear wave-uniform LDS dest, XOR-swizzled ds_read_b128 fragments (T2).
// V fragments loaded from global in-tile (no prefetch - spills, r8 lesson).
// ---------------------------------------------------------------------------
__global__ __launch_bounds__(512, 4) void attn_mfma(
    const unsigned short* __restrict__ kbuf, const unsigned short* __restrict__ vt,
    const unsigned short* __restrict__ qn, const float* __restrict__ bias,
    unsigned short* __restrict__ O) {
  const int qt = blockIdx.x, h = blockIdx.y, b = blockIdx.z;
  const int tid = threadIdx.x;
  const int w = tid >> 6;
  const int lane = tid & 63;
  const int cl = lane & 15;
  const int kg = lane >> 4;
  const int kb = kg * 8;
  const int qbase = qt * 112;
  const int valid = 196 - qbase > 112 ? 112 : 196 - qbase;
  const int bh = b * 12 + h;

  __shared__ __align__(16) short Qs[112][72];
  __shared__ __align__(16) char Kl[2][8192];   // linear swizzled K tiles
  __shared__ __align__(16) short pPs[112][72];
  __shared__ float pred[4][112];
  __shared__ float lsum[112];

  const bf16x8 zero8 = {0,0,0,0,0,0,0,0};
  const f32x4 zerof = {0.f,0.f,0.f,0.f};

  // K staging source address (bytes), pre-swizzled column
  const int srow = tid >> 3;                       // tile row 0..63
  const int ssw = ((tid & 7) * 16) ^ ((srow & 7) << 4);
  const long kbase = ((long)(b * 784 + srow) * 768 + h * 64) * 2 + ssw;

  // stage Q (reg->LDS, once)
  for (int f = tid; f < 896; f += 512) {
    int row = f >> 3, d8 = f & 7;
    bf16x8 v = zero8;
    if (row < valid)
      v = *(const bf16x8*)(qn + (long)(b * 196 + qbase + row) * 768 + h * 64 + d8 * 8);
    *(bf16x8*)&Qs[row][d8 * 8] = v;
  }
  // stage K tile 0 (async direct-to-LDS; tail rows read adjacent ws = benign)
  gload_lds16((const char*)kbuf + kbase, Kl[0] + w * 1024);
  __syncthreads();

  const int mt0 = w >> 2, snt = w & 3;
  const long vr0 = ((long)bh * 256 + w * 32 + cl) * 784;
  const long vr1 = vr0 + (long)16 * 784;

  f32x4 acc[7][2];
  #pragma unroll
  for (int mt = 0; mt < 7; ++mt) { acc[mt][0] = zerof; acc[mt][1] = zerof; }
  float lpart[4] = {0.f, 0.f, 0.f, 0.f};

  // K fragment row address pieces (XOR swizzle)
  const int krow = snt * 16 + cl;
  const int ksw = (krow & 7) << 4;

  for (int kt = 0; kt < 13; ++kt) {
    const int k0 = kt * 64;
    const int cur = kt & 1;
    // V fragments for this tile (sync loads first -> vmcnt can retire them
    // without draining the K prefetch issued after)
    bf16x8 vf00, vf01, vf10, vf11;
    vf00 = *(const bf16x8*)(vt + vr0 + k0 + kb);
    vf10 = *(const bf16x8*)(vt + vr0 + k0 + 32 + kb);
    vf01 = *(const bf16x8*)(vt + vr1 + k0 + kb);
    vf11 = *(const bf16x8*)(vt + vr1 + k0 + 32 + kb);
    // prefetch next K tile (async, drained by the barrier below)
    if (kt < 12)
      gload_lds16((const char*)kbuf + kbase + (long)(k0 + 64) * 1536,
                  Kl[cur ^ 1] + w * 1024);
    // QK^T -> P
    const char* kr = Kl[cur] + krow * 128;
    bf16x8 kk0 = *(const bf16x8*)(kr + ((kg * 16) ^ ksw));
    bf16x8 kk1 = *(const bf16x8*)(kr + ((64 + kg * 16) ^ ksw));
    #pragma unroll
    for (int i = 0; i < 4; ++i) {
      int mt = mt0 + 2 * i;
      if (mt >= 7) break;
      bf16x8 q0 = *(const bf16x8*)&Qs[mt * 16 + cl][kb];
      bf16x8 q1 = *(const bf16x8*)&Qs[mt * 16 + cl][32 + kb];
      f32x4 s = mfma16(kk1, q1, mfma16(kk0, q0, zerof));
      const int rowl = mt * 16 + cl;
      const int key0 = k0 + snt * 16 + kg * 4;
      const bool ok = (rowl < valid) && (key0 < 784);
      float4 b4 = make_float4(0.f, 0.f, 0.f, 0.f);
      if (ok) b4 = *(const float4*)(bias + (long)(qbase + rowl) * 784 + key0);
      float p0 = ok ? __expf(s[0] * 0.125f + b4.x) : 0.f;
      float p1 = ok ? __expf(s[1] * 0.125f + b4.y) : 0.f;
      float p2 = ok ? __expf(s[2] * 0.125f + b4.z) : 0.f;
      float p3 = ok ? __expf(s[3] * 0.125f + b4.w) : 0.f;
      lpart[i] += (p0 + p1) + (p2 + p3);
      union { ushort4 u; __hip_bfloat16 hh[4]; } pk;
      pk.hh[0] = __float2bfloat16(p0);
      pk.hh[1] = __float2bfloat16(p1);
      pk.hh[2] = __float2bfloat16(p2);
      pk.hh[3] = __float2bfloat16(p3);
      *(ushort4*)&pPs[rowl][snt * 16 + kg * 4] = pk.u;
    }
    __syncthreads();
    // PV
    #pragma unroll
    for (int mt = 0; mt < 7; ++mt) {
      bf16x8 pa0 = *(const bf16x8*)&pPs[mt * 16 + cl][kb];
      bf16x8 pa1 = *(const bf16x8*)&pPs[mt * 16 + cl][32 + kb];
      acc[mt][0] = mfma16(pa0, vf00, acc[mt][0]);
      acc[mt][0] = mfma16(pa1, vf10, acc[mt][0]);
      acc[mt][1] = mfma16(pa0, vf01, acc[mt][1]);
      acc[mt][1] = mfma16(pa1, vf11, acc[mt][1]);
    }
    __syncthreads();
  }

  #pragma unroll
  for (int i = 0; i < 4; ++i) {
    int mt = mt0 + 2 * i;
    if (mt >= 7) break;
    float v = lpart[i];
    v += __shfl_xor(v, 16);
    v += __shfl_xor(v, 32);
    if (kg == 0) pred[snt][mt * 16 + cl] = v;
  }
  __syncthreads();
  if (tid < 112)
    lsum[tid] = (pred[0][tid] + pred[1][tid]) + (pred[2][tid] + pred[3][tid]);
  __syncthreads();

  #pragma unroll
  for (int mt = 0; mt < 7; ++mt) {
    #pragma unroll
    for (int r = 0; r < 4; ++r) {
      const int rl = mt * 16 + kg * 4 + r;
      if (rl < valid) {
        const float inv = 1.0f / lsum[rl];
        #pragma unroll
        for (int nt2 = 0; nt2 < 2; ++nt2) {
          float ov = hswish(acc[mt][nt2][r] * inv);
          __hip_bfloat16 hv = __float2bfloat16(ov);
          O[(long)(b * 196 + qbase + rl) * 3072 + h * 256 + w * 32 + nt2 * 16 + cl] =
              *(unsigned short*)&hv;
        }
      }
    }
  }
}

// ---------------------------------------------------------------------------
extern "C" void kernel_launch(void* const* d_in, const int* in_sizes, int n_in,
                              void* d_out, int out_size, void* d_ws, size_t ws_size,
                              hipStream_t stream) {
  if (ws_size < WS_TOTAL) return;

  const float* x    = (const float*)d_in[0];
  const float* Wqkv = (const float*)d_in[1];
  const float* bn1s = (const float*)d_in[2];
  const float* Wq   = (const float*)d_in[3];
  const float* bn2s = (const float*)d_in[4];
  const float* bias = (const float*)d_in[5];
  const float* Wout = (const float*)d_in[6];

  char* ws = (char*)d_ws;
  unsigned short* kb   = (unsigned short*)(ws + OFF_K);
  unsigned short* xbT  = (unsigned short*)(ws + OFF_XBT);
  unsigned short* xqT  = (unsigned short*)(ws + OFF_XQT);
  float* t1            = (float*)(ws + OFF_T1);
  float* t2            = (float*)(ws + OFF_T2);
  unsigned short* sxb1 = (unsigned short*)(ws + OFF_SXB1);
  unsigned short* sxb2 = (unsigned short*)(ws + OFF_SXB2);
  unsigned short* vtb  = (unsigned short*)(ws + OFF_VT);
  unsigned short* qnb  = (unsigned short*)(ws + OFF_QN);
  unsigned short* xb   = (unsigned short*)(ws + OFF_XB);
  unsigned short* Ob   = (unsigned short*)(ws + OFF_O);
  unsigned short* wqkvt= (unsigned short*)(ws + OFF_WQKVT);
  unsigned short* wqt  = (unsigned short*)(ws + OFF_WQT);
  unsigned short* woutt= (unsigned short*)(ws + OFF_WOUTT);
  float* ps1  = (float*)(ws + OFF_PS1);
  float* ps2  = (float*)(ws + OFF_PS2);
  float* sx1  = (float*)(ws + OFF_SX1);
  float* cs1  = (float*)(ws + OFF_CS1);
  float* sx2  = (float*)(ws + OFF_SX2);
  float* cs2  = (float*)(ws + OFF_CS2);
  float* a1w  = (float*)(ws + OFF_A1);
  float* b1w  = (float*)(ws + OFF_B1);
  float* a2w  = (float*)(ws + OFF_A2);
  float* b2w  = (float*)(ws + OFF_B2);
  float* out  = (float*)d_out;

  // prep: bf16 copies / transposes of x
  convert_bf16<<<dim3(4704), 256, 0, stream>>>(x, xb, (long)M1 * Kc / 8);
  transpose_bf16<<<dim3(12, 784), 256, 0, stream>>>(x, xbT, M1, Kc);
  transpose_gather_bf16<<<dim3(12, 196), 256, 0, stream>>>(x, xqT);
  rowsum_bf16<<<dim3(384), 256, 0, stream>>>(xbT, cs1, M1);
  rowsum_bf16<<<dim3(384), 256, 0, stream>>>(xqT, cs2, M2);

  // Sx via split-K MFMA (+fused f32->bf16 convert)
  sx_mfma<<<dim3(3, 3, CH1), 256, 0, stream>>>(xbT, ps1, M1, M1 / CH1);
  sx_mfma<<<dim3(3, 3, CH2), 256, 0, stream>>>(xqT, ps2, M2, M2 / CH2);
  reduce_conv<<<dim3(576), 256, 0, stream>>>(ps1, sx1, sxb1, 384 * 384, CH1);
  reduce_conv<<<dim3(576), 256, 0, stream>>>(ps2, sx2, sxb2, 384 * 384, CH2);

  // weight transposes (overwrite ps1 region - dead after reduce)
  transpose_bf16<<<dim3(120, 12), 256, 0, stream>>>(Wqkv, wqkvt, Kc, N1);
  transpose_bf16<<<dim3(24, 12),  256, 0, stream>>>(Wq,   wqt,   Kc, Dq);
  transpose_bf16<<<dim3(16, 96),  256, 0, stream>>>(Wout, woutt, 4 * Dq, OUTD);

  // BN coefficients: T = Sx @ W via MFMA, then column reduce
  gemm_mfma<0, 0><<<dim3(30, 3), 256, 0, stream>>>(sxb1, wqkvt, t1, nullptr, nullptr, N1, Kc);
  gemm_mfma<0, 0><<<dim3(6, 3),  256, 0, stream>>>(sxb2, wqt,   t2, nullptr, nullptr, Dq, Kc);
  bnfinal<<<dim3(60), 256, 0, stream>>>(Wqkv, t1, cs1, bn1s, a1w, b1w, N1, 1.f / (float)M1);
  bnfinal<<<dim3(12), 256, 0, stream>>>(Wq,   t2, cs2, bn2s, a2w, b2w, Dq, 1.f / (float)M2);

  // projections
  gemm_mfma<0, 1><<<dim3(6, 196), 256, 0, stream>>>(xb, wqkvt, kb, a1w, b1w, 768, Kc);
  gemm_mfma<0, 2><<<dim3(24, 196), 256, 0, stream>>>(
      xb, wqkvt + (long)768 * Kc, vtb, a1w + 768, b1w + 768, 3072, Kc);
  gemm_mfma<1, 1><<<dim3(6, 49), 256, 0, stream>>>(xb, wqt, qnb, a2w, b2w, Dq, Kc);

  // attention -> hswish(O)
  attn_mfma<<<dim3(2, 12, 32), 512, 0, stream>>>(kb, vtb, qnb, bias, Ob);

  // out = O @ Wout^T
  gemm_mfma<0, 0><<<dim3(4, 49), 256, 0, stream>>>(Ob, woutt, out, nullptr, nullptr, OUTD, 4 * Dq);
}

// Round 11
// 487.046 us; speedup vs baseline: 1.1800x; 1.0256x over previous
//
#include <hip/hip_runtime.h>
#include <hip/hip_bf16.h>

// ---------------------------------------------------------------------------
// LeViT subsample attention (round 10).
//   = round 9 with:
//   (a) XCD chunked block swizzle (T1) on K-gemm, V-gemm, attn (L2 locality)
//   (b) merged rowsum / reduce_conv launches; dead f32 Sx stores dropped
// ---------------------------------------------------------------------------

static constexpr int M1 = 25088, N1 = 3840, Kc = 384;
static constexpr int M2 = 6272, Dq = 768, OUTD = 512;
static constexpr int CH1 = 14, CH2 = 7;

static constexpr size_t OFF_K    = 0;
static constexpr size_t OFF_XBT  = 0;
static constexpr size_t OFF_XQT  = 19267584;
static constexpr size_t OFF_T1   = 24084480;
static constexpr size_t OFF_T2   = 29982720;
static constexpr size_t OFF_SXB1 = 31162368;
static constexpr size_t OFF_SXB2 = 31457280;
static constexpr size_t OFF_VT   = 38535168;
static constexpr size_t OFF_QN   = 192675840;
static constexpr size_t OFF_O    = 202309632;
static constexpr size_t OFF_XB   = OFF_O;
static constexpr size_t OFF_PS1  = 240844800;
static constexpr size_t OFF_WQKVT= 240844800;
static constexpr size_t OFF_WQT  = 243793920;
static constexpr size_t OFF_WOUTT= 244383744;
static constexpr size_t OFF_PS2  = 249123840;
static constexpr size_t OFF_CS1  = 253853184;
static constexpr size_t OFF_CS2  = 254444544;
static constexpr size_t OFF_A1   = 254446080;
static constexpr size_t OFF_B1   = 254461440;
static constexpr size_t OFF_A2   = 254476800;
static constexpr size_t OFF_B2   = 254479872;
static constexpr size_t WS_TOTAL = 254482944;

typedef __attribute__((ext_vector_type(8))) short bf16x8;
typedef __attribute__((ext_vector_type(4))) float f32x4;

static __device__ __forceinline__ f32x4 mfma16(bf16x8 a, bf16x8 b, f32x4 c) {
  return __builtin_amdgcn_mfma_f32_16x16x32_bf16(a, b, c, 0, 0, 0);
}

__device__ __forceinline__ void gload_lds16(const void* g, void* l) {
  __builtin_amdgcn_global_load_lds(
      (const __attribute__((address_space(1))) unsigned int*)g,
      (__attribute__((address_space(3))) unsigned int*)l, 16, 0, 0);
}

__device__ __forceinline__ float hswish(float x) {
  float t = fminf(fmaxf(x + 3.0f, 0.0f), 6.0f);
  return x * t * (1.0f / 6.0f);
}

// --------------------------- prep kernels ----------------------------------
__global__ __launch_bounds__(256) void convert_bf16(
    const float* __restrict__ in, unsigned short* __restrict__ out, long n8) {
  long i = (long)blockIdx.x * 256 + threadIdx.x;
  if (i >= n8) return;
  float4 a = ((const float4*)in)[i * 2];
  float4 b = ((const float4*)in)[i * 2 + 1];
  union { uint4 u; __hip_bfloat16 h[8]; } pk;
  pk.h[0] = __float2bfloat16(a.x); pk.h[1] = __float2bfloat16(a.y);
  pk.h[2] = __float2bfloat16(a.z); pk.h[3] = __float2bfloat16(a.w);
  pk.h[4] = __float2bfloat16(b.x); pk.h[5] = __float2bfloat16(b.y);
  pk.h[6] = __float2bfloat16(b.z); pk.h[7] = __float2bfloat16(b.w);
  ((uint4*)out)[i] = pk.u;
}

__global__ __launch_bounds__(256) void transpose_bf16(
    const float* __restrict__ in, unsigned short* __restrict__ out, int R, int C) {
  __shared__ float t[32][33];
  const int c0 = blockIdx.x * 32, r0 = blockIdx.y * 32;
  const int x = threadIdx.x & 31, y = threadIdx.x >> 5;
  #pragma unroll
  for (int i = y; i < 32; i += 8) t[i][x] = in[(long)(r0 + i) * C + c0 + x];
  __syncthreads();
  #pragma unroll
  for (int i = y; i < 32; i += 8) {
    __hip_bfloat16 v = __float2bfloat16(t[x][i]);
    out[(long)(c0 + i) * R + r0 + x] = *(unsigned short*)&v;
  }
}

__global__ __launch_bounds__(256) void transpose_gather_bf16(
    const float* __restrict__ in, unsigned short* __restrict__ out) {
  __shared__ float t[32][33];
  const int c0 = blockIdx.x * 32, r0 = blockIdx.y * 32;
  const int x = threadIdx.x & 31, y = threadIdx.x >> 5;
  #pragma unroll
  for (int i = y; i < 32; i += 8) {
    int m2 = r0 + i;
    int bb = m2 / 196, tt = m2 - bb * 196;
    int h2 = tt / 14, w2 = tt - h2 * 14;
    long grow = (long)(bb * 784 + h2 * 56 + w2 * 2);
    t[i][x] = in[grow * 384 + c0 + x];
  }
  __syncthreads();
  #pragma unroll
  for (int i = y; i < 32; i += 8) {
    __hip_bfloat16 v = __float2bfloat16(t[x][i]);
    out[(long)(c0 + i) * 6272 + r0 + x] = *(unsigned short*)&v;
  }
}

// merged per-row sums: z=0 -> (srcA, M1) -> dstA ; z=1 -> (srcB, M2) -> dstB
__global__ __launch_bounds__(256) void rowsum2_bf16(
    const unsigned short* __restrict__ srcA, const unsigned short* __restrict__ srcB,
    float* __restrict__ dstA, float* __restrict__ dstB) {
  const int z = blockIdx.y;
  const unsigned short* src = z ? srcB : srcA;
  float* dst = z ? dstB : dstA;
  const int ncols = z ? M2 : M1;
  const long base = (long)blockIdx.x * ncols;
  float s = 0.f;
  for (int c = threadIdx.x * 8; c < ncols; c += 2048) {
    bf16x8 v = *(const bf16x8*)(src + base + c);
    #pragma unroll
    for (int j = 0; j < 8; ++j)
      s += __uint_as_float(((unsigned)(unsigned short)v[j]) << 16);
  }
  __shared__ float red[256];
  red[threadIdx.x] = s;
  __syncthreads();
  for (int st = 128; st > 0; st >>= 1) {
    if (threadIdx.x < st) red[threadIdx.x] += red[threadIdx.x + st];
    __syncthreads();
  }
  if (threadIdx.x == 0) dst[blockIdx.x] = red[0];
}

// merged chunk-reduce + bf16 convert (f32 result is dead -> bf16 only)
__global__ __launch_bounds__(256) void reduce_conv2(
    const float* __restrict__ srcA, const float* __restrict__ srcB,
    unsigned short* __restrict__ dstA, unsigned short* __restrict__ dstB) {
  const int z = blockIdx.y;
  const float* src = z ? srcB : srcA;
  unsigned short* dstb = z ? dstB : dstA;
  const int nchunks = z ? CH2 : CH1;
  int i = blockIdx.x * 256 + threadIdx.x;
  float s = 0.f;
  for (int c = 0; c < nchunks; ++c) s += src[(long)c * 147456 + i];
  __hip_bfloat16 hv = __float2bfloat16(s);
  dstb[i] = *(unsigned short*)&hv;
}

// --------------------------- BN finalize -----------------------------------
__global__ __launch_bounds__(256) void bnfinal(
    const float* __restrict__ W, const float* __restrict__ T, const float* __restrict__ cs,
    const float* __restrict__ scale, float* __restrict__ a, float* __restrict__ b,
    int N, float invM) {
  const int j = blockIdx.x * 64 + (threadIdx.x & 63);
  const int rq = threadIdx.x >> 6;
  float yy = 0.f, mu = 0.f;
  for (int k = rq * 96; k < rq * 96 + 96; ++k) {
    float w = W[(long)k * N + j];
    yy += w * T[(long)k * N + j];
    mu += cs[k] * w;
  }
  __shared__ float r1[256], r2[256];
  r1[threadIdx.x] = yy; r2[threadIdx.x] = mu;
  __syncthreads();
  if (threadIdx.x < 64) {
    int t = threadIdx.x;
    yy = r1[t] + r1[t + 64] + r1[t + 128] + r1[t + 192];
    mu = r2[t] + r2[t + 64] + r2[t + 128] + r2[t + 192];
    float mean = mu * invM;
    float var = yy * invM - mean * mean;
    float ai = rsqrtf(var + 1e-5f) * scale[j];
    a[j] = ai;
    b[j] = -mean * ai;
  }
}

// ---------------------------------------------------------------------------
// split-K MFMA X @ X^T (unchanged)
// ---------------------------------------------------------------------------
__global__ __launch_bounds__(256) void sx_mfma(
    const unsigned short* __restrict__ X, float* __restrict__ Cpart,
    int Kfull, int Kchunk) {
  __shared__ __align__(16) char As[16384];
  __shared__ __align__(16) char Bs[16384];
  const int tid = threadIdx.x;
  const int lane = tid & 63;
  const int wv = tid >> 6;
  const int wm = (wv >> 1) * 64, wn = (wv & 1) * 64;
  const int m0 = blockIdx.y * 128, n0 = blockIdx.x * 128;
  const int cl = lane & 15, kg = lane >> 4;
  const int srow = tid >> 3;
  const int swz = ((tid & 7) * 16) ^ ((srow & 7) << 4);
  const int ldsb = wv * 1024;
  const long zbase = (long)blockIdx.z * Kchunk;

  long arow[4], brow[4];
  #pragma unroll
  for (int is = 0; is < 4; ++is) {
    arow[is] = (long)(m0 + is * 32 + srow) * Kfull + zbase;
    brow[is] = (long)(n0 + is * 32 + srow) * Kfull + zbase;
  }

  f32x4 acc[4][4];
  const f32x4 zf = {0.f, 0.f, 0.f, 0.f};
  #pragma unroll
  for (int i = 0; i < 4; ++i)
    #pragma unroll
    for (int j = 0; j < 4; ++j) acc[i][j] = zf;

  for (int k0 = 0; k0 < Kchunk; k0 += 64) {
    #pragma unroll
    for (int is = 0; is < 4; ++is) {
      gload_lds16((const char*)X + (arow[is] + k0) * 2 + swz, As + is * 4096 + ldsb);
      gload_lds16((const char*)X + (brow[is] + k0) * 2 + swz, Bs + is * 4096 + ldsb);
    }
    __syncthreads();
    bf16x8 afr[4][2], bfr[4][2];
    #pragma unroll
    for (int t = 0; t < 4; ++t) {
      const int ar = wm + t * 16 + cl;
      const int br = wn + t * 16 + cl;
      const int sa = (ar & 7) << 4, sb = (br & 7) << 4;
      afr[t][0] = *(const bf16x8*)(As + ar * 128 + ((kg * 16) ^ sa));
      afr[t][1] = *(const bf16x8*)(As + ar * 128 + ((64 + kg * 16) ^ sa));
      bfr[t][0] = *(const bf16x8*)(Bs + br * 128 + ((kg * 16) ^ sb));
      bfr[t][1] = *(const bf16x8*)(Bs + br * 128 + ((64 + kg * 16) ^ sb));
    }
    #pragma unroll
    for (int mt = 0; mt < 4; ++mt)
      #pragma unroll
      for (int nt = 0; nt < 4; ++nt) {
        acc[mt][nt] = mfma16(bfr[nt][0], afr[mt][0], acc[mt][nt]);
        acc[mt][nt] = mfma16(bfr[nt][1], afr[mt][1], acc[mt][nt]);
      }
    __syncthreads();
  }

  float* Cp = Cpart + (long)blockIdx.z * 384 * 384;
  #pragma unroll
  for (int mt = 0; mt < 4; ++mt) {
    const int gm = m0 + wm + mt * 16 + cl;
    #pragma unroll
    for (int nt = 0; nt < 4; ++nt) {
      const int gn = n0 + wn + nt * 16 + kg * 4;
      *(float4*)(Cp + (long)gm * 384 + gn) =
          make_float4(acc[mt][nt][0], acc[mt][nt][1], acc[mt][nt][2], acc[mt][nt][3]);
    }
  }
}

// ---------------------------------------------------------------------------
// bf16 MFMA GEMM: C = A[M,K] @ Bt[N,K]^T.
// SWZ: XCD chunked block remap (requires gridX*gridY % 8 == 0).
// ---------------------------------------------------------------------------
template<int AMODE, int EPI, int SWZ = 0>
__global__ __launch_bounds__(256) void gemm_mfma(
    const unsigned short* __restrict__ A, const unsigned short* __restrict__ Bt,
    void* __restrict__ Cout, const float* __restrict__ ea, const float* __restrict__ eb,
    int N, int K) {
  constexpr int SMEM_BYTES = (EPI == 2) ? 34816 : 32768;
  __shared__ __align__(16) char smem[SMEM_BYTES];
  char* As = smem;
  char* Bs = smem + 16384;
  const int tid = threadIdx.x;
  const int lane = tid & 63;
  const int wv = tid >> 6;
  const int wm = (wv >> 1) * 64, wn = (wv & 1) * 64;

  int bx = blockIdx.x, by = blockIdx.y;
  if constexpr (SWZ) {
    const int gx = gridDim.x;
    const int tot = gx * gridDim.y;
    const int lin = by * gx + bx;
    const int cpx = tot >> 3;
    const int nl = (lin & 7) * cpx + (lin >> 3);
    bx = nl % gx; by = nl / gx;
  }
  const int m0 = by * 128, n0 = bx * 128;
  const int cl = lane & 15, kg = lane >> 4;

  const int srow = tid >> 3;
  const int swz = ((tid & 7) * 16) ^ ((srow & 7) << 4);
  const int ldsb = wv * 1024;

  long arow[4], brow[4];
  #pragma unroll
  for (int is = 0; is < 4; ++is) {
    int gm = m0 + is * 32 + srow;
    long grow;
    if constexpr (AMODE == 1) {
      int bb = gm / 196, t = gm - bb * 196;
      int h2 = t / 14, w2 = t - h2 * 14;
      grow = (long)(bb * 784 + h2 * 56 + w2 * 2);
    } else {
      grow = gm;
    }
    arow[is] = grow * (long)K;
    brow[is] = (long)(n0 + is * 32 + srow) * (long)K;
  }

  f32x4 acc[4][4];
  const f32x4 zf = {0.f, 0.f, 0.f, 0.f};
  #pragma unroll
  for (int i = 0; i < 4; ++i)
    #pragma unroll
    for (int j = 0; j < 4; ++j) acc[i][j] = zf;

  for (int k0 = 0; k0 < K; k0 += 64) {
    #pragma unroll
    for (int is = 0; is < 4; ++is) {
      gload_lds16((const char*)A  + (arow[is] + k0) * 2 + swz, As + is * 4096 + ldsb);
      gload_lds16((const char*)Bt + (brow[is] + k0) * 2 + swz, Bs + is * 4096 + ldsb);
    }
    __syncthreads();
    bf16x8 afr[4][2], bfr[4][2];
    #pragma unroll
    for (int t = 0; t < 4; ++t) {
      const int ar = wm + t * 16 + cl;
      const int br = wn + t * 16 + cl;
      const int sa = (ar & 7) << 4, sb = (br & 7) << 4;
      afr[t][0] = *(const bf16x8*)(As + ar * 128 + ((kg * 16) ^ sa));
      afr[t][1] = *(const bf16x8*)(As + ar * 128 + ((64 + kg * 16) ^ sa));
      bfr[t][0] = *(const bf16x8*)(Bs + br * 128 + ((kg * 16) ^ sb));
      bfr[t][1] = *(const bf16x8*)(Bs + br * 128 + ((64 + kg * 16) ^ sb));
    }
    #pragma unroll
    for (int mt = 0; mt < 4; ++mt)
      #pragma unroll
      for (int nt = 0; nt < 4; ++nt) {
        if constexpr (EPI == 2) {
          acc[mt][nt] = mfma16(afr[mt][0], bfr[nt][0], acc[mt][nt]);
          acc[mt][nt] = mfma16(afr[mt][1], bfr[nt][1], acc[mt][nt]);
        } else {
          acc[mt][nt] = mfma16(bfr[nt][0], afr[mt][0], acc[mt][nt]);
          acc[mt][nt] = mfma16(bfr[nt][1], afr[mt][1], acc[mt][nt]);
        }
      }
    __syncthreads();
  }

  if constexpr (EPI == 2) {
    char* Cs = smem;
    #pragma unroll
    for (int mt = 0; mt < 4; ++mt) {
      const int kl = wm + mt * 16 + kg * 4;
      #pragma unroll
      for (int nt = 0; nt < 4; ++nt) {
        const int dvl = wn + nt * 16 + cl;
        const int gn = n0 + dvl;
        const float av = ea[gn], bv = eb[gn];
        union { ushort4 u; __hip_bfloat16 h[4]; } pk;
        pk.h[0] = __float2bfloat16(acc[mt][nt][0] * av + bv);
        pk.h[1] = __float2bfloat16(acc[mt][nt][1] * av + bv);
        pk.h[2] = __float2bfloat16(acc[mt][nt][2] * av + bv);
        pk.h[3] = __float2bfloat16(acc[mt][nt][3] * av + bv);
        *(ushort4*)(Cs + dvl * 272 + kl * 2) = pk.u;
      }
    }
    __syncthreads();
    const int hh = n0 >> 8;
    #pragma unroll
    for (int l = 0; l < 8; ++l) {
      const int row = l * 16 + (tid >> 4);
      const int seg = tid & 15;
      const int gm = m0 + seg * 8;
      const int bb = gm / 784, kk = gm - bb * 784;
      const int dvl = (n0 + row) & 255;
      uint4 v = *(const uint4*)(Cs + row * 272 + seg * 16);
      *(uint4*)((unsigned short*)Cout + ((long)(bb * 12 + hh) * 256 + dvl) * 784 + kk) = v;
    }
  } else {
    #pragma unroll
    for (int mt = 0; mt < 4; ++mt) {
      #pragma unroll
      for (int nt = 0; nt < 4; ++nt) {
        const int gm = m0 + wm + mt * 16 + cl;
        const int gn = n0 + wn + nt * 16 + kg * 4;
        if constexpr (EPI == 1) {
          float4 a4 = *(const float4*)(ea + gn);
          float4 b4 = *(const float4*)(eb + gn);
          union { ushort4 u; __hip_bfloat16 h[4]; } pk;
          pk.h[0] = __float2bfloat16(acc[mt][nt][0] * a4.x + b4.x);
          pk.h[1] = __float2bfloat16(acc[mt][nt][1] * a4.y + b4.y);
          pk.h[2] = __float2bfloat16(acc[mt][nt][2] * a4.z + b4.z);
          pk.h[3] = __float2bfloat16(acc[mt][nt][3] * a4.w + b4.w);
          *(ushort4*)((unsigned short*)Cout + (long)gm * N + gn) = pk.u;
        } else {
          *(float4*)((float*)Cout + (long)gm * N + gn) =
              make_float4(acc[mt][nt][0], acc[mt][nt][1], acc[mt][nt][2], acc[mt][nt][3]);
        }
      }
    }
  }
}

// ---------------------------------------------------------------------------
// Single-pass MFMA flash attention (round-9 structure) + XCD chunk swizzle:
// both q-tiles of a (b,h) land in the same XCD chunk -> K/V shared in L2.
// ---------------------------------------------------------------------------
__global__ __launch_bounds__(512, 4) void attn_mfma(
    const unsigned short* __restrict__ kbuf, const unsigned short* __restrict__ vt,
    const unsigned short* __restrict__ qn, const float* __restrict__ bias,
    unsigned short* __restrict__ O) {
  // chunked XCD remap: p -> wrk = (p&7)*96 + (p>>3); qt fastest, then h, b
  const int p = blockIdx.x + 2 * (blockIdx.y + 12 * blockIdx.z);
  const int wrk = ((p & 7) * 96) + (p >> 3);
  const int qt = wrk & 1;
  const int hb = wrk >> 1;
  const int h = hb % 12, b = hb / 12;

  const int tid = threadIdx.x;
  const int w = tid >> 6;
  const int lane = tid & 63;
  const int cl = lane & 15;
  const int kg = lane >> 4;
  const int kb = kg * 8;
  const int qbase = qt * 112;
  const int valid = 196 - qbase > 112 ? 112 : 196 - qbase;
  const int bh = b * 12 + h;

  __shared__ __align__(16) short Qs[112][72];
  __shared__ __align__(16) char Kl[2][8192];
  __shared__ __align__(16) short pPs[112][72];
  __shared__ float pred[4][112];
  __shared__ float lsum[112];

  const bf16x8 zero8 = {0,0,0,0,0,0,0,0};
  const f32x4 zerof = {0.f,0.f,0.f,0.f};

  const int srow = tid >> 3;
  const int ssw = ((tid & 7) * 16) ^ ((srow & 7) << 4);
  const long kbase = ((long)(b * 784 + srow) * 768 + h * 64) * 2 + ssw;

  for (int f = tid; f < 896; f += 512) {
    int row = f >> 3, d8 = f & 7;
    bf16x8 v = zero8;
    if (row < valid)
      v = *(const bf16x8*)(qn + (long)(b * 196 + qbase + row) * 768 + h * 64 + d8 * 8);
    *(bf16x8*)&Qs[row][d8 * 8] = v;
  }
  gload_lds16((const char*)kbuf + kbase, Kl[0] + w * 1024);
  __syncthreads();

  const int mt0 = w >> 2, snt = w & 3;
  const long vr0 = ((long)bh * 256 + w * 32 + cl) * 784;
  const long vr1 = vr0 + (long)16 * 784;

  f32x4 acc[7][2];
  #pragma unroll
  for (int mt = 0; mt < 7; ++mt) { acc[mt][0] = zerof; acc[mt][1] = zerof; }
  float lpart[4] = {0.f, 0.f, 0.f, 0.f};

  const int krow = snt * 16 + cl;
  const int ksw = (krow & 7) << 4;

  for (int kt = 0; kt < 13; ++kt) {
    const int k0 = kt * 64;
    const int cur = kt & 1;
    bf16x8 vf00, vf01, vf10, vf11;
    vf00 = *(const bf16x8*)(vt + vr0 + k0 + kb);
    vf10 = *(const bf16x8*)(vt + vr0 + k0 + 32 + kb);
    vf01 = *(const bf16x8*)(vt + vr1 + k0 + kb);
    vf11 = *(const bf16x8*)(vt + vr1 + k0 + 32 + kb);
    if (kt < 12)
      gload_lds16((const char*)kbuf + kbase + (long)(k0 + 64) * 1536,
                  Kl[cur ^ 1] + w * 1024);
    const char* kr = Kl[cur] + krow * 128;
    bf16x8 kk0 = *(const bf16x8*)(kr + ((kg * 16) ^ ksw));
    bf16x8 kk1 = *(const bf16x8*)(kr + ((64 + kg * 16) ^ ksw));
    #pragma unroll
    for (int i = 0; i < 4; ++i) {
      int mt = mt0 + 2 * i;
      if (mt >= 7) break;
      bf16x8 q0 = *(const bf16x8*)&Qs[mt * 16 + cl][kb];
      bf16x8 q1 = *(const bf16x8*)&Qs[mt * 16 + cl][32 + kb];
      f32x4 s = mfma16(kk1, q1, mfma16(kk0, q0, zerof));
      const int rowl = mt * 16 + cl;
      const int key0 = k0 + snt * 16 + kg * 4;
      const bool ok = (rowl < valid) && (key0 < 784);
      float4 b4 = make_float4(0.f, 0.f, 0.f, 0.f);
      if (ok) b4 = *(const float4*)(bias + (long)(qbase + rowl) * 784 + key0);
      float p0 = ok ? __expf(s[0] * 0.125f + b4.x) : 0.f;
      float p1 = ok ? __expf(s[1] * 0.125f + b4.y) : 0.f;
      float p2 = ok ? __expf(s[2] * 0.125f + b4.z) : 0.f;
      float p3 = ok ? __expf(s[3] * 0.125f + b4.w) : 0.f;
      lpart[i] += (p0 + p1) + (p2 + p3);
      union { ushort4 u; __hip_bfloat16 hh[4]; } pk;
      pk.hh[0] = __float2bfloat16(p0);
      pk.hh[1] = __float2bfloat16(p1);
      pk.hh[2] = __float2bfloat16(p2);
      pk.hh[3] = __float2bfloat16(p3);
      *(ushort4*)&pPs[rowl][snt * 16 + kg * 4] = pk.u;
    }
    __syncthreads();
    #pragma unroll
    for (int mt = 0; mt < 7; ++mt) {
      bf16x8 pa0 = *(const bf16x8*)&pPs[mt * 16 + cl][kb];
      bf16x8 pa1 = *(const bf16x8*)&pPs[mt * 16 + cl][32 + kb];
      acc[mt][0] = mfma16(pa0, vf00, acc[mt][0]);
      acc[mt][0] = mfma16(pa1, vf10, acc[mt][0]);
      acc[mt][1] = mfma16(pa0, vf01, acc[mt][1]);
      acc[mt][1] = mfma16(pa1, vf11, acc[mt][1]);
    }
    __syncthreads();
  }

  #pragma unroll
  for (int i = 0; i < 4; ++i) {
    int mt = mt0 + 2 * i;
    if (mt >= 7) break;
    float v = lpart[i];
    v += __shfl_xor(v, 16);
    v += __shfl_xor(v, 32);
    if (kg == 0) pred[snt][mt * 16 + cl] = v;
  }
  __syncthreads();
  if (tid < 112)
    lsum[tid] = (pred[0][tid] + pred[1][tid]) + (pred[2][tid] + pred[3][tid]);
  __syncthreads();

  #pragma unroll
  for (int mt = 0; mt < 7; ++mt) {
    #pragma unroll
    for (int r = 0; r < 4; ++r) {
      const int rl = mt * 16 + kg * 4 + r;
      if (rl < valid) {
        const float inv = 1.0f / lsum[rl];
        #pragma unroll
        for (int nt2 = 0; nt2 < 2; ++nt2) {
          float ov = hswish(acc[mt][nt2][r] * inv);
          __hip_bfloat16 hv = __float2bfloat16(ov);
          O[(long)(b * 196 + qbase + rl) * 3072 + h * 256 + w * 32 + nt2 * 16 + cl] =
              *(unsigned short*)&hv;
        }
      }
    }
  }
}

// ---------------------------------------------------------------------------
extern "C" void kernel_launch(void* const* d_in, const int* in_sizes, int n_in,
                              void* d_out, int out_size, void* d_ws, size_t ws_size,
                              hipStream_t stream) {
  if (ws_size < WS_TOTAL) return;

  const float* x    = (const float*)d_in[0];
  const float* Wqkv = (const float*)d_in[1];
  const float* bn1s = (const float*)d_in[2];
  const float* Wq   = (const float*)d_in[3];
  const float* bn2s = (const float*)d_in[4];
  const float* bias = (const float*)d_in[5];
  const float* Wout = (const float*)d_in[6];

  char* ws = (char*)d_ws;
  unsigned short* kb   = (unsigned short*)(ws + OFF_K);
  unsigned short* xbT  = (unsigned short*)(ws + OFF_XBT);
  unsigned short* xqT  = (unsigned short*)(ws + OFF_XQT);
  float* t1            = (float*)(ws + OFF_T1);
  float* t2            = (float*)(ws + OFF_T2);
  unsigned short* sxb1 = (unsigned short*)(ws + OFF_SXB1);
  unsigned short* sxb2 = (unsigned short*)(ws + OFF_SXB2);
  unsigned short* vtb  = (unsigned short*)(ws + OFF_VT);
  unsigned short* qnb  = (unsigned short*)(ws + OFF_QN);
  unsigned short* xb   = (unsigned short*)(ws + OFF_XB);
  unsigned short* Ob   = (unsigned short*)(ws + OFF_O);
  unsigned short* wqkvt= (unsigned short*)(ws + OFF_WQKVT);
  unsigned short* wqt  = (unsigned short*)(ws + OFF_WQT);
  unsigned short* woutt= (unsigned short*)(ws + OFF_WOUTT);
  float* ps1  = (float*)(ws + OFF_PS1);
  float* ps2  = (float*)(ws + OFF_PS2);
  float* cs1  = (float*)(ws + OFF_CS1);
  float* cs2  = (float*)(ws + OFF_CS2);
  float* a1w  = (float*)(ws + OFF_A1);
  float* b1w  = (float*)(ws + OFF_B1);
  float* a2w  = (float*)(ws + OFF_A2);
  float* b2w  = (float*)(ws + OFF_B2);
  float* out  = (float*)d_out;

  // prep: bf16 copies / transposes of x
  convert_bf16<<<dim3(4704), 256, 0, stream>>>(x, xb, (long)M1 * Kc / 8);
  transpose_bf16<<<dim3(12, 784), 256, 0, stream>>>(x, xbT, M1, Kc);
  transpose_gather_bf16<<<dim3(12, 196), 256, 0, stream>>>(x, xqT);
  rowsum2_bf16<<<dim3(384, 2), 256, 0, stream>>>(xbT, xqT, cs1, cs2);

  // Sx via split-K MFMA (+fused f32->bf16 convert)
  sx_mfma<<<dim3(3, 3, CH1), 256, 0, stream>>>(xbT, ps1, M1, M1 / CH1);
  sx_mfma<<<dim3(3, 3, CH2), 256, 0, stream>>>(xqT, ps2, M2, M2 / CH2);
  reduce_conv2<<<dim3(576, 2), 256, 0, stream>>>(ps1, ps2, sxb1, sxb2);

  // weight transposes (overwrite ps1 region - dead after reduce)
  transpose_bf16<<<dim3(120, 12), 256, 0, stream>>>(Wqkv, wqkvt, Kc, N1);
  transpose_bf16<<<dim3(24, 12),  256, 0, stream>>>(Wq,   wqt,   Kc, Dq);
  transpose_bf16<<<dim3(16, 96),  256, 0, stream>>>(Wout, woutt, 4 * Dq, OUTD);

  // BN coefficients: T = Sx @ W via MFMA, then column reduce
  gemm_mfma<0, 0><<<dim3(30, 3), 256, 0, stream>>>(sxb1, wqkvt, t1, nullptr, nullptr, N1, Kc);
  gemm_mfma<0, 0><<<dim3(6, 3),  256, 0, stream>>>(sxb2, wqt,   t2, nullptr, nullptr, Dq, Kc);
  bnfinal<<<dim3(60), 256, 0, stream>>>(Wqkv, t1, cs1, bn1s, a1w, b1w, N1, 1.f / (float)M1);
  bnfinal<<<dim3(12), 256, 0, stream>>>(Wq,   t2, cs2, bn2s, a2w, b2w, Dq, 1.f / (float)M2);

  // projections (K and V gemms XCD-swizzled: grids 1176 / 4704, both % 8 == 0)
  gemm_mfma<0, 1, 1><<<dim3(6, 196), 256, 0, stream>>>(xb, wqkvt, kb, a1w, b1w, 768, Kc);
  gemm_mfma<0, 2, 1><<<dim3(24, 196), 256, 0, stream>>>(
      xb, wqkvt + (long)768 * Kc, vtb, a1w + 768, b1w + 768, 3072, Kc);
  gemm_mfma<1, 1><<<dim3(6, 49), 256, 0, stream>>>(xb, wqt, qnb, a2w, b2w, Dq, Kc);

  // attention -> hswish(O)
  attn_mfma<<<dim3(2, 12, 32), 512, 0, stream>>>(kb, vtb, qnb, bias, Ob);

  // out = O @ Wout^T
  gemm_mfma<0, 0><<<dim3(4, 49), 256, 0, stream>>>(Ob, woutt, out, nullptr, nullptr, OUTD, 4 * Dq);
}

// Round 12
// 475.158 us; speedup vs baseline: 1.2096x; 1.0250x over previous
//
#include <hip/hip_runtime.h>
#include <hip/hip_bf16.h>

// ---------------------------------------------------------------------------
// LeViT subsample attention (round 11).
//   = round 10 with:
//   (a) attn_mfma: q-tile 112 -> 64 rows; LDS 51.2 -> 36.1 KB -> 4 blocks/CU
//       (32 waves/CU); acc 56 -> 32 VGPR; grid (4,12,32) chunk-swizzled
//   (b) prep_x: fused x->bf16 convert + transpose (reads x once)
// ---------------------------------------------------------------------------

static constexpr int M1 = 25088, N1 = 3840, Kc = 384;
static constexpr int M2 = 6272, Dq = 768, OUTD = 512;
static constexpr int CH1 = 14, CH2 = 7;

static constexpr size_t OFF_K    = 0;
static constexpr size_t OFF_XBT  = 0;
static constexpr size_t OFF_XQT  = 19267584;
static constexpr size_t OFF_T1   = 24084480;
static constexpr size_t OFF_T2   = 29982720;
static constexpr size_t OFF_SXB1 = 31162368;
static constexpr size_t OFF_SXB2 = 31457280;
static constexpr size_t OFF_VT   = 38535168;
static constexpr size_t OFF_QN   = 192675840;
static constexpr size_t OFF_O    = 202309632;
static constexpr size_t OFF_XB   = OFF_O;
static constexpr size_t OFF_PS1  = 240844800;
static constexpr size_t OFF_WQKVT= 240844800;
static constexpr size_t OFF_WQT  = 243793920;
static constexpr size_t OFF_WOUTT= 244383744;
static constexpr size_t OFF_PS2  = 249123840;
static constexpr size_t OFF_CS1  = 253853184;
static constexpr size_t OFF_CS2  = 254444544;
static constexpr size_t OFF_A1   = 254446080;
static constexpr size_t OFF_B1   = 254461440;
static constexpr size_t OFF_A2   = 254476800;
static constexpr size_t OFF_B2   = 254479872;
static constexpr size_t WS_TOTAL = 254482944;

typedef __attribute__((ext_vector_type(8))) short bf16x8;
typedef __attribute__((ext_vector_type(4))) float f32x4;

static __device__ __forceinline__ f32x4 mfma16(bf16x8 a, bf16x8 b, f32x4 c) {
  return __builtin_amdgcn_mfma_f32_16x16x32_bf16(a, b, c, 0, 0, 0);
}

__device__ __forceinline__ void gload_lds16(const void* g, void* l) {
  __builtin_amdgcn_global_load_lds(
      (const __attribute__((address_space(1))) unsigned int*)g,
      (__attribute__((address_space(3))) unsigned int*)l, 16, 0, 0);
}

__device__ __forceinline__ float hswish(float x) {
  float t = fminf(fmaxf(x + 3.0f, 0.0f), 6.0f);
  return x * t * (1.0f / 6.0f);
}

// --------------------------- prep kernels ----------------------------------
// fused: xb (bf16 row-major copy) + xbT (bf16 transpose), reads x once.
__global__ __launch_bounds__(256) void prep_x(
    const float* __restrict__ in, unsigned short* __restrict__ xb,
    unsigned short* __restrict__ xbT) {
  __shared__ float t[32][33];
  const int c0 = blockIdx.x * 32, r0 = blockIdx.y * 32;
  const int x = threadIdx.x & 31, y = threadIdx.x >> 5;
  #pragma unroll
  for (int i = y; i < 32; i += 8) {
    float v = in[(long)(r0 + i) * 384 + c0 + x];
    t[i][x] = v;
    __hip_bfloat16 hv = __float2bfloat16(v);
    xb[(long)(r0 + i) * 384 + c0 + x] = *(unsigned short*)&hv;
  }
  __syncthreads();
  #pragma unroll
  for (int i = y; i < 32; i += 8) {
    __hip_bfloat16 v = __float2bfloat16(t[x][i]);
    xbT[(long)(c0 + i) * 25088 + r0 + x] = *(unsigned short*)&v;
  }
}

__global__ __launch_bounds__(256) void transpose_bf16(
    const float* __restrict__ in, unsigned short* __restrict__ out, int R, int C) {
  __shared__ float t[32][33];
  const int c0 = blockIdx.x * 32, r0 = blockIdx.y * 32;
  const int x = threadIdx.x & 31, y = threadIdx.x >> 5;
  #pragma unroll
  for (int i = y; i < 32; i += 8) t[i][x] = in[(long)(r0 + i) * C + c0 + x];
  __syncthreads();
  #pragma unroll
  for (int i = y; i < 32; i += 8) {
    __hip_bfloat16 v = __float2bfloat16(t[x][i]);
    out[(long)(c0 + i) * R + r0 + x] = *(unsigned short*)&v;
  }
}

__global__ __launch_bounds__(256) void transpose_gather_bf16(
    const float* __restrict__ in, unsigned short* __restrict__ out) {
  __shared__ float t[32][33];
  const int c0 = blockIdx.x * 32, r0 = blockIdx.y * 32;
  const int x = threadIdx.x & 31, y = threadIdx.x >> 5;
  #pragma unroll
  for (int i = y; i < 32; i += 8) {
    int m2 = r0 + i;
    int bb = m2 / 196, tt = m2 - bb * 196;
    int h2 = tt / 14, w2 = tt - h2 * 14;
    long grow = (long)(bb * 784 + h2 * 56 + w2 * 2);
    t[i][x] = in[grow * 384 + c0 + x];
  }
  __syncthreads();
  #pragma unroll
  for (int i = y; i < 32; i += 8) {
    __hip_bfloat16 v = __float2bfloat16(t[x][i]);
    out[(long)(c0 + i) * 6272 + r0 + x] = *(unsigned short*)&v;
  }
}

// merged per-row sums: z=0 -> (srcA, M1) -> dstA ; z=1 -> (srcB, M2) -> dstB
__global__ __launch_bounds__(256) void rowsum2_bf16(
    const unsigned short* __restrict__ srcA, const unsigned short* __restrict__ srcB,
    float* __restrict__ dstA, float* __restrict__ dstB) {
  const int z = blockIdx.y;
  const unsigned short* src = z ? srcB : srcA;
  float* dst = z ? dstB : dstA;
  const int ncols = z ? M2 : M1;
  const long base = (long)blockIdx.x * ncols;
  float s = 0.f;
  for (int c = threadIdx.x * 8; c < ncols; c += 2048) {
    bf16x8 v = *(const bf16x8*)(src + base + c);
    #pragma unroll
    for (int j = 0; j < 8; ++j)
      s += __uint_as_float(((unsigned)(unsigned short)v[j]) << 16);
  }
  __shared__ float red[256];
  red[threadIdx.x] = s;
  __syncthreads();
  for (int st = 128; st > 0; st >>= 1) {
    if (threadIdx.x < st) red[threadIdx.x] += red[threadIdx.x + st];
    __syncthreads();
  }
  if (threadIdx.x == 0) dst[blockIdx.x] = red[0];
}

// merged chunk-reduce + bf16 convert
__global__ __launch_bounds__(256) void reduce_conv2(
    const float* __restrict__ srcA, const float* __restrict__ srcB,
    unsigned short* __restrict__ dstA, unsigned short* __restrict__ dstB) {
  const int z = blockIdx.y;
  const float* src = z ? srcB : srcA;
  unsigned short* dstb = z ? dstB : dstA;
  const int nchunks = z ? CH2 : CH1;
  int i = blockIdx.x * 256 + threadIdx.x;
  float s = 0.f;
  for (int c = 0; c < nchunks; ++c) s += src[(long)c * 147456 + i];
  __hip_bfloat16 hv = __float2bfloat16(s);
  dstb[i] = *(unsigned short*)&hv;
}

// --------------------------- BN finalize -----------------------------------
__global__ __launch_bounds__(256) void bnfinal(
    const float* __restrict__ W, const float* __restrict__ T, const float* __restrict__ cs,
    const float* __restrict__ scale, float* __restrict__ a, float* __restrict__ b,
    int N, float invM) {
  const int j = blockIdx.x * 64 + (threadIdx.x & 63);
  const int rq = threadIdx.x >> 6;
  float yy = 0.f, mu = 0.f;
  for (int k = rq * 96; k < rq * 96 + 96; ++k) {
    float w = W[(long)k * N + j];
    yy += w * T[(long)k * N + j];
    mu += cs[k] * w;
  }
  __shared__ float r1[256], r2[256];
  r1[threadIdx.x] = yy; r2[threadIdx.x] = mu;
  __syncthreads();
  if (threadIdx.x < 64) {
    int t = threadIdx.x;
    yy = r1[t] + r1[t + 64] + r1[t + 128] + r1[t + 192];
    mu = r2[t] + r2[t + 64] + r2[t + 128] + r2[t + 192];
    float mean = mu * invM;
    float var = yy * invM - mean * mean;
    float ai = rsqrtf(var + 1e-5f) * scale[j];
    a[j] = ai;
    b[j] = -mean * ai;
  }
}

// ---------------------------------------------------------------------------
// split-K MFMA X @ X^T (unchanged)
// ---------------------------------------------------------------------------
__global__ __launch_bounds__(256) void sx_mfma(
    const unsigned short* __restrict__ X, float* __restrict__ Cpart,
    int Kfull, int Kchunk) {
  __shared__ __align__(16) char As[16384];
  __shared__ __align__(16) char Bs[16384];
  const int tid = threadIdx.x;
  const int lane = tid & 63;
  const int wv = tid >> 6;
  const int wm = (wv >> 1) * 64, wn = (wv & 1) * 64;
  const int m0 = blockIdx.y * 128, n0 = blockIdx.x * 128;
  const int cl = lane & 15, kg = lane >> 4;
  const int srow = tid >> 3;
  const int swz = ((tid & 7) * 16) ^ ((srow & 7) << 4);
  const int ldsb = wv * 1024;
  const long zbase = (long)blockIdx.z * Kchunk;

  long arow[4], brow[4];
  #pragma unroll
  for (int is = 0; is < 4; ++is) {
    arow[is] = (long)(m0 + is * 32 + srow) * Kfull + zbase;
    brow[is] = (long)(n0 + is * 32 + srow) * Kfull + zbase;
  }

  f32x4 acc[4][4];
  const f32x4 zf = {0.f, 0.f, 0.f, 0.f};
  #pragma unroll
  for (int i = 0; i < 4; ++i)
    #pragma unroll
    for (int j = 0; j < 4; ++j) acc[i][j] = zf;

  for (int k0 = 0; k0 < Kchunk; k0 += 64) {
    #pragma unroll
    for (int is = 0; is < 4; ++is) {
      gload_lds16((const char*)X + (arow[is] + k0) * 2 + swz, As + is * 4096 + ldsb);
      gload_lds16((const char*)X + (brow[is] + k0) * 2 + swz, Bs + is * 4096 + ldsb);
    }
    __syncthreads();
    bf16x8 afr[4][2], bfr[4][2];
    #pragma unroll
    for (int t = 0; t < 4; ++t) {
      const int ar = wm + t * 16 + cl;
      const int br = wn + t * 16 + cl;
      const int sa = (ar & 7) << 4, sb = (br & 7) << 4;
      afr[t][0] = *(const bf16x8*)(As + ar * 128 + ((kg * 16) ^ sa));
      afr[t][1] = *(const bf16x8*)(As + ar * 128 + ((64 + kg * 16) ^ sa));
      bfr[t][0] = *(const bf16x8*)(Bs + br * 128 + ((kg * 16) ^ sb));
      bfr[t][1] = *(const bf16x8*)(Bs + br * 128 + ((64 + kg * 16) ^ sb));
    }
    #pragma unroll
    for (int mt = 0; mt < 4; ++mt)
      #pragma unroll
      for (int nt = 0; nt < 4; ++nt) {
        acc[mt][nt] = mfma16(bfr[nt][0], afr[mt][0], acc[mt][nt]);
        acc[mt][nt] = mfma16(bfr[nt][1], afr[mt][1], acc[mt][nt]);
      }
    __syncthreads();
  }

  float* Cp = Cpart + (long)blockIdx.z * 384 * 384;
  #pragma unroll
  for (int mt = 0; mt < 4; ++mt) {
    const int gm = m0 + wm + mt * 16 + cl;
    #pragma unroll
    for (int nt = 0; nt < 4; ++nt) {
      const int gn = n0 + wn + nt * 16 + kg * 4;
      *(float4*)(Cp + (long)gm * 384 + gn) =
          make_float4(acc[mt][nt][0], acc[mt][nt][1], acc[mt][nt][2], acc[mt][nt][3]);
    }
  }
}

// ---------------------------------------------------------------------------
// bf16 MFMA GEMM: C = A[M,K] @ Bt[N,K]^T.  SWZ: XCD chunked remap.
// ---------------------------------------------------------------------------
template<int AMODE, int EPI, int SWZ = 0>
__global__ __launch_bounds__(256) void gemm_mfma(
    const unsigned short* __restrict__ A, const unsigned short* __restrict__ Bt,
    void* __restrict__ Cout, const float* __restrict__ ea, const float* __restrict__ eb,
    int N, int K) {
  constexpr int SMEM_BYTES = (EPI == 2) ? 34816 : 32768;
  __shared__ __align__(16) char smem[SMEM_BYTES];
  char* As = smem;
  char* Bs = smem + 16384;
  const int tid = threadIdx.x;
  const int lane = tid & 63;
  const int wv = tid >> 6;
  const int wm = (wv >> 1) * 64, wn = (wv & 1) * 64;

  int bx = blockIdx.x, by = blockIdx.y;
  if constexpr (SWZ) {
    const int gx = gridDim.x;
    const int tot = gx * gridDim.y;
    const int lin = by * gx + bx;
    const int cpx = tot >> 3;
    const int nl = (lin & 7) * cpx + (lin >> 3);
    bx = nl % gx; by = nl / gx;
  }
  const int m0 = by * 128, n0 = bx * 128;
  const int cl = lane & 15, kg = lane >> 4;

  const int srow = tid >> 3;
  const int swz = ((tid & 7) * 16) ^ ((srow & 7) << 4);
  const int ldsb = wv * 1024;

  long arow[4], brow[4];
  #pragma unroll
  for (int is = 0; is < 4; ++is) {
    int gm = m0 + is * 32 + srow;
    long grow;
    if constexpr (AMODE == 1) {
      int bb = gm / 196, t = gm - bb * 196;
      int h2 = t / 14, w2 = t - h2 * 14;
      grow = (long)(bb * 784 + h2 * 56 + w2 * 2);
    } else {
      grow = gm;
    }
    arow[is] = grow * (long)K;
    brow[is] = (long)(n0 + is * 32 + srow) * (long)K;
  }

  f32x4 acc[4][4];
  const f32x4 zf = {0.f, 0.f, 0.f, 0.f};
  #pragma unroll
  for (int i = 0; i < 4; ++i)
    #pragma unroll
    for (int j = 0; j < 4; ++j) acc[i][j] = zf;

  for (int k0 = 0; k0 < K; k0 += 64) {
    #pragma unroll
    for (int is = 0; is < 4; ++is) {
      gload_lds16((const char*)A  + (arow[is] + k0) * 2 + swz, As + is * 4096 + ldsb);
      gload_lds16((const char*)Bt + (brow[is] + k0) * 2 + swz, Bs + is * 4096 + ldsb);
    }
    __syncthreads();
    bf16x8 afr[4][2], bfr[4][2];
    #pragma unroll
    for (int t = 0; t < 4; ++t) {
      const int ar = wm + t * 16 + cl;
      const int br = wn + t * 16 + cl;
      const int sa = (ar & 7) << 4, sb = (br & 7) << 4;
      afr[t][0] = *(const bf16x8*)(As + ar * 128 + ((kg * 16) ^ sa));
      afr[t][1] = *(const bf16x8*)(As + ar * 128 + ((64 + kg * 16) ^ sa));
      bfr[t][0] = *(const bf16x8*)(Bs + br * 128 + ((kg * 16) ^ sb));
      bfr[t][1] = *(const bf16x8*)(Bs + br * 128 + ((64 + kg * 16) ^ sb));
    }
    #pragma unroll
    for (int mt = 0; mt < 4; ++mt)
      #pragma unroll
      for (int nt = 0; nt < 4; ++nt) {
        if constexpr (EPI == 2) {
          acc[mt][nt] = mfma16(afr[mt][0], bfr[nt][0], acc[mt][nt]);
          acc[mt][nt] = mfma16(afr[mt][1], bfr[nt][1], acc[mt][nt]);
        } else {
          acc[mt][nt] = mfma16(bfr[nt][0], afr[mt][0], acc[mt][nt]);
          acc[mt][nt] = mfma16(bfr[nt][1], afr[mt][1], acc[mt][nt]);
        }
      }
    __syncthreads();
  }

  if constexpr (EPI == 2) {
    char* Cs = smem;
    #pragma unroll
    for (int mt = 0; mt < 4; ++mt) {
      const int kl = wm + mt * 16 + kg * 4;
      #pragma unroll
      for (int nt = 0; nt < 4; ++nt) {
        const int dvl = wn + nt * 16 + cl;
        const int gn = n0 + dvl;
        const float av = ea[gn], bv = eb[gn];
        union { ushort4 u; __hip_bfloat16 h[4]; } pk;
        pk.h[0] = __float2bfloat16(acc[mt][nt][0] * av + bv);
        pk.h[1] = __float2bfloat16(acc[mt][nt][1] * av + bv);
        pk.h[2] = __float2bfloat16(acc[mt][nt][2] * av + bv);
        pk.h[3] = __float2bfloat16(acc[mt][nt][3] * av + bv);
        *(ushort4*)(Cs + dvl * 272 + kl * 2) = pk.u;
      }
    }
    __syncthreads();
    const int hh = n0 >> 8;
    #pragma unroll
    for (int l = 0; l < 8; ++l) {
      const int row = l * 16 + (tid >> 4);
      const int seg = tid & 15;
      const int gm = m0 + seg * 8;
      const int bb = gm / 784, kk = gm - bb * 784;
      const int dvl = (n0 + row) & 255;
      uint4 v = *(const uint4*)(Cs + row * 272 + seg * 16);
      *(uint4*)((unsigned short*)Cout + ((long)(bb * 12 + hh) * 256 + dvl) * 784 + kk) = v;
    }
  } else {
    #pragma unroll
    for (int mt = 0; mt < 4; ++mt) {
      #pragma unroll
      for (int nt = 0; nt < 4; ++nt) {
        const int gm = m0 + wm + mt * 16 + cl;
        const int gn = n0 + wn + nt * 16 + kg * 4;
        if constexpr (EPI == 1) {
          float4 a4 = *(const float4*)(ea + gn);
          float4 b4 = *(const float4*)(eb + gn);
          union { ushort4 u; __hip_bfloat16 h[4]; } pk;
          pk.h[0] = __float2bfloat16(acc[mt][nt][0] * a4.x + b4.x);
          pk.h[1] = __float2bfloat16(acc[mt][nt][1] * a4.y + b4.y);
          pk.h[2] = __float2bfloat16(acc[mt][nt][2] * a4.z + b4.z);
          pk.h[3] = __float2bfloat16(acc[mt][nt][3] * a4.w + b4.w);
          *(ushort4*)((unsigned short*)Cout + (long)gm * N + gn) = pk.u;
        } else {
          *(float4*)((float*)Cout + (long)gm * N + gn) =
              make_float4(acc[mt][nt][0], acc[mt][nt][1], acc[mt][nt][2], acc[mt][nt][3]);
        }
      }
    }
  }
}

// ---------------------------------------------------------------------------
// Single-pass MFMA flash attention. q-tile = 64 rows (4 tiles per (b,h)),
// LDS 36.1 KB -> 4 blocks/CU. Chunked XCD remap keeps the 4 q-tiles of a
// (b,h) on one XCD -> K/V L2-shared. K via global_load_lds (swizzled source).
// ---------------------------------------------------------------------------
__global__ __launch_bounds__(512, 4) void attn_mfma(
    const unsigned short* __restrict__ kbuf, const unsigned short* __restrict__ vt,
    const unsigned short* __restrict__ qn, const float* __restrict__ bias,
    unsigned short* __restrict__ O) {
  // grid (4,12,32) = 1536 blocks; chunk remap: 4 q-tiles of a bh adjacent
  const int p = blockIdx.x + 4 * (blockIdx.y + 12 * blockIdx.z);
  const int wrk = ((p & 7) * 192) + (p >> 3);
  const int qt = wrk & 3;
  const int hb = wrk >> 2;
  const int h = hb % 12, b = hb / 12;

  const int tid = threadIdx.x;
  const int w = tid >> 6;
  const int lane = tid & 63;
  const int cl = lane & 15;
  const int kg = lane >> 4;
  const int kb = kg * 8;
  const int qbase = qt * 64;
  const int valid = (196 - qbase) > 64 ? 64 : (196 - qbase);   // 64,64,64,4
  const int nmt = (valid + 15) >> 4;                           // 4 or 1
  const int bh = b * 12 + h;

  __shared__ __align__(16) short Qs[64][72];
  __shared__ __align__(16) char Kl[2][8192];
  __shared__ __align__(16) short pPs[64][72];
  __shared__ float pred[4][64];
  __shared__ float lsum[64];

  const bf16x8 zero8 = {0,0,0,0,0,0,0,0};
  const f32x4 zerof = {0.f,0.f,0.f,0.f};

  const int srow = tid >> 3;
  const int ssw = ((tid & 7) * 16) ^ ((srow & 7) << 4);
  const long kbase = ((long)(b * 784 + srow) * 768 + h * 64) * 2 + ssw;

  // stage Q: 512 threads cover 64 rows x 8 segments exactly
  {
    int row = tid >> 3, d8 = tid & 7;
    bf16x8 v = zero8;
    if (row < valid)
      v = *(const bf16x8*)(qn + (long)(b * 196 + qbase + row) * 768 + h * 64 + d8 * 8);
    *(bf16x8*)&Qs[row][d8 * 8] = v;
  }
  gload_lds16((const char*)kbuf + kbase, Kl[0] + w * 1024);
  __syncthreads();

  const int mt0 = w >> 2, snt = w & 3;
  const long vr0 = ((long)bh * 256 + w * 32 + cl) * 784;
  const long vr1 = vr0 + (long)16 * 784;

  f32x4 acc[4][2];
  #pragma unroll
  for (int mt = 0; mt < 4; ++mt) { acc[mt][0] = zerof; acc[mt][1] = zerof; }
  float lpart[2] = {0.f, 0.f};

  const int krow = snt * 16 + cl;
  const int ksw = (krow & 7) << 4;

  for (int kt = 0; kt < 13; ++kt) {
    const int k0 = kt * 64;
    const int cur = kt & 1;
    bf16x8 vf00, vf01, vf10, vf11;
    vf00 = *(const bf16x8*)(vt + vr0 + k0 + kb);
    vf10 = *(const bf16x8*)(vt + vr0 + k0 + 32 + kb);
    vf01 = *(const bf16x8*)(vt + vr1 + k0 + kb);
    vf11 = *(const bf16x8*)(vt + vr1 + k0 + 32 + kb);
    if (kt < 12)
      gload_lds16((const char*)kbuf + kbase + (long)(k0 + 64) * 1536,
                  Kl[cur ^ 1] + w * 1024);
    const char* kr = Kl[cur] + krow * 128;
    bf16x8 kk0 = *(const bf16x8*)(kr + ((kg * 16) ^ ksw));
    bf16x8 kk1 = *(const bf16x8*)(kr + ((64 + kg * 16) ^ ksw));
    #pragma unroll
    for (int i = 0; i < 2; ++i) {
      int mt = mt0 + 2 * i;
      if (mt >= nmt) break;
      bf16x8 q0 = *(const bf16x8*)&Qs[mt * 16 + cl][kb];
      bf16x8 q1 = *(const bf16x8*)&Qs[mt * 16 + cl][32 + kb];
      f32x4 s = mfma16(kk1, q1, mfma16(kk0, q0, zerof));
      const int rowl = mt * 16 + cl;
      const int key0 = k0 + snt * 16 + kg * 4;
      const bool ok = (rowl < valid) && (key0 < 784);
      float4 b4 = make_float4(0.f, 0.f, 0.f, 0.f);
      if (ok) b4 = *(const float4*)(bias + (long)(qbase + rowl) * 784 + key0);
      float p0 = ok ? __expf(s[0] * 0.125f + b4.x) : 0.f;
      float p1 = ok ? __expf(s[1] * 0.125f + b4.y) : 0.f;
      float p2 = ok ? __expf(s[2] * 0.125f + b4.z) : 0.f;
      float p3 = ok ? __expf(s[3] * 0.125f + b4.w) : 0.f;
      lpart[i] += (p0 + p1) + (p2 + p3);
      union { ushort4 u; __hip_bfloat16 hh[4]; } pk;
      pk.hh[0] = __float2bfloat16(p0);
      pk.hh[1] = __float2bfloat16(p1);
      pk.hh[2] = __float2bfloat16(p2);
      pk.hh[3] = __float2bfloat16(p3);
      *(ushort4*)&pPs[rowl][snt * 16 + kg * 4] = pk.u;
    }
    __syncthreads();
    #pragma unroll
    for (int mt = 0; mt < 4; ++mt) {
      if (mt >= nmt) break;
      bf16x8 pa0 = *(const bf16x8*)&pPs[mt * 16 + cl][kb];
      bf16x8 pa1 = *(const bf16x8*)&pPs[mt * 16 + cl][32 + kb];
      acc[mt][0] = mfma16(pa0, vf00, acc[mt][0]);
      acc[mt][0] = mfma16(pa1, vf10, acc[mt][0]);
      acc[mt][1] = mfma16(pa0, vf01, acc[mt][1]);
      acc[mt][1] = mfma16(pa1, vf11, acc[mt][1]);
    }
    __syncthreads();
  }

  #pragma unroll
  for (int i = 0; i < 2; ++i) {
    int mt = mt0 + 2 * i;
    if (mt >= nmt) break;
    float v = lpart[i];
    v += __shfl_xor(v, 16);
    v += __shfl_xor(v, 32);
    if (kg == 0) pred[snt][mt * 16 + cl] = v;
  }
  __syncthreads();
  if (tid < 64 && tid < ((nmt * 16 < 64) ? nmt * 16 : 64))
    lsum[tid] = (pred[0][tid] + pred[1][tid]) + (pred[2][tid] + pred[3][tid]);
  else if (tid < 64)
    lsum[tid] = 1.f;
  __syncthreads();

  #pragma unroll
  for (int mt = 0; mt < 4; ++mt) {
    #pragma unroll
    for (int r = 0; r < 4; ++r) {
      const int rl = mt * 16 + kg * 4 + r;
      if (rl < valid) {
        const float inv = 1.0f / lsum[rl];
        #pragma unroll
        for (int nt2 = 0; nt2 < 2; ++nt2) {
          float ov = hswish(acc[mt][nt2][r] * inv);
          __hip_bfloat16 hv = __float2bfloat16(ov);
          O[(long)(b * 196 + qbase + rl) * 3072 + h * 256 + w * 32 + nt2 * 16 + cl] =
              *(unsigned short*)&hv;
        }
      }
    }
  }
}

// ---------------------------------------------------------------------------
extern "C" void kernel_launch(void* const* d_in, const int* in_sizes, int n_in,
                              void* d_out, int out_size, void* d_ws, size_t ws_size,
                              hipStream_t stream) {
  if (ws_size < WS_TOTAL) return;

  const float* x    = (const float*)d_in[0];
  const float* Wqkv = (const float*)d_in[1];
  const float* bn1s = (const float*)d_in[2];
  const float* Wq   = (const float*)d_in[3];
  const float* bn2s = (const float*)d_in[4];
  const float* bias = (const float*)d_in[5];
  const float* Wout = (const float*)d_in[6];

  char* ws = (char*)d_ws;
  unsigned short* kb   = (unsigned short*)(ws + OFF_K);
  unsigned short* xbT  = (unsigned short*)(ws + OFF_XBT);
  unsigned short* xqT  = (unsigned short*)(ws + OFF_XQT);
  float* t1            = (float*)(ws + OFF_T1);
  float* t2            = (float*)(ws + OFF_T2);
  unsigned short* sxb1 = (unsigned short*)(ws + OFF_SXB1);
  unsigned short* sxb2 = (unsigned short*)(ws + OFF_SXB2);
  unsigned short* vtb  = (unsigned short*)(ws + OFF_VT);
  unsigned short* qnb  = (unsigned short*)(ws + OFF_QN);
  unsigned short* xb   = (unsigned short*)(ws + OFF_XB);
  unsigned short* Ob   = (unsigned short*)(ws + OFF_O);
  unsigned short* wqkvt= (unsigned short*)(ws + OFF_WQKVT);
  unsigned short* wqt  = (unsigned short*)(ws + OFF_WQT);
  unsigned short* woutt= (unsigned short*)(ws + OFF_WOUTT);
  float* ps1  = (float*)(ws + OFF_PS1);
  float* ps2  = (float*)(ws + OFF_PS2);
  float* cs1  = (float*)(ws + OFF_CS1);
  float* cs2  = (float*)(ws + OFF_CS2);
  float* a1w  = (float*)(ws + OFF_A1);
  float* b1w  = (float*)(ws + OFF_B1);
  float* a2w  = (float*)(ws + OFF_A2);
  float* b2w  = (float*)(ws + OFF_B2);
  float* out  = (float*)d_out;

  // prep: fused convert+transpose of x; gathered transpose; colsums
  prep_x<<<dim3(12, 784), 256, 0, stream>>>(x, xb, xbT);
  transpose_gather_bf16<<<dim3(12, 196), 256, 0, stream>>>(x, xqT);
  rowsum2_bf16<<<dim3(384, 2), 256, 0, stream>>>(xbT, xqT, cs1, cs2);

  // Sx via split-K MFMA (+fused f32->bf16 convert)
  sx_mfma<<<dim3(3, 3, CH1), 256, 0, stream>>>(xbT, ps1, M1, M1 / CH1);
  sx_mfma<<<dim3(3, 3, CH2), 256, 0, stream>>>(xqT, ps2, M2, M2 / CH2);
  reduce_conv2<<<dim3(576, 2), 256, 0, stream>>>(ps1, ps2, sxb1, sxb2);

  // weight transposes (overwrite ps1 region - dead after reduce)
  transpose_bf16<<<dim3(120, 12), 256, 0, stream>>>(Wqkv, wqkvt, Kc, N1);
  transpose_bf16<<<dim3(24, 12),  256, 0, stream>>>(Wq,   wqt,   Kc, Dq);
  transpose_bf16<<<dim3(16, 96),  256, 0, stream>>>(Wout, woutt, 4 * Dq, OUTD);

  // BN coefficients: T = Sx @ W via MFMA, then column reduce
  gemm_mfma<0, 0><<<dim3(30, 3), 256, 0, stream>>>(sxb1, wqkvt, t1, nullptr, nullptr, N1, Kc);
  gemm_mfma<0, 0><<<dim3(6, 3),  256, 0, stream>>>(sxb2, wqt,   t2, nullptr, nullptr, Dq, Kc);
  bnfinal<<<dim3(60), 256, 0, stream>>>(Wqkv, t1, cs1, bn1s, a1w, b1w, N1, 1.f / (float)M1);
  bnfinal<<<dim3(12), 256, 0, stream>>>(Wq,   t2, cs2, bn2s, a2w, b2w, Dq, 1.f / (float)M2);

  // projections (K and V gemms XCD-swizzled)
  gemm_mfma<0, 1, 1><<<dim3(6, 196), 256, 0, stream>>>(xb, wqkvt, kb, a1w, b1w, 768, Kc);
  gemm_mfma<0, 2, 1><<<dim3(24, 196), 256, 0, stream>>>(
      xb, wqkvt + (long)768 * Kc, vtb, a1w + 768, b1w + 768, 3072, Kc);
  gemm_mfma<1, 1><<<dim3(6, 49), 256, 0, stream>>>(xb, wqt, qnb, a2w, b2w, Dq, Kc);

  // attention -> hswish(O)
  attn_mfma<<<dim3(4, 12, 32), 512, 0, stream>>>(kb, vtb, qnb, bias, Ob);

  // out = O @ Wout^T
  gemm_mfma<0, 0><<<dim3(4, 49), 256, 0, stream>>>(Ob, woutt, out, nullptr, nullptr, OUTD, 4 * Dq);
}

// Round 13
// 472.777 us; speedup vs baseline: 1.2156x; 1.0050x over previous
//
#include <hip/hip_runtime.h>
#include <hip/hip_bf16.h>

// ---------------------------------------------------------------------------
// LeViT subsample attention (round 12).
//   = round 11 with attn_mfma V-register ping-pong prefetch (one k-tile
//     ahead). Fits now: r11 base VGPR=48 + 16 prefetch = 64 (at the 8-wave
//     cliff, not over it -- r8's spill was 64+16).
// ---------------------------------------------------------------------------

static constexpr int M1 = 25088, N1 = 3840, Kc = 384;
static constexpr int M2 = 6272, Dq = 768, OUTD = 512;
static constexpr int CH1 = 14, CH2 = 7;

static constexpr size_t OFF_K    = 0;
static constexpr size_t OFF_XBT  = 0;
static constexpr size_t OFF_XQT  = 19267584;
static constexpr size_t OFF_T1   = 24084480;
static constexpr size_t OFF_T2   = 29982720;
static constexpr size_t OFF_SXB1 = 31162368;
static constexpr size_t OFF_SXB2 = 31457280;
static constexpr size_t OFF_VT   = 38535168;
static constexpr size_t OFF_QN   = 192675840;
static constexpr size_t OFF_O    = 202309632;
static constexpr size_t OFF_XB   = OFF_O;
static constexpr size_t OFF_PS1  = 240844800;
static constexpr size_t OFF_WQKVT= 240844800;
static constexpr size_t OFF_WQT  = 243793920;
static constexpr size_t OFF_WOUTT= 244383744;
static constexpr size_t OFF_PS2  = 249123840;
static constexpr size_t OFF_CS1  = 253853184;
static constexpr size_t OFF_CS2  = 254444544;
static constexpr size_t OFF_A1   = 254446080;
static constexpr size_t OFF_B1   = 254461440;
static constexpr size_t OFF_A2   = 254476800;
static constexpr size_t OFF_B2   = 254479872;
static constexpr size_t WS_TOTAL = 254482944;

typedef __attribute__((ext_vector_type(8))) short bf16x8;
typedef __attribute__((ext_vector_type(4))) float f32x4;

static __device__ __forceinline__ f32x4 mfma16(bf16x8 a, bf16x8 b, f32x4 c) {
  return __builtin_amdgcn_mfma_f32_16x16x32_bf16(a, b, c, 0, 0, 0);
}

__device__ __forceinline__ void gload_lds16(const void* g, void* l) {
  __builtin_amdgcn_global_load_lds(
      (const __attribute__((address_space(1))) unsigned int*)g,
      (__attribute__((address_space(3))) unsigned int*)l, 16, 0, 0);
}

__device__ __forceinline__ float hswish(float x) {
  float t = fminf(fmaxf(x + 3.0f, 0.0f), 6.0f);
  return x * t * (1.0f / 6.0f);
}

// --------------------------- prep kernels ----------------------------------
__global__ __launch_bounds__(256) void prep_x(
    const float* __restrict__ in, unsigned short* __restrict__ xb,
    unsigned short* __restrict__ xbT) {
  __shared__ float t[32][33];
  const int c0 = blockIdx.x * 32, r0 = blockIdx.y * 32;
  const int x = threadIdx.x & 31, y = threadIdx.x >> 5;
  #pragma unroll
  for (int i = y; i < 32; i += 8) {
    float v = in[(long)(r0 + i) * 384 + c0 + x];
    t[i][x] = v;
    __hip_bfloat16 hv = __float2bfloat16(v);
    xb[(long)(r0 + i) * 384 + c0 + x] = *(unsigned short*)&hv;
  }
  __syncthreads();
  #pragma unroll
  for (int i = y; i < 32; i += 8) {
    __hip_bfloat16 v = __float2bfloat16(t[x][i]);
    xbT[(long)(c0 + i) * 25088 + r0 + x] = *(unsigned short*)&v;
  }
}

__global__ __launch_bounds__(256) void transpose_bf16(
    const float* __restrict__ in, unsigned short* __restrict__ out, int R, int C) {
  __shared__ float t[32][33];
  const int c0 = blockIdx.x * 32, r0 = blockIdx.y * 32;
  const int x = threadIdx.x & 31, y = threadIdx.x >> 5;
  #pragma unroll
  for (int i = y; i < 32; i += 8) t[i][x] = in[(long)(r0 + i) * C + c0 + x];
  __syncthreads();
  #pragma unroll
  for (int i = y; i < 32; i += 8) {
    __hip_bfloat16 v = __float2bfloat16(t[x][i]);
    out[(long)(c0 + i) * R + r0 + x] = *(unsigned short*)&v;
  }
}

__global__ __launch_bounds__(256) void transpose_gather_bf16(
    const float* __restrict__ in, unsigned short* __restrict__ out) {
  __shared__ float t[32][33];
  const int c0 = blockIdx.x * 32, r0 = blockIdx.y * 32;
  const int x = threadIdx.x & 31, y = threadIdx.x >> 5;
  #pragma unroll
  for (int i = y; i < 32; i += 8) {
    int m2 = r0 + i;
    int bb = m2 / 196, tt = m2 - bb * 196;
    int h2 = tt / 14, w2 = tt - h2 * 14;
    long grow = (long)(bb * 784 + h2 * 56 + w2 * 2);
    t[i][x] = in[grow * 384 + c0 + x];
  }
  __syncthreads();
  #pragma unroll
  for (int i = y; i < 32; i += 8) {
    __hip_bfloat16 v = __float2bfloat16(t[x][i]);
    out[(long)(c0 + i) * 6272 + r0 + x] = *(unsigned short*)&v;
  }
}

__global__ __launch_bounds__(256) void rowsum2_bf16(
    const unsigned short* __restrict__ srcA, const unsigned short* __restrict__ srcB,
    float* __restrict__ dstA, float* __restrict__ dstB) {
  const int z = blockIdx.y;
  const unsigned short* src = z ? srcB : srcA;
  float* dst = z ? dstB : dstA;
  const int ncols = z ? M2 : M1;
  const long base = (long)blockIdx.x * ncols;
  float s = 0.f;
  for (int c = threadIdx.x * 8; c < ncols; c += 2048) {
    bf16x8 v = *(const bf16x8*)(src + base + c);
    #pragma unroll
    for (int j = 0; j < 8; ++j)
      s += __uint_as_float(((unsigned)(unsigned short)v[j]) << 16);
  }
  __shared__ float red[256];
  red[threadIdx.x] = s;
  __syncthreads();
  for (int st = 128; st > 0; st >>= 1) {
    if (threadIdx.x < st) red[threadIdx.x] += red[threadIdx.x + st];
    __syncthreads();
  }
  if (threadIdx.x == 0) dst[blockIdx.x] = red[0];
}

__global__ __launch_bounds__(256) void reduce_conv2(
    const float* __restrict__ srcA, const float* __restrict__ srcB,
    unsigned short* __restrict__ dstA, unsigned short* __restrict__ dstB) {
  const int z = blockIdx.y;
  const float* src = z ? srcB : srcA;
  unsigned short* dstb = z ? dstB : dstA;
  const int nchunks = z ? CH2 : CH1;
  int i = blockIdx.x * 256 + threadIdx.x;
  float s = 0.f;
  for (int c = 0; c < nchunks; ++c) s += src[(long)c * 147456 + i];
  __hip_bfloat16 hv = __float2bfloat16(s);
  dstb[i] = *(unsigned short*)&hv;
}

// --------------------------- BN finalize -----------------------------------
__global__ __launch_bounds__(256) void bnfinal(
    const float* __restrict__ W, const float* __restrict__ T, const float* __restrict__ cs,
    const float* __restrict__ scale, float* __restrict__ a, float* __restrict__ b,
    int N, float invM) {
  const int j = blockIdx.x * 64 + (threadIdx.x & 63);
  const int rq = threadIdx.x >> 6;
  float yy = 0.f, mu = 0.f;
  for (int k = rq * 96; k < rq * 96 + 96; ++k) {
    float w = W[(long)k * N + j];
    yy += w * T[(long)k * N + j];
    mu += cs[k] * w;
  }
  __shared__ float r1[256], r2[256];
  r1[threadIdx.x] = yy; r2[threadIdx.x] = mu;
  __syncthreads();
  if (threadIdx.x < 64) {
    int t = threadIdx.x;
    yy = r1[t] + r1[t + 64] + r1[t + 128] + r1[t + 192];
    mu = r2[t] + r2[t + 64] + r2[t + 128] + r2[t + 192];
    float mean = mu * invM;
    float var = yy * invM - mean * mean;
    float ai = rsqrtf(var + 1e-5f) * scale[j];
    a[j] = ai;
    b[j] = -mean * ai;
  }
}

// ---------------------------------------------------------------------------
// split-K MFMA X @ X^T
// ---------------------------------------------------------------------------
__global__ __launch_bounds__(256) void sx_mfma(
    const unsigned short* __restrict__ X, float* __restrict__ Cpart,
    int Kfull, int Kchunk) {
  __shared__ __align__(16) char As[16384];
  __shared__ __align__(16) char Bs[16384];
  const int tid = threadIdx.x;
  const int lane = tid & 63;
  const int wv = tid >> 6;
  const int wm = (wv >> 1) * 64, wn = (wv & 1) * 64;
  const int m0 = blockIdx.y * 128, n0 = blockIdx.x * 128;
  const int cl = lane & 15, kg = lane >> 4;
  const int srow = tid >> 3;
  const int swz = ((tid & 7) * 16) ^ ((srow & 7) << 4);
  const int ldsb = wv * 1024;
  const long zbase = (long)blockIdx.z * Kchunk;

  long arow[4], brow[4];
  #pragma unroll
  for (int is = 0; is < 4; ++is) {
    arow[is] = (long)(m0 + is * 32 + srow) * Kfull + zbase;
    brow[is] = (long)(n0 + is * 32 + srow) * Kfull + zbase;
  }

  f32x4 acc[4][4];
  const f32x4 zf = {0.f, 0.f, 0.f, 0.f};
  #pragma unroll
  for (int i = 0; i < 4; ++i)
    #pragma unroll
    for (int j = 0; j < 4; ++j) acc[i][j] = zf;

  for (int k0 = 0; k0 < Kchunk; k0 += 64) {
    #pragma unroll
    for (int is = 0; is < 4; ++is) {
      gload_lds16((const char*)X + (arow[is] + k0) * 2 + swz, As + is * 4096 + ldsb);
      gload_lds16((const char*)X + (brow[is] + k0) * 2 + swz, Bs + is * 4096 + ldsb);
    }
    __syncthreads();
    bf16x8 afr[4][2], bfr[4][2];
    #pragma unroll
    for (int t = 0; t < 4; ++t) {
      const int ar = wm + t * 16 + cl;
      const int br = wn + t * 16 + cl;
      const int sa = (ar & 7) << 4, sb = (br & 7) << 4;
      afr[t][0] = *(const bf16x8*)(As + ar * 128 + ((kg * 16) ^ sa));
      afr[t][1] = *(const bf16x8*)(As + ar * 128 + ((64 + kg * 16) ^ sa));
      bfr[t][0] = *(const bf16x8*)(Bs + br * 128 + ((kg * 16) ^ sb));
      bfr[t][1] = *(const bf16x8*)(Bs + br * 128 + ((64 + kg * 16) ^ sb));
    }
    #pragma unroll
    for (int mt = 0; mt < 4; ++mt)
      #pragma unroll
      for (int nt = 0; nt < 4; ++nt) {
        acc[mt][nt] = mfma16(bfr[nt][0], afr[mt][0], acc[mt][nt]);
        acc[mt][nt] = mfma16(bfr[nt][1], afr[mt][1], acc[mt][nt]);
      }
    __syncthreads();
  }

  float* Cp = Cpart + (long)blockIdx.z * 384 * 384;
  #pragma unroll
  for (int mt = 0; mt < 4; ++mt) {
    const int gm = m0 + wm + mt * 16 + cl;
    #pragma unroll
    for (int nt = 0; nt < 4; ++nt) {
      const int gn = n0 + wn + nt * 16 + kg * 4;
      *(float4*)(Cp + (long)gm * 384 + gn) =
          make_float4(acc[mt][nt][0], acc[mt][nt][1], acc[mt][nt][2], acc[mt][nt][3]);
    }
  }
}

// ---------------------------------------------------------------------------
// bf16 MFMA GEMM: C = A[M,K] @ Bt[N,K]^T.  SWZ: XCD chunked remap.
// ---------------------------------------------------------------------------
template<int AMODE, int EPI, int SWZ = 0>
__global__ __launch_bounds__(256) void gemm_mfma(
    const unsigned short* __restrict__ A, const unsigned short* __restrict__ Bt,
    void* __restrict__ Cout, const float* __restrict__ ea, const float* __restrict__ eb,
    int N, int K) {
  constexpr int SMEM_BYTES = (EPI == 2) ? 34816 : 32768;
  __shared__ __align__(16) char smem[SMEM_BYTES];
  char* As = smem;
  char* Bs = smem + 16384;
  const int tid = threadIdx.x;
  const int lane = tid & 63;
  const int wv = tid >> 6;
  const int wm = (wv >> 1) * 64, wn = (wv & 1) * 64;

  int bx = blockIdx.x, by = blockIdx.y;
  if constexpr (SWZ) {
    const int gx = gridDim.x;
    const int tot = gx * gridDim.y;
    const int lin = by * gx + bx;
    const int cpx = tot >> 3;
    const int nl = (lin & 7) * cpx + (lin >> 3);
    bx = nl % gx; by = nl / gx;
  }
  const int m0 = by * 128, n0 = bx * 128;
  const int cl = lane & 15, kg = lane >> 4;

  const int srow = tid >> 3;
  const int swz = ((tid & 7) * 16) ^ ((srow & 7) << 4);
  const int ldsb = wv * 1024;

  long arow[4], brow[4];
  #pragma unroll
  for (int is = 0; is < 4; ++is) {
    int gm = m0 + is * 32 + srow;
    long grow;
    if constexpr (AMODE == 1) {
      int bb = gm / 196, t = gm - bb * 196;
      int h2 = t / 14, w2 = t - h2 * 14;
      grow = (long)(bb * 784 + h2 * 56 + w2 * 2);
    } else {
      grow = gm;
    }
    arow[is] = grow * (long)K;
    brow[is] = (long)(n0 + is * 32 + srow) * (long)K;
  }

  f32x4 acc[4][4];
  const f32x4 zf = {0.f, 0.f, 0.f, 0.f};
  #pragma unroll
  for (int i = 0; i < 4; ++i)
    #pragma unroll
    for (int j = 0; j < 4; ++j) acc[i][j] = zf;

  for (int k0 = 0; k0 < K; k0 += 64) {
    #pragma unroll
    for (int is = 0; is < 4; ++is) {
      gload_lds16((const char*)A  + (arow[is] + k0) * 2 + swz, As + is * 4096 + ldsb);
      gload_lds16((const char*)Bt + (brow[is] + k0) * 2 + swz, Bs + is * 4096 + ldsb);
    }
    __syncthreads();
    bf16x8 afr[4][2], bfr[4][2];
    #pragma unroll
    for (int t = 0; t < 4; ++t) {
      const int ar = wm + t * 16 + cl;
      const int br = wn + t * 16 + cl;
      const int sa = (ar & 7) << 4, sb = (br & 7) << 4;
      afr[t][0] = *(const bf16x8*)(As + ar * 128 + ((kg * 16) ^ sa));
      afr[t][1] = *(const bf16x8*)(As + ar * 128 + ((64 + kg * 16) ^ sa));
      bfr[t][0] = *(const bf16x8*)(Bs + br * 128 + ((kg * 16) ^ sb));
      bfr[t][1] = *(const bf16x8*)(Bs + br * 128 + ((64 + kg * 16) ^ sb));
    }
    #pragma unroll
    for (int mt = 0; mt < 4; ++mt)
      #pragma unroll
      for (int nt = 0; nt < 4; ++nt) {
        if constexpr (EPI == 2) {
          acc[mt][nt] = mfma16(afr[mt][0], bfr[nt][0], acc[mt][nt]);
          acc[mt][nt] = mfma16(afr[mt][1], bfr[nt][1], acc[mt][nt]);
        } else {
          acc[mt][nt] = mfma16(bfr[nt][0], afr[mt][0], acc[mt][nt]);
          acc[mt][nt] = mfma16(bfr[nt][1], afr[mt][1], acc[mt][nt]);
        }
      }
    __syncthreads();
  }

  if constexpr (EPI == 2) {
    char* Cs = smem;
    #pragma unroll
    for (int mt = 0; mt < 4; ++mt) {
      const int kl = wm + mt * 16 + kg * 4;
      #pragma unroll
      for (int nt = 0; nt < 4; ++nt) {
        const int dvl = wn + nt * 16 + cl;
        const int gn = n0 + dvl;
        const float av = ea[gn], bv = eb[gn];
        union { ushort4 u; __hip_bfloat16 h[4]; } pk;
        pk.h[0] = __float2bfloat16(acc[mt][nt][0] * av + bv);
        pk.h[1] = __float2bfloat16(acc[mt][nt][1] * av + bv);
        pk.h[2] = __float2bfloat16(acc[mt][nt][2] * av + bv);
        pk.h[3] = __float2bfloat16(acc[mt][nt][3] * av + bv);
        *(ushort4*)(Cs + dvl * 272 + kl * 2) = pk.u;
      }
    }
    __syncthreads();
    const int hh = n0 >> 8;
    #pragma unroll
    for (int l = 0; l < 8; ++l) {
      const int row = l * 16 + (tid >> 4);
      const int seg = tid & 15;
      const int gm = m0 + seg * 8;
      const int bb = gm / 784, kk = gm - bb * 784;
      const int dvl = (n0 + row) & 255;
      uint4 v = *(const uint4*)(Cs + row * 272 + seg * 16);
      *(uint4*)((unsigned short*)Cout + ((long)(bb * 12 + hh) * 256 + dvl) * 784 + kk) = v;
    }
  } else {
    #pragma unroll
    for (int mt = 0; mt < 4; ++mt) {
      #pragma unroll
      for (int nt = 0; nt < 4; ++nt) {
        const int gm = m0 + wm + mt * 16 + cl;
        const int gn = n0 + wn + nt * 16 + kg * 4;
        if constexpr (EPI == 1) {
          float4 a4 = *(const float4*)(ea + gn);
          float4 b4 = *(const float4*)(eb + gn);
          union { ushort4 u; __hip_bfloat16 h[4]; } pk;
          pk.h[0] = __float2bfloat16(acc[mt][nt][0] * a4.x + b4.x);
          pk.h[1] = __float2bfloat16(acc[mt][nt][1] * a4.y + b4.y);
          pk.h[2] = __float2bfloat16(acc[mt][nt][2] * a4.z + b4.z);
          pk.h[3] = __float2bfloat16(acc[mt][nt][3] * a4.w + b4.w);
          *(ushort4*)((unsigned short*)Cout + (long)gm * N + gn) = pk.u;
        } else {
          *(float4*)((float*)Cout + (long)gm * N + gn) =
              make_float4(acc[mt][nt][0], acc[mt][nt][1], acc[mt][nt][2], acc[mt][nt][3]);
        }
      }
    }
  }
}

// ---------------------------------------------------------------------------
// Single-pass MFMA flash attention. q-tile = 64 rows, 4 blocks/CU, chunked
// XCD remap; K via global_load_lds double buffer; V regs ping-pong prefetch
// one tile ahead (fits: 48 base + 16 = 64 VGPR).
// ---------------------------------------------------------------------------
#define LOAD_VF(KT, V0, V1, V2, V3) { \
    const int kvo_ = (KT) * 64 + kb; \
    V0 = *(const bf16x8*)(vt + vr0 + kvo_); \
    V1 = *(const bf16x8*)(vt + vr0 + kvo_ + 32); \
    V2 = *(const bf16x8*)(vt + vr1 + kvo_); \
    V3 = *(const bf16x8*)(vt + vr1 + kvo_ + 32); }

#define ATTN_STEP(KT, CUR, VC0, VC1, VC2, VC3, VN0, VN1, VN2, VN3) { \
    const int k0_ = (KT) * 64; \
    if ((KT) < 12) \
      gload_lds16((const char*)kbuf + kbase + (long)(k0_ + 64) * 1536, \
                  Kl[(CUR) ^ 1] + w * 1024); \
    if ((KT) + 1 < 13) { LOAD_VF((KT) + 1, VN0, VN1, VN2, VN3); } \
    const char* kr_ = Kl[CUR] + krow * 128; \
    bf16x8 kk0_ = *(const bf16x8*)(kr_ + ((kg * 16) ^ ksw)); \
    bf16x8 kk1_ = *(const bf16x8*)(kr_ + ((64 + kg * 16) ^ ksw)); \
    _Pragma("unroll") \
    for (int i_ = 0; i_ < 2; ++i_) { \
      int mt_ = mt0 + 2 * i_; \
      if (mt_ >= nmt) break; \
      bf16x8 q0_ = *(const bf16x8*)&Qs[mt_ * 16 + cl][kb]; \
      bf16x8 q1_ = *(const bf16x8*)&Qs[mt_ * 16 + cl][32 + kb]; \
      f32x4 s_ = mfma16(kk1_, q1_, mfma16(kk0_, q0_, zerof)); \
      const int rowl_ = mt_ * 16 + cl; \
      const int key0_ = k0_ + snt * 16 + kg * 4; \
      const bool ok_ = (rowl_ < valid) && (key0_ < 784); \
      float4 b4_ = make_float4(0.f, 0.f, 0.f, 0.f); \
      if (ok_) b4_ = *(const float4*)(bias + (long)(qbase + rowl_) * 784 + key0_); \
      float p0_ = ok_ ? __expf(s_[0] * 0.125f + b4_.x) : 0.f; \
      float p1_ = ok_ ? __expf(s_[1] * 0.125f + b4_.y) : 0.f; \
      float p2_ = ok_ ? __expf(s_[2] * 0.125f + b4_.z) : 0.f; \
      float p3_ = ok_ ? __expf(s_[3] * 0.125f + b4_.w) : 0.f; \
      lpart[i_] += (p0_ + p1_) + (p2_ + p3_); \
      union { ushort4 u; __hip_bfloat16 hh_[4]; } pk_; \
      pk_.hh_[0] = __float2bfloat16(p0_); pk_.hh_[1] = __float2bfloat16(p1_); \
      pk_.hh_[2] = __float2bfloat16(p2_); pk_.hh_[3] = __float2bfloat16(p3_); \
      *(ushort4*)&pPs[rowl_][snt * 16 + kg * 4] = pk_.u; \
    } \
    __syncthreads(); \
    _Pragma("unroll") \
    for (int mt_ = 0; mt_ < 4; ++mt_) { \
      if (mt_ >= nmt) break; \
      bf16x8 pa0_ = *(const bf16x8*)&pPs[mt_ * 16 + cl][kb]; \
      bf16x8 pa1_ = *(const bf16x8*)&pPs[mt_ * 16 + cl][32 + kb]; \
      acc[mt_][0] = mfma16(pa0_, VC0, acc[mt_][0]); \
      acc[mt_][0] = mfma16(pa1_, VC1, acc[mt_][0]); \
      acc[mt_][1] = mfma16(pa0_, VC2, acc[mt_][1]); \
      acc[mt_][1] = mfma16(pa1_, VC3, acc[mt_][1]); \
    } \
    __syncthreads(); }

__global__ __launch_bounds__(512, 4) void attn_mfma(
    const unsigned short* __restrict__ kbuf, const unsigned short* __restrict__ vt,
    const unsigned short* __restrict__ qn, const float* __restrict__ bias,
    unsigned short* __restrict__ O) {
  const int p = blockIdx.x + 4 * (blockIdx.y + 12 * blockIdx.z);
  const int wrk = ((p & 7) * 192) + (p >> 3);
  const int qt = wrk & 3;
  const int hb = wrk >> 2;
  const int h = hb % 12, b = hb / 12;

  const int tid = threadIdx.x;
  const int w = tid >> 6;
  const int lane = tid & 63;
  const int cl = lane & 15;
  const int kg = lane >> 4;
  const int kb = kg * 8;
  const int qbase = qt * 64;
  const int valid = (196 - qbase) > 64 ? 64 : (196 - qbase);
  const int nmt = (valid + 15) >> 4;
  const int bh = b * 12 + h;

  __shared__ __align__(16) short Qs[64][72];
  __shared__ __align__(16) char Kl[2][8192];
  __shared__ __align__(16) short pPs[64][72];
  __shared__ float pred[4][64];
  __shared__ float lsum[64];

  const bf16x8 zero8 = {0,0,0,0,0,0,0,0};
  const f32x4 zerof = {0.f,0.f,0.f,0.f};

  const int srow = tid >> 3;
  const int ssw = ((tid & 7) * 16) ^ ((srow & 7) << 4);
  const long kbase = ((long)(b * 784 + srow) * 768 + h * 64) * 2 + ssw;

  {
    int row = tid >> 3, d8 = tid & 7;
    bf16x8 v = zero8;
    if (row < valid)
      v = *(const bf16x8*)(qn + (long)(b * 196 + qbase + row) * 768 + h * 64 + d8 * 8);
    *(bf16x8*)&Qs[row][d8 * 8] = v;
  }
  gload_lds16((const char*)kbuf + kbase, Kl[0] + w * 1024);

  const int mt0 = w >> 2, snt = w & 3;
  const long vr0 = ((long)bh * 256 + w * 32 + cl) * 784;
  const long vr1 = vr0 + (long)16 * 784;

  // prefetch V tile 0 before the barrier
  bf16x8 vA0, vA1, vA2, vA3;
  bf16x8 vB0 = zero8, vB1 = zero8, vB2 = zero8, vB3 = zero8;
  LOAD_VF(0, vA0, vA1, vA2, vA3);
  __syncthreads();

  f32x4 acc[4][2];
  #pragma unroll
  for (int mt = 0; mt < 4; ++mt) { acc[mt][0] = zerof; acc[mt][1] = zerof; }
  float lpart[2] = {0.f, 0.f};

  const int krow = snt * 16 + cl;
  const int ksw = (krow & 7) << 4;

  for (int kt2 = 0; kt2 < 13; kt2 += 2) {
    ATTN_STEP(kt2, 0, vA0, vA1, vA2, vA3, vB0, vB1, vB2, vB3);
    if (kt2 + 1 < 13) {
      ATTN_STEP(kt2 + 1, 1, vB0, vB1, vB2, vB3, vA0, vA1, vA2, vA3);
    }
  }

  #pragma unroll
  for (int i = 0; i < 2; ++i) {
    int mt = mt0 + 2 * i;
    if (mt >= nmt) break;
    float v = lpart[i];
    v += __shfl_xor(v, 16);
    v += __shfl_xor(v, 32);
    if (kg == 0) pred[snt][mt * 16 + cl] = v;
  }
  __syncthreads();
  if (tid < 64 && tid < ((nmt * 16 < 64) ? nmt * 16 : 64))
    lsum[tid] = (pred[0][tid] + pred[1][tid]) + (pred[2][tid] + pred[3][tid]);
  else if (tid < 64)
    lsum[tid] = 1.f;
  __syncthreads();

  #pragma unroll
  for (int mt = 0; mt < 4; ++mt) {
    #pragma unroll
    for (int r = 0; r < 4; ++r) {
      const int rl = mt * 16 + kg * 4 + r;
      if (rl < valid) {
        const float inv = 1.0f / lsum[rl];
        #pragma unroll
        for (int nt2 = 0; nt2 < 2; ++nt2) {
          float ov = hswish(acc[mt][nt2][r] * inv);
          __hip_bfloat16 hv = __float2bfloat16(ov);
          O[(long)(b * 196 + qbase + rl) * 3072 + h * 256 + w * 32 + nt2 * 16 + cl] =
              *(unsigned short*)&hv;
        }
      }
    }
  }
}

// ---------------------------------------------------------------------------
extern "C" void kernel_launch(void* const* d_in, const int* in_sizes, int n_in,
                              void* d_out, int out_size, void* d_ws, size_t ws_size,
                              hipStream_t stream) {
  if (ws_size < WS_TOTAL) return;

  const float* x    = (const float*)d_in[0];
  const float* Wqkv = (const float*)d_in[1];
  const float* bn1s = (const float*)d_in[2];
  const float* Wq   = (const float*)d_in[3];
  const float* bn2s = (const float*)d_in[4];
  const float* bias = (const float*)d_in[5];
  const float* Wout = (const float*)d_in[6];

  char* ws = (char*)d_ws;
  unsigned short* kb   = (unsigned short*)(ws + OFF_K);
  unsigned short* xbT  = (unsigned short*)(ws + OFF_XBT);
  unsigned short* xqT  = (unsigned short*)(ws + OFF_XQT);
  float* t1            = (float*)(ws + OFF_T1);
  float* t2            = (float*)(ws + OFF_T2);
  unsigned short* sxb1 = (unsigned short*)(ws + OFF_SXB1);
  unsigned short* sxb2 = (unsigned short*)(ws + OFF_SXB2);
  unsigned short* vtb  = (unsigned short*)(ws + OFF_VT);
  unsigned short* qnb  = (unsigned short*)(ws + OFF_QN);
  unsigned short* xb   = (unsigned short*)(ws + OFF_XB);
  unsigned short* Ob   = (unsigned short*)(ws + OFF_O);
  unsigned short* wqkvt= (unsigned short*)(ws + OFF_WQKVT);
  unsigned short* wqt  = (unsigned short*)(ws + OFF_WQT);
  unsigned short* woutt= (unsigned short*)(ws + OFF_WOUTT);
  float* ps1  = (float*)(ws + OFF_PS1);
  float* ps2  = (float*)(ws + OFF_PS2);
  float* cs1  = (float*)(ws + OFF_CS1);
  float* cs2  = (float*)(ws + OFF_CS2);
  float* a1w  = (float*)(ws + OFF_A1);
  float* b1w  = (float*)(ws + OFF_B1);
  float* a2w  = (float*)(ws + OFF_A2);
  float* b2w  = (float*)(ws + OFF_B2);
  float* out  = (float*)d_out;

  prep_x<<<dim3(12, 784), 256, 0, stream>>>(x, xb, xbT);
  transpose_gather_bf16<<<dim3(12, 196), 256, 0, stream>>>(x, xqT);
  rowsum2_bf16<<<dim3(384, 2), 256, 0, stream>>>(xbT, xqT, cs1, cs2);

  sx_mfma<<<dim3(3, 3, CH1), 256, 0, stream>>>(xbT, ps1, M1, M1 / CH1);
  sx_mfma<<<dim3(3, 3, CH2), 256, 0, stream>>>(xqT, ps2, M2, M2 / CH2);
  reduce_conv2<<<dim3(576, 2), 256, 0, stream>>>(ps1, ps2, sxb1, sxb2);

  transpose_bf16<<<dim3(120, 12), 256, 0, stream>>>(Wqkv, wqkvt, Kc, N1);
  transpose_bf16<<<dim3(24, 12),  256, 0, stream>>>(Wq,   wqt,   Kc, Dq);
  transpose_bf16<<<dim3(16, 96),  256, 0, stream>>>(Wout, woutt, 4 * Dq, OUTD);

  gemm_mfma<0, 0><<<dim3(30, 3), 256, 0, stream>>>(sxb1, wqkvt, t1, nullptr, nullptr, N1, Kc);
  gemm_mfma<0, 0><<<dim3(6, 3),  256, 0, stream>>>(sxb2, wqt,   t2, nullptr, nullptr, Dq, Kc);
  bnfinal<<<dim3(60), 256, 0, stream>>>(Wqkv, t1, cs1, bn1s, a1w, b1w, N1, 1.f / (float)M1);
  bnfinal<<<dim3(12), 256, 0, stream>>>(Wq,   t2, cs2, bn2s, a2w, b2w, Dq, 1.f / (float)M2);

  gemm_mfma<0, 1, 1><<<dim3(6, 196), 256, 0, stream>>>(xb, wqkvt, kb, a1w, b1w, 768, Kc);
  gemm_mfma<0, 2, 1><<<dim3(24, 196), 256, 0, stream>>>(
      xb, wqkvt + (long)768 * Kc, vtb, a1w + 768, b1w + 768, 3072, Kc);
  gemm_mfma<1, 1><<<dim3(6, 49), 256, 0, stream>>>(xb, wqt, qnb, a2w, b2w, Dq, Kc);

  attn_mfma<<<dim3(4, 12, 32), 512, 0, stream>>>(kb, vtb, qnb, bias, Ob);

  gemm_mfma<0, 0><<<dim3(4, 49), 256, 0, stream>>>(Ob, woutt, out, nullptr, nullptr, OUTD, 4 * Dq);
}

// Round 14
// 472.610 us; speedup vs baseline: 1.2161x; 1.0004x over previous
//
#include <hip/hip_runtime.h>
#include <hip/hip_bf16.h>

// ---------------------------------------------------------------------------
// LeViT subsample attention (round 13).
//   = round 12 with attn_mfma barrier surgery (T4 counted vmcnt):
//   bias loads hoisted & always-issued (uniform vmem count), raw s_barrier +
//   lgkmcnt(0) (no vmcnt drain), explicit vmcnt(11) before K fragment reads.
//   K/V prefetches now survive across barriers -> latency hidden per tile.
// ---------------------------------------------------------------------------

static constexpr int M1 = 25088, N1 = 3840, Kc = 384;
static constexpr int M2 = 6272, Dq = 768, OUTD = 512;
static constexpr int CH1 = 14, CH2 = 7;

static constexpr size_t OFF_K    = 0;
static constexpr size_t OFF_XBT  = 0;
static constexpr size_t OFF_XQT  = 19267584;
static constexpr size_t OFF_T1   = 24084480;
static constexpr size_t OFF_T2   = 29982720;
static constexpr size_t OFF_SXB1 = 31162368;
static constexpr size_t OFF_SXB2 = 31457280;
static constexpr size_t OFF_VT   = 38535168;
static constexpr size_t OFF_QN   = 192675840;
static constexpr size_t OFF_O    = 202309632;
static constexpr size_t OFF_XB   = OFF_O;
static constexpr size_t OFF_PS1  = 240844800;
static constexpr size_t OFF_WQKVT= 240844800;
static constexpr size_t OFF_WQT  = 243793920;
static constexpr size_t OFF_WOUTT= 244383744;
static constexpr size_t OFF_PS2  = 249123840;
static constexpr size_t OFF_CS1  = 253853184;
static constexpr size_t OFF_CS2  = 254444544;
static constexpr size_t OFF_A1   = 254446080;
static constexpr size_t OFF_B1   = 254461440;
static constexpr size_t OFF_A2   = 254476800;
static constexpr size_t OFF_B2   = 254479872;
static constexpr size_t WS_TOTAL = 254482944;

typedef __attribute__((ext_vector_type(8))) short bf16x8;
typedef __attribute__((ext_vector_type(4))) float f32x4;

static __device__ __forceinline__ f32x4 mfma16(bf16x8 a, bf16x8 b, f32x4 c) {
  return __builtin_amdgcn_mfma_f32_16x16x32_bf16(a, b, c, 0, 0, 0);
}

__device__ __forceinline__ void gload_lds16(const void* g, void* l) {
  __builtin_amdgcn_global_load_lds(
      (const __attribute__((address_space(1))) unsigned int*)g,
      (__attribute__((address_space(3))) unsigned int*)l, 16, 0, 0);
}

__device__ __forceinline__ float hswish(float x) {
  float t = fminf(fmaxf(x + 3.0f, 0.0f), 6.0f);
  return x * t * (1.0f / 6.0f);
}

// --------------------------- prep kernels ----------------------------------
__global__ __launch_bounds__(256) void prep_x(
    const float* __restrict__ in, unsigned short* __restrict__ xb,
    unsigned short* __restrict__ xbT) {
  __shared__ float t[32][33];
  const int c0 = blockIdx.x * 32, r0 = blockIdx.y * 32;
  const int x = threadIdx.x & 31, y = threadIdx.x >> 5;
  #pragma unroll
  for (int i = y; i < 32; i += 8) {
    float v = in[(long)(r0 + i) * 384 + c0 + x];
    t[i][x] = v;
    __hip_bfloat16 hv = __float2bfloat16(v);
    xb[(long)(r0 + i) * 384 + c0 + x] = *(unsigned short*)&hv;
  }
  __syncthreads();
  #pragma unroll
  for (int i = y; i < 32; i += 8) {
    __hip_bfloat16 v = __float2bfloat16(t[x][i]);
    xbT[(long)(c0 + i) * 25088 + r0 + x] = *(unsigned short*)&v;
  }
}

__global__ __launch_bounds__(256) void transpose_bf16(
    const float* __restrict__ in, unsigned short* __restrict__ out, int R, int C) {
  __shared__ float t[32][33];
  const int c0 = blockIdx.x * 32, r0 = blockIdx.y * 32;
  const int x = threadIdx.x & 31, y = threadIdx.x >> 5;
  #pragma unroll
  for (int i = y; i < 32; i += 8) t[i][x] = in[(long)(r0 + i) * C + c0 + x];
  __syncthreads();
  #pragma unroll
  for (int i = y; i < 32; i += 8) {
    __hip_bfloat16 v = __float2bfloat16(t[x][i]);
    out[(long)(c0 + i) * R + r0 + x] = *(unsigned short*)&v;
  }
}

__global__ __launch_bounds__(256) void transpose_gather_bf16(
    const float* __restrict__ in, unsigned short* __restrict__ out) {
  __shared__ float t[32][33];
  const int c0 = blockIdx.x * 32, r0 = blockIdx.y * 32;
  const int x = threadIdx.x & 31, y = threadIdx.x >> 5;
  #pragma unroll
  for (int i = y; i < 32; i += 8) {
    int m2 = r0 + i;
    int bb = m2 / 196, tt = m2 - bb * 196;
    int h2 = tt / 14, w2 = tt - h2 * 14;
    long grow = (long)(bb * 784 + h2 * 56 + w2 * 2);
    t[i][x] = in[grow * 384 + c0 + x];
  }
  __syncthreads();
  #pragma unroll
  for (int i = y; i < 32; i += 8) {
    __hip_bfloat16 v = __float2bfloat16(t[x][i]);
    out[(long)(c0 + i) * 6272 + r0 + x] = *(unsigned short*)&v;
  }
}

__global__ __launch_bounds__(256) void rowsum2_bf16(
    const unsigned short* __restrict__ srcA, const unsigned short* __restrict__ srcB,
    float* __restrict__ dstA, float* __restrict__ dstB) {
  const int z = blockIdx.y;
  const unsigned short* src = z ? srcB : srcA;
  float* dst = z ? dstB : dstA;
  const int ncols = z ? M2 : M1;
  const long base = (long)blockIdx.x * ncols;
  float s = 0.f;
  for (int c = threadIdx.x * 8; c < ncols; c += 2048) {
    bf16x8 v = *(const bf16x8*)(src + base + c);
    #pragma unroll
    for (int j = 0; j < 8; ++j)
      s += __uint_as_float(((unsigned)(unsigned short)v[j]) << 16);
  }
  __shared__ float red[256];
  red[threadIdx.x] = s;
  __syncthreads();
  for (int st = 128; st > 0; st >>= 1) {
    if (threadIdx.x < st) red[threadIdx.x] += red[threadIdx.x + st];
    __syncthreads();
  }
  if (threadIdx.x == 0) dst[blockIdx.x] = red[0];
}

__global__ __launch_bounds__(256) void reduce_conv2(
    const float* __restrict__ srcA, const float* __restrict__ srcB,
    unsigned short* __restrict__ dstA, unsigned short* __restrict__ dstB) {
  const int z = blockIdx.y;
  const float* src = z ? srcB : srcA;
  unsigned short* dstb = z ? dstB : dstA;
  const int nchunks = z ? CH2 : CH1;
  int i = blockIdx.x * 256 + threadIdx.x;
  float s = 0.f;
  for (int c = 0; c < nchunks; ++c) s += src[(long)c * 147456 + i];
  __hip_bfloat16 hv = __float2bfloat16(s);
  dstb[i] = *(unsigned short*)&hv;
}

// --------------------------- BN finalize -----------------------------------
__global__ __launch_bounds__(256) void bnfinal(
    const float* __restrict__ W, const float* __restrict__ T, const float* __restrict__ cs,
    const float* __restrict__ scale, float* __restrict__ a, float* __restrict__ b,
    int N, float invM) {
  const int j = blockIdx.x * 64 + (threadIdx.x & 63);
  const int rq = threadIdx.x >> 6;
  float yy = 0.f, mu = 0.f;
  for (int k = rq * 96; k < rq * 96 + 96; ++k) {
    float w = W[(long)k * N + j];
    yy += w * T[(long)k * N + j];
    mu += cs[k] * w;
  }
  __shared__ float r1[256], r2[256];
  r1[threadIdx.x] = yy; r2[threadIdx.x] = mu;
  __syncthreads();
  if (threadIdx.x < 64) {
    int t = threadIdx.x;
    yy = r1[t] + r1[t + 64] + r1[t + 128] + r1[t + 192];
    mu = r2[t] + r2[t + 64] + r2[t + 128] + r2[t + 192];
    float mean = mu * invM;
    float var = yy * invM - mean * mean;
    float ai = rsqrtf(var + 1e-5f) * scale[j];
    a[j] = ai;
    b[j] = -mean * ai;
  }
}

// ---------------------------------------------------------------------------
// split-K MFMA X @ X^T
// ---------------------------------------------------------------------------
__global__ __launch_bounds__(256) void sx_mfma(
    const unsigned short* __restrict__ X, float* __restrict__ Cpart,
    int Kfull, int Kchunk) {
  __shared__ __align__(16) char As[16384];
  __shared__ __align__(16) char Bs[16384];
  const int tid = threadIdx.x;
  const int lane = tid & 63;
  const int wv = tid >> 6;
  const int wm = (wv >> 1) * 64, wn = (wv & 1) * 64;
  const int m0 = blockIdx.y * 128, n0 = blockIdx.x * 128;
  const int cl = lane & 15, kg = lane >> 4;
  const int srow = tid >> 3;
  const int swz = ((tid & 7) * 16) ^ ((srow & 7) << 4);
  const int ldsb = wv * 1024;
  const long zbase = (long)blockIdx.z * Kchunk;

  long arow[4], brow[4];
  #pragma unroll
  for (int is = 0; is < 4; ++is) {
    arow[is] = (long)(m0 + is * 32 + srow) * Kfull + zbase;
    brow[is] = (long)(n0 + is * 32 + srow) * Kfull + zbase;
  }

  f32x4 acc[4][4];
  const f32x4 zf = {0.f, 0.f, 0.f, 0.f};
  #pragma unroll
  for (int i = 0; i < 4; ++i)
    #pragma unroll
    for (int j = 0; j < 4; ++j) acc[i][j] = zf;

  for (int k0 = 0; k0 < Kchunk; k0 += 64) {
    #pragma unroll
    for (int is = 0; is < 4; ++is) {
      gload_lds16((const char*)X + (arow[is] + k0) * 2 + swz, As + is * 4096 + ldsb);
      gload_lds16((const char*)X + (brow[is] + k0) * 2 + swz, Bs + is * 4096 + ldsb);
    }
    __syncthreads();
    bf16x8 afr[4][2], bfr[4][2];
    #pragma unroll
    for (int t = 0; t < 4; ++t) {
      const int ar = wm + t * 16 + cl;
      const int br = wn + t * 16 + cl;
      const int sa = (ar & 7) << 4, sb = (br & 7) << 4;
      afr[t][0] = *(const bf16x8*)(As + ar * 128 + ((kg * 16) ^ sa));
      afr[t][1] = *(const bf16x8*)(As + ar * 128 + ((64 + kg * 16) ^ sa));
      bfr[t][0] = *(const bf16x8*)(Bs + br * 128 + ((kg * 16) ^ sb));
      bfr[t][1] = *(const bf16x8*)(Bs + br * 128 + ((64 + kg * 16) ^ sb));
    }
    #pragma unroll
    for (int mt = 0; mt < 4; ++mt)
      #pragma unroll
      for (int nt = 0; nt < 4; ++nt) {
        acc[mt][nt] = mfma16(bfr[nt][0], afr[mt][0], acc[mt][nt]);
        acc[mt][nt] = mfma16(bfr[nt][1], afr[mt][1], acc[mt][nt]);
      }
    __syncthreads();
  }

  float* Cp = Cpart + (long)blockIdx.z * 384 * 384;
  #pragma unroll
  for (int mt = 0; mt < 4; ++mt) {
    const int gm = m0 + wm + mt * 16 + cl;
    #pragma unroll
    for (int nt = 0; nt < 4; ++nt) {
      const int gn = n0 + wn + nt * 16 + kg * 4;
      *(float4*)(Cp + (long)gm * 384 + gn) =
          make_float4(acc[mt][nt][0], acc[mt][nt][1], acc[mt][nt][2], acc[mt][nt][3]);
    }
  }
}

// ---------------------------------------------------------------------------
// bf16 MFMA GEMM: C = A[M,K] @ Bt[N,K]^T.  SWZ: XCD chunked remap.
// ---------------------------------------------------------------------------
template<int AMODE, int EPI, int SWZ = 0>
__global__ __launch_bounds__(256) void gemm_mfma(
    const unsigned short* __restrict__ A, const unsigned short* __restrict__ Bt,
    void* __restrict__ Cout, const float* __restrict__ ea, const float* __restrict__ eb,
    int N, int K) {
  constexpr int SMEM_BYTES = (EPI == 2) ? 34816 : 32768;
  __shared__ __align__(16) char smem[SMEM_BYTES];
  char* As = smem;
  char* Bs = smem + 16384;
  const int tid = threadIdx.x;
  const int lane = tid & 63;
  const int wv = tid >> 6;
  const int wm = (wv >> 1) * 64, wn = (wv & 1) * 64;

  int bx = blockIdx.x, by = blockIdx.y;
  if constexpr (SWZ) {
    const int gx = gridDim.x;
    const int tot = gx * gridDim.y;
    const int lin = by * gx + bx;
    const int cpx = tot >> 3;
    const int nl = (lin & 7) * cpx + (lin >> 3);
    bx = nl % gx; by = nl / gx;
  }
  const int m0 = by * 128, n0 = bx * 128;
  const int cl = lane & 15, kg = lane >> 4;

  const int srow = tid >> 3;
  const int swz = ((tid & 7) * 16) ^ ((srow & 7) << 4);
  const int ldsb = wv * 1024;

  long arow[4], brow[4];
  #pragma unroll
  for (int is = 0; is < 4; ++is) {
    int gm = m0 + is * 32 + srow;
    long grow;
    if constexpr (AMODE == 1) {
      int bb = gm / 196, t = gm - bb * 196;
      int h2 = t / 14, w2 = t - h2 * 14;
      grow = (long)(bb * 784 + h2 * 56 + w2 * 2);
    } else {
      grow = gm;
    }
    arow[is] = grow * (long)K;
    brow[is] = (long)(n0 + is * 32 + srow) * (long)K;
  }

  f32x4 acc[4][4];
  const f32x4 zf = {0.f, 0.f, 0.f, 0.f};
  #pragma unroll
  for (int i = 0; i < 4; ++i)
    #pragma unroll
    for (int j = 0; j < 4; ++j) acc[i][j] = zf;

  for (int k0 = 0; k0 < K; k0 += 64) {
    #pragma unroll
    for (int is = 0; is < 4; ++is) {
      gload_lds16((const char*)A  + (arow[is] + k0) * 2 + swz, As + is * 4096 + ldsb);
      gload_lds16((const char*)Bt + (brow[is] + k0) * 2 + swz, Bs + is * 4096 + ldsb);
    }
    __syncthreads();
    bf16x8 afr[4][2], bfr[4][2];
    #pragma unroll
    for (int t = 0; t < 4; ++t) {
      const int ar = wm + t * 16 + cl;
      const int br = wn + t * 16 + cl;
      const int sa = (ar & 7) << 4, sb = (br & 7) << 4;
      afr[t][0] = *(const bf16x8*)(As + ar * 128 + ((kg * 16) ^ sa));
      afr[t][1] = *(const bf16x8*)(As + ar * 128 + ((64 + kg * 16) ^ sa));
      bfr[t][0] = *(const bf16x8*)(Bs + br * 128 + ((kg * 16) ^ sb));
      bfr[t][1] = *(const bf16x8*)(Bs + br * 128 + ((64 + kg * 16) ^ sb));
    }
    #pragma unroll
    for (int mt = 0; mt < 4; ++mt)
      #pragma unroll
      for (int nt = 0; nt < 4; ++nt) {
        if constexpr (EPI == 2) {
          acc[mt][nt] = mfma16(afr[mt][0], bfr[nt][0], acc[mt][nt]);
          acc[mt][nt] = mfma16(afr[mt][1], bfr[nt][1], acc[mt][nt]);
        } else {
          acc[mt][nt] = mfma16(bfr[nt][0], afr[mt][0], acc[mt][nt]);
          acc[mt][nt] = mfma16(bfr[nt][1], afr[mt][1], acc[mt][nt]);
        }
      }
    __syncthreads();
  }

  if constexpr (EPI == 2) {
    char* Cs = smem;
    #pragma unroll
    for (int mt = 0; mt < 4; ++mt) {
      const int kl = wm + mt * 16 + kg * 4;
      #pragma unroll
      for (int nt = 0; nt < 4; ++nt) {
        const int dvl = wn + nt * 16 + cl;
        const int gn = n0 + dvl;
        const float av = ea[gn], bv = eb[gn];
        union { ushort4 u; __hip_bfloat16 h[4]; } pk;
        pk.h[0] = __float2bfloat16(acc[mt][nt][0] * av + bv);
        pk.h[1] = __float2bfloat16(acc[mt][nt][1] * av + bv);
        pk.h[2] = __float2bfloat16(acc[mt][nt][2] * av + bv);
        pk.h[3] = __float2bfloat16(acc[mt][nt][3] * av + bv);
        *(ushort4*)(Cs + dvl * 272 + kl * 2) = pk.u;
      }
    }
    __syncthreads();
    const int hh = n0 >> 8;
    #pragma unroll
    for (int l = 0; l < 8; ++l) {
      const int row = l * 16 + (tid >> 4);
      const int seg = tid & 15;
      const int gm = m0 + seg * 8;
      const int bb = gm / 784, kk = gm - bb * 784;
      const int dvl = (n0 + row) & 255;
      uint4 v = *(const uint4*)(Cs + row * 272 + seg * 16);
      *(uint4*)((unsigned short*)Cout + ((long)(bb * 12 + hh) * 256 + dvl) * 784 + kk) = v;
    }
  } else {
    #pragma unroll
    for (int mt = 0; mt < 4; ++mt) {
      #pragma unroll
      for (int nt = 0; nt < 4; ++nt) {
        const int gm = m0 + wm + mt * 16 + cl;
        const int gn = n0 + wn + nt * 16 + kg * 4;
        if constexpr (EPI == 1) {
          float4 a4 = *(const float4*)(ea + gn);
          float4 b4 = *(const float4*)(eb + gn);
          union { ushort4 u; __hip_bfloat16 h[4]; } pk;
          pk.h[0] = __float2bfloat16(acc[mt][nt][0] * a4.x + b4.x);
          pk.h[1] = __float2bfloat16(acc[mt][nt][1] * a4.y + b4.y);
          pk.h[2] = __float2bfloat16(acc[mt][nt][2] * a4.z + b4.z);
          pk.h[3] = __float2bfloat16(acc[mt][nt][3] * a4.w + b4.w);
          *(ushort4*)((unsigned short*)Cout + (long)gm * N + gn) = pk.u;
        } else {
          *(float4*)((float*)Cout + (long)gm * N + gn) =
              make_float4(acc[mt][nt][0], acc[mt][nt][1], acc[mt][nt][2], acc[mt][nt][3]);
        }
      }
    }
  }
}

// ---------------------------------------------------------------------------
// Single-pass MFMA flash attention, counted-vmcnt schedule (T4).
// Per tile the vmem issue order is UNIFORM across waves/tiles:
//   bias x2 (clamped, always) -> K gload (always) -> V x4 (always)
// Raw barriers drain lgkm only; vmcnt(11) before K fragment reads guarantees
// (in-order vmcnt) this tile's K gload has landed while keeping next-tile
// K/V prefetches in flight.
// ---------------------------------------------------------------------------
#define RAW_BAR() { \
    asm volatile("s_waitcnt lgkmcnt(0)" ::: "memory"); \
    __builtin_amdgcn_sched_barrier(0); \
    __builtin_amdgcn_s_barrier(); \
    __builtin_amdgcn_sched_barrier(0); }

#define LOAD_VF(KT, V0, V1, V2, V3) { \
    const int kvo_ = (KT) * 64 + kb; \
    V0 = *(const bf16x8*)(vt + vr0 + kvo_); \
    V1 = *(const bf16x8*)(vt + vr0 + kvo_ + 32); \
    V2 = *(const bf16x8*)(vt + vr1 + kvo_); \
    V3 = *(const bf16x8*)(vt + vr1 + kvo_ + 32); }

#define ATTN_STEP(KT, CUR, VC0, VC1, VC2, VC3, VN0, VN1, VN2, VN3) { \
    const int k0_ = (KT) * 64; \
    /* ---- bias loads first (always 2 issues, clamped addresses) ---- */ \
    const int key0_ = k0_ + snt * 16 + kg * 4; \
    const int rowl0_ = mt0 * 16 + cl; \
    const int rowl1_ = (mt0 + 2) * 16 + cl; \
    const bool ok0_ = (mt0 < nmt) && (rowl0_ < valid) && (key0_ < 784); \
    const bool ok1_ = (mt0 + 2 < nmt) && (rowl1_ < valid) && (key0_ < 784); \
    const long boff0_ = ok0_ ? ((long)(qbase + rowl0_) * 784 + key0_) : 0; \
    const long boff1_ = ok1_ ? ((long)(qbase + rowl1_) * 784 + key0_) : 0; \
    float4 b40_ = *(const float4*)(bias + boff0_); \
    float4 b41_ = *(const float4*)(bias + boff1_); \
    /* ---- prefetch next K tile + next V regs (always issued) ---- */ \
    gload_lds16((const char*)kbuf + kbase + (long)(k0_ + 64) * 1536, \
                Kl[(CUR) ^ 1] + w * 1024); \
    LOAD_VF((KT) + 1, VN0, VN1, VN2, VN3); \
    /* ---- K(KT) landed: <=11 outstanding => oldest (K gload) done ---- */ \
    asm volatile("s_waitcnt vmcnt(11)" ::: "memory"); \
    __builtin_amdgcn_sched_barrier(0); \
    const char* kr_ = Kl[CUR] + krow * 128; \
    bf16x8 kk0_ = *(const bf16x8*)(kr_ + ((kg * 16) ^ ksw)); \
    bf16x8 kk1_ = *(const bf16x8*)(kr_ + ((64 + kg * 16) ^ ksw)); \
    _Pragma("unroll") \
    for (int i_ = 0; i_ < 2; ++i_) { \
      int mt_ = mt0 + 2 * i_; \
      if (mt_ >= nmt) break; \
      const bool ok_ = i_ ? ok1_ : ok0_; \
      const float4 b4_ = i_ ? b41_ : b40_; \
      bf16x8 q0_ = *(const bf16x8*)&Qs[mt_ * 16 + cl][kb]; \
      bf16x8 q1_ = *(const bf16x8*)&Qs[mt_ * 16 + cl][32 + kb]; \
      f32x4 s_ = mfma16(kk1_, q1_, mfma16(kk0_, q0_, zerof)); \
      const int rowl_ = mt_ * 16 + cl; \
      float p0_ = ok_ ? __expf(s_[0] * 0.125f + b4_.x) : 0.f; \
      float p1_ = ok_ ? __expf(s_[1] * 0.125f + b4_.y) : 0.f; \
      float p2_ = ok_ ? __expf(s_[2] * 0.125f + b4_.z) : 0.f; \
      float p3_ = ok_ ? __expf(s_[3] * 0.125f + b4_.w) : 0.f; \
      lpart[i_] += (p0_ + p1_) + (p2_ + p3_); \
      union { ushort4 u; __hip_bfloat16 hh_[4]; } pk_; \
      pk_.hh_[0] = __float2bfloat16(p0_); pk_.hh_[1] = __float2bfloat16(p1_); \
      pk_.hh_[2] = __float2bfloat16(p2_); pk_.hh_[3] = __float2bfloat16(p3_); \
      *(ushort4*)&pPs[rowl_][snt * 16 + kg * 4] = pk_.u; \
    } \
    RAW_BAR(); \
    _Pragma("unroll") \
    for (int mt_ = 0; mt_ < 4; ++mt_) { \
      if (mt_ >= nmt) break; \
      bf16x8 pa0_ = *(const bf16x8*)&pPs[mt_ * 16 + cl][kb]; \
      bf16x8 pa1_ = *(const bf16x8*)&pPs[mt_ * 16 + cl][32 + kb]; \
      acc[mt_][0] = mfma16(pa0_, VC0, acc[mt_][0]); \
      acc[mt_][0] = mfma16(pa1_, VC1, acc[mt_][0]); \
      acc[mt_][1] = mfma16(pa0_, VC2, acc[mt_][1]); \
      acc[mt_][1] = mfma16(pa1_, VC3, acc[mt_][1]); \
    } \
    RAW_BAR(); }

__global__ __launch_bounds__(512, 4) void attn_mfma(
    const unsigned short* __restrict__ kbuf, const unsigned short* __restrict__ vt,
    const unsigned short* __restrict__ qn, const float* __restrict__ bias,
    unsigned short* __restrict__ O) {
  const int p = blockIdx.x + 4 * (blockIdx.y + 12 * blockIdx.z);
  const int wrk = ((p & 7) * 192) + (p >> 3);
  const int qt = wrk & 3;
  const int hb = wrk >> 2;
  const int h = hb % 12, b = hb / 12;

  const int tid = threadIdx.x;
  const int w = tid >> 6;
  const int lane = tid & 63;
  const int cl = lane & 15;
  const int kg = lane >> 4;
  const int kb = kg * 8;
  const int qbase = qt * 64;
  const int valid = (196 - qbase) > 64 ? 64 : (196 - qbase);
  const int nmt = (valid + 15) >> 4;
  const int bh = b * 12 + h;

  __shared__ __align__(16) short Qs[64][72];
  __shared__ __align__(16) char Kl[2][8192];
  __shared__ __align__(16) short pPs[64][72];
  __shared__ float pred[4][64];
  __shared__ float lsum[64];

  const bf16x8 zero8 = {0,0,0,0,0,0,0,0};
  const f32x4 zerof = {0.f,0.f,0.f,0.f};

  const int srow = tid >> 3;
  const int ssw = ((tid & 7) * 16) ^ ((srow & 7) << 4);
  const long kbase = ((long)(b * 784 + srow) * 768 + h * 64) * 2 + ssw;

  {
    int row = tid >> 3, d8 = tid & 7;
    bf16x8 v = zero8;
    if (row < valid)
      v = *(const bf16x8*)(qn + (long)(b * 196 + qbase + row) * 768 + h * 64 + d8 * 8);
    *(bf16x8*)&Qs[row][d8 * 8] = v;
  }
  gload_lds16((const char*)kbuf + kbase, Kl[0] + w * 1024);

  const int mt0 = w >> 2, snt = w & 3;
  const long vr0 = ((long)bh * 256 + w * 32 + cl) * 784;
  const long vr1 = vr0 + (long)16 * 784;

  // prefetch V tile 0; the full __syncthreads drains everything once,
  // establishing the per-tile vmcnt invariant.
  bf16x8 vA0, vA1, vA2, vA3;
  bf16x8 vB0 = zero8, vB1 = zero8, vB2 = zero8, vB3 = zero8;
  LOAD_VF(0, vA0, vA1, vA2, vA3);
  __syncthreads();

  f32x4 acc[4][2];
  #pragma unroll
  for (int mt = 0; mt < 4; ++mt) { acc[mt][0] = zerof; acc[mt][1] = zerof; }
  float lpart[2] = {0.f, 0.f};

  const int krow = snt * 16 + cl;
  const int ksw = (krow & 7) << 4;

  for (int kt2 = 0; kt2 < 13; kt2 += 2) {
    ATTN_STEP(kt2, 0, vA0, vA1, vA2, vA3, vB0, vB1, vB2, vB3);
    if (kt2 + 1 < 13) {
      ATTN_STEP(kt2 + 1, 1, vB0, vB1, vB2, vB3, vA0, vA1, vA2, vA3);
    }
  }

  #pragma unroll
  for (int i = 0; i < 2; ++i) {
    int mt = mt0 + 2 * i;
    if (mt >= nmt) break;
    float v = lpart[i];
    v += __shfl_xor(v, 16);
    v += __shfl_xor(v, 32);
    if (kg == 0) pred[snt][mt * 16 + cl] = v;
  }
  __syncthreads();
  if (tid < 64 && tid < ((nmt * 16 < 64) ? nmt * 16 : 64))
    lsum[tid] = (pred[0][tid] + pred[1][tid]) + (pred[2][tid] + pred[3][tid]);
  else if (tid < 64)
    lsum[tid] = 1.f;
  __syncthreads();

  #pragma unroll
  for (int mt = 0; mt < 4; ++mt) {
    #pragma unroll
    for (int r = 0; r < 4; ++r) {
      const int rl = mt * 16 + kg * 4 + r;
      if (rl < valid) {
        const float inv = 1.0f / lsum[rl];
        #pragma unroll
        for (int nt2 = 0; nt2 < 2; ++nt2) {
          float ov = hswish(acc[mt][nt2][r] * inv);
          __hip_bfloat16 hv = __float2bfloat16(ov);
          O[(long)(b * 196 + qbase + rl) * 3072 + h * 256 + w * 32 + nt2 * 16 + cl] =
              *(unsigned short*)&hv;
        }
      }
    }
  }
}

// ---------------------------------------------------------------------------
extern "C" void kernel_launch(void* const* d_in, const int* in_sizes, int n_in,
                              void* d_out, int out_size, void* d_ws, size_t ws_size,
                              hipStream_t stream) {
  if (ws_size < WS_TOTAL) return;

  const float* x    = (const float*)d_in[0];
  const float* Wqkv = (const float*)d_in[1];
  const float* bn1s = (const float*)d_in[2];
  const float* Wq   = (const float*)d_in[3];
  const float* bn2s = (const float*)d_in[4];
  const float* bias = (const float*)d_in[5];
  const float* Wout = (const float*)d_in[6];

  char* ws = (char*)d_ws;
  unsigned short* kb   = (unsigned short*)(ws + OFF_K);
  unsigned short* xbT  = (unsigned short*)(ws + OFF_XBT);
  unsigned short* xqT  = (unsigned short*)(ws + OFF_XQT);
  float* t1            = (float*)(ws + OFF_T1);
  float* t2            = (float*)(ws + OFF_T2);
  unsigned short* sxb1 = (unsigned short*)(ws + OFF_SXB1);
  unsigned short* sxb2 = (unsigned short*)(ws + OFF_SXB2);
  unsigned short* vtb  = (unsigned short*)(ws + OFF_VT);
  unsigned short* qnb  = (unsigned short*)(ws + OFF_QN);
  unsigned short* xb   = (unsigned short*)(ws + OFF_XB);
  unsigned short* Ob   = (unsigned short*)(ws + OFF_O);
  unsigned short* wqkvt= (unsigned short*)(ws + OFF_WQKVT);
  unsigned short* wqt  = (unsigned short*)(ws + OFF_WQT);
  unsigned short* woutt= (unsigned short*)(ws + OFF_WOUTT);
  float* ps1  = (float*)(ws + OFF_PS1);
  float* ps2  = (float*)(ws + OFF_PS2);
  float* cs1  = (float*)(ws + OFF_CS1);
  float* cs2  = (float*)(ws + OFF_CS2);
  float* a1w  = (float*)(ws + OFF_A1);
  float* b1w  = (float*)(ws + OFF_B1);
  float* a2w  = (float*)(ws + OFF_A2);
  float* b2w  = (float*)(ws + OFF_B2);
  float* out  = (float*)d_out;

  prep_x<<<dim3(12, 784), 256, 0, stream>>>(x, xb, xbT);
  transpose_gather_bf16<<<dim3(12, 196), 256, 0, stream>>>(x, xqT);
  rowsum2_bf16<<<dim3(384, 2), 256, 0, stream>>>(xbT, xqT, cs1, cs2);

  sx_mfma<<<dim3(3, 3, CH1), 256, 0, stream>>>(xbT, ps1, M1, M1 / CH1);
  sx_mfma<<<dim3(3, 3, CH2), 256, 0, stream>>>(xqT, ps2, M2, M2 / CH2);
  reduce_conv2<<<dim3(576, 2), 256, 0, stream>>>(ps1, ps2, sxb1, sxb2);

  transpose_bf16<<<dim3(120, 12), 256, 0, stream>>>(Wqkv, wqkvt, Kc, N1);
  transpose_bf16<<<dim3(24, 12),  256, 0, stream>>>(Wq,   wqt,   Kc, Dq);
  transpose_bf16<<<dim3(16, 96),  256, 0, stream>>>(Wout, woutt, 4 * Dq, OUTD);

  gemm_mfma<0, 0><<<dim3(30, 3), 256, 0, stream>>>(sxb1, wqkvt, t1, nullptr, nullptr, N1, Kc);
  gemm_mfma<0, 0><<<dim3(6, 3),  256, 0, stream>>>(sxb2, wqt,   t2, nullptr, nullptr, Dq, Kc);
  bnfinal<<<dim3(60), 256, 0, stream>>>(Wqkv, t1, cs1, bn1s, a1w, b1w, N1, 1.f / (float)M1);
  bnfinal<<<dim3(12), 256, 0, stream>>>(Wq,   t2, cs2, bn2s, a2w, b2w, Dq, 1.f / (float)M2);

  gemm_mfma<0, 1, 1><<<dim3(6, 196), 256, 0, stream>>>(xb, wqkvt, kb, a1w, b1w, 768, Kc);
  gemm_mfma<0, 2, 1><<<dim3(24, 196), 256, 0, stream>>>(
      xb, wqkvt + (long)768 * Kc, vtb, a1w + 768, b1w + 768, 3072, Kc);
  gemm_mfma<1, 1><<<dim3(6, 49), 256, 0, stream>>>(xb, wqt, qnb, a2w, b2w, Dq, Kc);

  attn_mfma<<<dim3(4, 12, 32), 512, 0, stream>>>(kb, vtb, qnb, bias, Ob);

  gemm_mfma<0, 0><<<dim3(4, 49), 256, 0, stream>>>(Ob, woutt, out, nullptr, nullptr, OUTD, 4 * Dq);
}

// Round 15
// 433.547 us; speedup vs baseline: 1.3256x; 1.0901x over previous
//
#include <hip/hip_runtime.h>
#include <hip/hip_bf16.h>

// ---------------------------------------------------------------------------
// LeViT subsample attention (round 14).
//   = round 13 with:
//   (a) launch consolidation: prep_x+gather merged; 3 weight transposes
//       merged; 2 sx_mfma merged; 2 bnfinal merged  (20 -> 15 launches)
//   (b) attn_mfma: s_setprio(1) around the PV MFMA cluster (T5)
// ---------------------------------------------------------------------------

static constexpr int M1 = 25088, N1 = 3840, Kc = 384;
static constexpr int M2 = 6272, Dq = 768, OUTD = 512;
static constexpr int CH1 = 14, CH2 = 7;

static constexpr size_t OFF_K    = 0;
static constexpr size_t OFF_XBT  = 0;
static constexpr size_t OFF_XQT  = 19267584;
static constexpr size_t OFF_T1   = 24084480;
static constexpr size_t OFF_T2   = 29982720;
static constexpr size_t OFF_SXB1 = 31162368;
static constexpr size_t OFF_SXB2 = 31457280;
static constexpr size_t OFF_VT   = 38535168;
static constexpr size_t OFF_QN   = 192675840;
static constexpr size_t OFF_O    = 202309632;
static constexpr size_t OFF_XB   = OFF_O;
static constexpr size_t OFF_PS1  = 240844800;
static constexpr size_t OFF_WQKVT= 240844800;
static constexpr size_t OFF_WQT  = 243793920;
static constexpr size_t OFF_WOUTT= 244383744;
static constexpr size_t OFF_PS2  = 249123840;
static constexpr size_t OFF_CS1  = 253853184;
static constexpr size_t OFF_CS2  = 254444544;
static constexpr size_t OFF_A1   = 254446080;
static constexpr size_t OFF_B1   = 254461440;
static constexpr size_t OFF_A2   = 254476800;
static constexpr size_t OFF_B2   = 254479872;
static constexpr size_t WS_TOTAL = 254482944;

typedef __attribute__((ext_vector_type(8))) short bf16x8;
typedef __attribute__((ext_vector_type(4))) float f32x4;

static __device__ __forceinline__ f32x4 mfma16(bf16x8 a, bf16x8 b, f32x4 c) {
  return __builtin_amdgcn_mfma_f32_16x16x32_bf16(a, b, c, 0, 0, 0);
}

__device__ __forceinline__ void gload_lds16(const void* g, void* l) {
  __builtin_amdgcn_global_load_lds(
      (const __attribute__((address_space(1))) unsigned int*)g,
      (__attribute__((address_space(3))) unsigned int*)l, 16, 0, 0);
}

__device__ __forceinline__ float hswish(float x) {
  float t = fminf(fmaxf(x + 3.0f, 0.0f), 6.0f);
  return x * t * (1.0f / 6.0f);
}

// --------------------------- prep kernels ----------------------------------
// merged: by<784 -> xb copy + xbT transpose tile; by>=784 -> gathered xqT tile
__global__ __launch_bounds__(256) void prep_x2(
    const float* __restrict__ in, unsigned short* __restrict__ xb,
    unsigned short* __restrict__ xbT, unsigned short* __restrict__ xqT) {
  __shared__ float t[32][33];
  const int c0 = blockIdx.x * 32;
  const int x = threadIdx.x & 31, y = threadIdx.x >> 5;
  if ((int)blockIdx.y < 784) {
    const int r0 = blockIdx.y * 32;
    #pragma unroll
    for (int i = y; i < 32; i += 8) {
      float v = in[(long)(r0 + i) * 384 + c0 + x];
      t[i][x] = v;
      __hip_bfloat16 hv = __float2bfloat16(v);
      xb[(long)(r0 + i) * 384 + c0 + x] = *(unsigned short*)&hv;
    }
    __syncthreads();
    #pragma unroll
    for (int i = y; i < 32; i += 8) {
      __hip_bfloat16 v = __float2bfloat16(t[x][i]);
      xbT[(long)(c0 + i) * 25088 + r0 + x] = *(unsigned short*)&v;
    }
  } else {
    const int r0 = (blockIdx.y - 784) * 32;
    #pragma unroll
    for (int i = y; i < 32; i += 8) {
      int m2 = r0 + i;
      int bb = m2 / 196, tt = m2 - bb * 196;
      int h2 = tt / 14, w2 = tt - h2 * 14;
      long grow = (long)(bb * 784 + h2 * 56 + w2 * 2);
      t[i][x] = in[grow * 384 + c0 + x];
    }
    __syncthreads();
    #pragma unroll
    for (int i = y; i < 32; i += 8) {
      __hip_bfloat16 v = __float2bfloat16(t[x][i]);
      xqT[(long)(c0 + i) * 6272 + r0 + x] = *(unsigned short*)&v;
    }
  }
}

// merged weight transposes: [0,1440) Wqkv; [1440,1728) Wq; [1728,3264) Wout
__global__ __launch_bounds__(256) void transpose3(
    const float* __restrict__ Wqkv, const float* __restrict__ Wq,
    const float* __restrict__ Wout, unsigned short* __restrict__ wqkvt,
    unsigned short* __restrict__ wqt, unsigned short* __restrict__ woutt) {
  __shared__ float t[32][33];
  const int id = blockIdx.x;
  const float* in; unsigned short* out; int R, C, c0, r0;
  if (id < 1440)      { in = Wqkv; out = wqkvt; R = 384;  C = 3840;
                        c0 = (id % 120) * 32; r0 = (id / 120) * 32; }
  else if (id < 1728) { int i = id - 1440; in = Wq; out = wqt; R = 384; C = 768;
                        c0 = (i % 24) * 32; r0 = (i / 24) * 32; }
  else                { int i = id - 1728; in = Wout; out = woutt; R = 3072; C = 512;
                        c0 = (i % 16) * 32; r0 = (i / 16) * 32; }
  const int x = threadIdx.x & 31, y = threadIdx.x >> 5;
  #pragma unroll
  for (int i = y; i < 32; i += 8) t[i][x] = in[(long)(r0 + i) * C + c0 + x];
  __syncthreads();
  #pragma unroll
  for (int i = y; i < 32; i += 8) {
    __hip_bfloat16 v = __float2bfloat16(t[x][i]);
    out[(long)(c0 + i) * R + r0 + x] = *(unsigned short*)&v;
  }
}

__global__ __launch_bounds__(256) void rowsum2_bf16(
    const unsigned short* __restrict__ srcA, const unsigned short* __restrict__ srcB,
    float* __restrict__ dstA, float* __restrict__ dstB) {
  const int z = blockIdx.y;
  const unsigned short* src = z ? srcB : srcA;
  float* dst = z ? dstB : dstA;
  const int ncols = z ? M2 : M1;
  const long base = (long)blockIdx.x * ncols;
  float s = 0.f;
  for (int c = threadIdx.x * 8; c < ncols; c += 2048) {
    bf16x8 v = *(const bf16x8*)(src + base + c);
    #pragma unroll
    for (int j = 0; j < 8; ++j)
      s += __uint_as_float(((unsigned)(unsigned short)v[j]) << 16);
  }
  __shared__ float red[256];
  red[threadIdx.x] = s;
  __syncthreads();
  for (int st = 128; st > 0; st >>= 1) {
    if (threadIdx.x < st) red[threadIdx.x] += red[threadIdx.x + st];
    __syncthreads();
  }
  if (threadIdx.x == 0) dst[blockIdx.x] = red[0];
}

__global__ __launch_bounds__(256) void reduce_conv2(
    const float* __restrict__ srcA, const float* __restrict__ srcB,
    unsigned short* __restrict__ dstA, unsigned short* __restrict__ dstB) {
  const int z = blockIdx.y;
  const float* src = z ? srcB : srcA;
  unsigned short* dstb = z ? dstB : dstA;
  const int nchunks = z ? CH2 : CH1;
  int i = blockIdx.x * 256 + threadIdx.x;
  float s = 0.f;
  for (int c = 0; c < nchunks; ++c) s += src[(long)c * 147456 + i];
  __hip_bfloat16 hv = __float2bfloat16(s);
  dstb[i] = *(unsigned short*)&hv;
}

// --------------------------- BN finalize (merged) --------------------------
// blocks [0,60): N1 variant; [60,72): Dq variant
__global__ __launch_bounds__(256) void bnfinal2(
    const float* __restrict__ W1, const float* __restrict__ T1v,
    const float* __restrict__ cs1, const float* __restrict__ s1,
    float* __restrict__ a1, float* __restrict__ b1,
    const float* __restrict__ W2, const float* __restrict__ T2v,
    const float* __restrict__ cs2, const float* __restrict__ s2,
    float* __restrict__ a2, float* __restrict__ b2) {
  const int id = blockIdx.x;
  const float *W, *T, *cs, *scale; float *a, *b; int N; float invM; int jb;
  if (id < 60) { W = W1; T = T1v; cs = cs1; scale = s1; a = a1; b = b1;
                 N = N1; invM = 1.f / (float)M1; jb = id; }
  else         { W = W2; T = T2v; cs = cs2; scale = s2; a = a2; b = b2;
                 N = Dq; invM = 1.f / (float)M2; jb = id - 60; }
  const int j = jb * 64 + (threadIdx.x & 63);
  const int rq = threadIdx.x >> 6;
  float yy = 0.f, mu = 0.f;
  for (int k = rq * 96; k < rq * 96 + 96; ++k) {
    float w = W[(long)k * N + j];
    yy += w * T[(long)k * N + j];
    mu += cs[k] * w;
  }
  __shared__ float r1[256], r2[256];
  r1[threadIdx.x] = yy; r2[threadIdx.x] = mu;
  __syncthreads();
  if (threadIdx.x < 64) {
    int t = threadIdx.x;
    yy = r1[t] + r1[t + 64] + r1[t + 128] + r1[t + 192];
    mu = r2[t] + r2[t + 64] + r2[t + 128] + r2[t + 192];
    float mean = mu * invM;
    float var = yy * invM - mean * mean;
    float ai = rsqrtf(var + 1e-5f) * scale[j];
    a[j] = ai;
    b[j] = -mean * ai;
  }
}

// ---------------------------------------------------------------------------
// split-K MFMA X @ X^T, merged: z<CH1 -> xbT chunk z; else xqT chunk z-CH1
// ---------------------------------------------------------------------------
__global__ __launch_bounds__(256) void sx_mfma2(
    const unsigned short* __restrict__ XA, const unsigned short* __restrict__ XB,
    float* __restrict__ psA, float* __restrict__ psB) {
  const unsigned short* X; float* Cp; int Kfull, Kchunk, zi;
  if ((int)blockIdx.z < CH1) { X = XA; Cp = psA; Kfull = M1; Kchunk = M1 / CH1; zi = blockIdx.z; }
  else { X = XB; Cp = psB; Kfull = M2; Kchunk = M2 / CH2; zi = blockIdx.z - CH1; }

  __shared__ __align__(16) char As[16384];
  __shared__ __align__(16) char Bs[16384];
  const int tid = threadIdx.x;
  const int lane = tid & 63;
  const int wv = tid >> 6;
  const int wm = (wv >> 1) * 64, wn = (wv & 1) * 64;
  const int m0 = blockIdx.y * 128, n0 = blockIdx.x * 128;
  const int cl = lane & 15, kg = lane >> 4;
  const int srow = tid >> 3;
  const int swz = ((tid & 7) * 16) ^ ((srow & 7) << 4);
  const int ldsb = wv * 1024;
  const long zbase = (long)zi * Kchunk;

  long arow[4], brow[4];
  #pragma unroll
  for (int is = 0; is < 4; ++is) {
    arow[is] = (long)(m0 + is * 32 + srow) * Kfull + zbase;
    brow[is] = (long)(n0 + is * 32 + srow) * Kfull + zbase;
  }

  f32x4 acc[4][4];
  const f32x4 zf = {0.f, 0.f, 0.f, 0.f};
  #pragma unroll
  for (int i = 0; i < 4; ++i)
    #pragma unroll
    for (int j = 0; j < 4; ++j) acc[i][j] = zf;

  for (int k0 = 0; k0 < Kchunk; k0 += 64) {
    #pragma unroll
    for (int is = 0; is < 4; ++is) {
      gload_lds16((const char*)X + (arow[is] + k0) * 2 + swz, As + is * 4096 + ldsb);
      gload_lds16((const char*)X + (brow[is] + k0) * 2 + swz, Bs + is * 4096 + ldsb);
    }
    __syncthreads();
    bf16x8 afr[4][2], bfr[4][2];
    #pragma unroll
    for (int t = 0; t < 4; ++t) {
      const int ar = wm + t * 16 + cl;
      const int br = wn + t * 16 + cl;
      const int sa = (ar & 7) << 4, sb = (br & 7) << 4;
      afr[t][0] = *(const bf16x8*)(As + ar * 128 + ((kg * 16) ^ sa));
      afr[t][1] = *(const bf16x8*)(As + ar * 128 + ((64 + kg * 16) ^ sa));
      bfr[t][0] = *(const bf16x8*)(Bs + br * 128 + ((kg * 16) ^ sb));
      bfr[t][1] = *(const bf16x8*)(Bs + br * 128 + ((64 + kg * 16) ^ sb));
    }
    #pragma unroll
    for (int mt = 0; mt < 4; ++mt)
      #pragma unroll
      for (int nt = 0; nt < 4; ++nt) {
        acc[mt][nt] = mfma16(bfr[nt][0], afr[mt][0], acc[mt][nt]);
        acc[mt][nt] = mfma16(bfr[nt][1], afr[mt][1], acc[mt][nt]);
      }
    __syncthreads();
  }

  float* Cpz = Cp + (long)zi * 384 * 384;
  #pragma unroll
  for (int mt = 0; mt < 4; ++mt) {
    const int gm = m0 + wm + mt * 16 + cl;
    #pragma unroll
    for (int nt = 0; nt < 4; ++nt) {
      const int gn = n0 + wn + nt * 16 + kg * 4;
      *(float4*)(Cpz + (long)gm * 384 + gn) =
          make_float4(acc[mt][nt][0], acc[mt][nt][1], acc[mt][nt][2], acc[mt][nt][3]);
    }
  }
}

// ---------------------------------------------------------------------------
// bf16 MFMA GEMM: C = A[M,K] @ Bt[N,K]^T.  SWZ: XCD chunked remap.
// ---------------------------------------------------------------------------
template<int AMODE, int EPI, int SWZ = 0>
__global__ __launch_bounds__(256) void gemm_mfma(
    const unsigned short* __restrict__ A, const unsigned short* __restrict__ Bt,
    void* __restrict__ Cout, const float* __restrict__ ea, const float* __restrict__ eb,
    int N, int K) {
  constexpr int SMEM_BYTES = (EPI == 2) ? 34816 : 32768;
  __shared__ __align__(16) char smem[SMEM_BYTES];
  char* As = smem;
  char* Bs = smem + 16384;
  const int tid = threadIdx.x;
  const int lane = tid & 63;
  const int wv = tid >> 6;
  const int wm = (wv >> 1) * 64, wn = (wv & 1) * 64;

  int bx = blockIdx.x, by = blockIdx.y;
  if constexpr (SWZ) {
    const int gx = gridDim.x;
    const int tot = gx * gridDim.y;
    const int lin = by * gx + bx;
    const int cpx = tot >> 3;
    const int nl = (lin & 7) * cpx + (lin >> 3);
    bx = nl % gx; by = nl / gx;
  }
  const int m0 = by * 128, n0 = bx * 128;
  const int cl = lane & 15, kg = lane >> 4;

  const int srow = tid >> 3;
  const int swz = ((tid & 7) * 16) ^ ((srow & 7) << 4);
  const int ldsb = wv * 1024;

  long arow[4], brow[4];
  #pragma unroll
  for (int is = 0; is < 4; ++is) {
    int gm = m0 + is * 32 + srow;
    long grow;
    if constexpr (AMODE == 1) {
      int bb = gm / 196, t = gm - bb * 196;
      int h2 = t / 14, w2 = t - h2 * 14;
      grow = (long)(bb * 784 + h2 * 56 + w2 * 2);
    } else {
      grow = gm;
    }
    arow[is] = grow * (long)K;
    brow[is] = (long)(n0 + is * 32 + srow) * (long)K;
  }

  f32x4 acc[4][4];
  const f32x4 zf = {0.f, 0.f, 0.f, 0.f};
  #pragma unroll
  for (int i = 0; i < 4; ++i)
    #pragma unroll
    for (int j = 0; j < 4; ++j) acc[i][j] = zf;

  for (int k0 = 0; k0 < K; k0 += 64) {
    #pragma unroll
    for (int is = 0; is < 4; ++is) {
      gload_lds16((const char*)A  + (arow[is] + k0) * 2 + swz, As + is * 4096 + ldsb);
      gload_lds16((const char*)Bt + (brow[is] + k0) * 2 + swz, Bs + is * 4096 + ldsb);
    }
    __syncthreads();
    bf16x8 afr[4][2], bfr[4][2];
    #pragma unroll
    for (int t = 0; t < 4; ++t) {
      const int ar = wm + t * 16 + cl;
      const int br = wn + t * 16 + cl;
      const int sa = (ar & 7) << 4, sb = (br & 7) << 4;
      afr[t][0] = *(const bf16x8*)(As + ar * 128 + ((kg * 16) ^ sa));
      afr[t][1] = *(const bf16x8*)(As + ar * 128 + ((64 + kg * 16) ^ sa));
      bfr[t][0] = *(const bf16x8*)(Bs + br * 128 + ((kg * 16) ^ sb));
      bfr[t][1] = *(const bf16x8*)(Bs + br * 128 + ((64 + kg * 16) ^ sb));
    }
    #pragma unroll
    for (int mt = 0; mt < 4; ++mt)
      #pragma unroll
      for (int nt = 0; nt < 4; ++nt) {
        if constexpr (EPI == 2) {
          acc[mt][nt] = mfma16(afr[mt][0], bfr[nt][0], acc[mt][nt]);
          acc[mt][nt] = mfma16(afr[mt][1], bfr[nt][1], acc[mt][nt]);
        } else {
          acc[mt][nt] = mfma16(bfr[nt][0], afr[mt][0], acc[mt][nt]);
          acc[mt][nt] = mfma16(bfr[nt][1], afr[mt][1], acc[mt][nt]);
        }
      }
    __syncthreads();
  }

  if constexpr (EPI == 2) {
    char* Cs = smem;
    #pragma unroll
    for (int mt = 0; mt < 4; ++mt) {
      const int kl = wm + mt * 16 + kg * 4;
      #pragma unroll
      for (int nt = 0; nt < 4; ++nt) {
        const int dvl = wn + nt * 16 + cl;
        const int gn = n0 + dvl;
        const float av = ea[gn], bv = eb[gn];
        union { ushort4 u; __hip_bfloat16 h[4]; } pk;
        pk.h[0] = __float2bfloat16(acc[mt][nt][0] * av + bv);
        pk.h[1] = __float2bfloat16(acc[mt][nt][1] * av + bv);
        pk.h[2] = __float2bfloat16(acc[mt][nt][2] * av + bv);
        pk.h[3] = __float2bfloat16(acc[mt][nt][3] * av + bv);
        *(ushort4*)(Cs + dvl * 272 + kl * 2) = pk.u;
      }
    }
    __syncthreads();
    const int hh = n0 >> 8;
    #pragma unroll
    for (int l = 0; l < 8; ++l) {
      const int row = l * 16 + (tid >> 4);
      const int seg = tid & 15;
      const int gm = m0 + seg * 8;
      const int bb = gm / 784, kk = gm - bb * 784;
      const int dvl = (n0 + row) & 255;
      uint4 v = *(const uint4*)(Cs + row * 272 + seg * 16);
      *(uint4*)((unsigned short*)Cout + ((long)(bb * 12 + hh) * 256 + dvl) * 784 + kk) = v;
    }
  } else {
    #pragma unroll
    for (int mt = 0; mt < 4; ++mt) {
      #pragma unroll
      for (int nt = 0; nt < 4; ++nt) {
        const int gm = m0 + wm + mt * 16 + cl;
        const int gn = n0 + wn + nt * 16 + kg * 4;
        if constexpr (EPI == 1) {
          float4 a4 = *(const float4*)(ea + gn);
          float4 b4 = *(const float4*)(eb + gn);
          union { ushort4 u; __hip_bfloat16 h[4]; } pk;
          pk.h[0] = __float2bfloat16(acc[mt][nt][0] * a4.x + b4.x);
          pk.h[1] = __float2bfloat16(acc[mt][nt][1] * a4.y + b4.y);
          pk.h[2] = __float2bfloat16(acc[mt][nt][2] * a4.z + b4.z);
          pk.h[3] = __float2bfloat16(acc[mt][nt][3] * a4.w + b4.w);
          *(ushort4*)((unsigned short*)Cout + (long)gm * N + gn) = pk.u;
        } else {
          *(float4*)((float*)Cout + (long)gm * N + gn) =
              make_float4(acc[mt][nt][0], acc[mt][nt][1], acc[mt][nt][2], acc[mt][nt][3]);
        }
      }
    }
  }
}

// ---------------------------------------------------------------------------
// Single-pass MFMA flash attention, counted-vmcnt schedule (round-13) +
// s_setprio around the PV MFMA cluster (T5).
// ---------------------------------------------------------------------------
#define RAW_BAR() { \
    asm volatile("s_waitcnt lgkmcnt(0)" ::: "memory"); \
    __builtin_amdgcn_sched_barrier(0); \
    __builtin_amdgcn_s_barrier(); \
    __builtin_amdgcn_sched_barrier(0); }

#define LOAD_VF(KT, V0, V1, V2, V3) { \
    const int kvo_ = (KT) * 64 + kb; \
    V0 = *(const bf16x8*)(vt + vr0 + kvo_); \
    V1 = *(const bf16x8*)(vt + vr0 + kvo_ + 32); \
    V2 = *(const bf16x8*)(vt + vr1 + kvo_); \
    V3 = *(const bf16x8*)(vt + vr1 + kvo_ + 32); }

#define ATTN_STEP(KT, CUR, VC0, VC1, VC2, VC3, VN0, VN1, VN2, VN3) { \
    const int k0_ = (KT) * 64; \
    const int key0_ = k0_ + snt * 16 + kg * 4; \
    const int rowl0_ = mt0 * 16 + cl; \
    const int rowl1_ = (mt0 + 2) * 16 + cl; \
    const bool ok0_ = (mt0 < nmt) && (rowl0_ < valid) && (key0_ < 784); \
    const bool ok1_ = (mt0 + 2 < nmt) && (rowl1_ < valid) && (key0_ < 784); \
    const long boff0_ = ok0_ ? ((long)(qbase + rowl0_) * 784 + key0_) : 0; \
    const long boff1_ = ok1_ ? ((long)(qbase + rowl1_) * 784 + key0_) : 0; \
    float4 b40_ = *(const float4*)(bias + boff0_); \
    float4 b41_ = *(const float4*)(bias + boff1_); \
    gload_lds16((const char*)kbuf + kbase + (long)(k0_ + 64) * 1536, \
                Kl[(CUR) ^ 1] + w * 1024); \
    LOAD_VF((KT) + 1, VN0, VN1, VN2, VN3); \
    asm volatile("s_waitcnt vmcnt(11)" ::: "memory"); \
    __builtin_amdgcn_sched_barrier(0); \
    const char* kr_ = Kl[CUR] + krow * 128; \
    bf16x8 kk0_ = *(const bf16x8*)(kr_ + ((kg * 16) ^ ksw)); \
    bf16x8 kk1_ = *(const bf16x8*)(kr_ + ((64 + kg * 16) ^ ksw)); \
    _Pragma("unroll") \
    for (int i_ = 0; i_ < 2; ++i_) { \
      int mt_ = mt0 + 2 * i_; \
      if (mt_ >= nmt) break; \
      const bool ok_ = i_ ? ok1_ : ok0_; \
      const float4 b4_ = i_ ? b41_ : b40_; \
      bf16x8 q0_ = *(const bf16x8*)&Qs[mt_ * 16 + cl][kb]; \
      bf16x8 q1_ = *(const bf16x8*)&Qs[mt_ * 16 + cl][32 + kb]; \
      f32x4 s_ = mfma16(kk1_, q1_, mfma16(kk0_, q0_, zerof)); \
      const int rowl_ = mt_ * 16 + cl; \
      float p0_ = ok_ ? __expf(s_[0] * 0.125f + b4_.x) : 0.f; \
      float p1_ = ok_ ? __expf(s_[1] * 0.125f + b4_.y) : 0.f; \
      float p2_ = ok_ ? __expf(s_[2] * 0.125f + b4_.z) : 0.f; \
      float p3_ = ok_ ? __expf(s_[3] * 0.125f + b4_.w) : 0.f; \
      lpart[i_] += (p0_ + p1_) + (p2_ + p3_); \
      union { ushort4 u; __hip_bfloat16 hh_[4]; } pk_; \
      pk_.hh_[0] = __float2bfloat16(p0_); pk_.hh_[1] = __float2bfloat16(p1_); \
      pk_.hh_[2] = __float2bfloat16(p2_); pk_.hh_[3] = __float2bfloat16(p3_); \
      *(ushort4*)&pPs[rowl_][snt * 16 + kg * 4] = pk_.u; \
    } \
    RAW_BAR(); \
    __builtin_amdgcn_s_setprio(1); \
    _Pragma("unroll") \
    for (int mt_ = 0; mt_ < 4; ++mt_) { \
      if (mt_ >= nmt) break; \
      bf16x8 pa0_ = *(const bf16x8*)&pPs[mt_ * 16 + cl][kb]; \
      bf16x8 pa1_ = *(const bf16x8*)&pPs[mt_ * 16 + cl][32 + kb]; \
      acc[mt_][0] = mfma16(pa0_, VC0, acc[mt_][0]); \
      acc[mt_][0] = mfma16(pa1_, VC1, acc[mt_][0]); \
      acc[mt_][1] = mfma16(pa0_, VC2, acc[mt_][1]); \
      acc[mt_][1] = mfma16(pa1_, VC3, acc[mt_][1]); \
    } \
    __builtin_amdgcn_s_setprio(0); \
    RAW_BAR(); }

__global__ __launch_bounds__(512, 4) void attn_mfma(
    const unsigned short* __restrict__ kbuf, const unsigned short* __restrict__ vt,
    const unsigned short* __restrict__ qn, const float* __restrict__ bias,
    unsigned short* __restrict__ O) {
  const int p = blockIdx.x + 4 * (blockIdx.y + 12 * blockIdx.z);
  const int wrk = ((p & 7) * 192) + (p >> 3);
  const int qt = wrk & 3;
  const int hb = wrk >> 2;
  const int h = hb % 12, b = hb / 12;

  const int tid = threadIdx.x;
  const int w = tid >> 6;
  const int lane = tid & 63;
  const int cl = lane & 15;
  const int kg = lane >> 4;
  const int kb = kg * 8;
  const int qbase = qt * 64;
  const int valid = (196 - qbase) > 64 ? 64 : (196 - qbase);
  const int nmt = (valid + 15) >> 4;
  const int bh = b * 12 + h;

  __shared__ __align__(16) short Qs[64][72];
  __shared__ __align__(16) char Kl[2][8192];
  __shared__ __align__(16) short pPs[64][72];
  __shared__ float pred[4][64];
  __shared__ float lsum[64];

  const bf16x8 zero8 = {0,0,0,0,0,0,0,0};
  const f32x4 zerof = {0.f,0.f,0.f,0.f};

  const int srow = tid >> 3;
  const int ssw = ((tid & 7) * 16) ^ ((srow & 7) << 4);
  const long kbase = ((long)(b * 784 + srow) * 768 + h * 64) * 2 + ssw;

  {
    int row = tid >> 3, d8 = tid & 7;
    bf16x8 v = zero8;
    if (row < valid)
      v = *(const bf16x8*)(qn + (long)(b * 196 + qbase + row) * 768 + h * 64 + d8 * 8);
    *(bf16x8*)&Qs[row][d8 * 8] = v;
  }
  gload_lds16((const char*)kbuf + kbase, Kl[0] + w * 1024);

  const int mt0 = w >> 2, snt = w & 3;
  const long vr0 = ((long)bh * 256 + w * 32 + cl) * 784;
  const long vr1 = vr0 + (long)16 * 784;

  bf16x8 vA0, vA1, vA2, vA3;
  bf16x8 vB0 = zero8, vB1 = zero8, vB2 = zero8, vB3 = zero8;
  LOAD_VF(0, vA0, vA1, vA2, vA3);
  __syncthreads();

  f32x4 acc[4][2];
  #pragma unroll
  for (int mt = 0; mt < 4; ++mt) { acc[mt][0] = zerof; acc[mt][1] = zerof; }
  float lpart[2] = {0.f, 0.f};

  const int krow = snt * 16 + cl;
  const int ksw = (krow & 7) << 4;

  for (int kt2 = 0; kt2 < 13; kt2 += 2) {
    ATTN_STEP(kt2, 0, vA0, vA1, vA2, vA3, vB0, vB1, vB2, vB3);
    if (kt2 + 1 < 13) {
      ATTN_STEP(kt2 + 1, 1, vB0, vB1, vB2, vB3, vA0, vA1, vA2, vA3);
    }
  }

  #pragma unroll
  for (int i = 0; i < 2; ++i) {
    int mt = mt0 + 2 * i;
    if (mt >= nmt) break;
    float v = lpart[i];
    v += __shfl_xor(v, 16);
    v += __shfl_xor(v, 32);
    if (kg == 0) pred[snt][mt * 16 + cl] = v;
  }
  __syncthreads();
  if (tid < 64 && tid < ((nmt * 16 < 64) ? nmt * 16 : 64))
    lsum[tid] = (pred[0][tid] + pred[1][tid]) + (pred[2][tid] + pred[3][tid]);
  else if (tid < 64)
    lsum[tid] = 1.f;
  __syncthreads();

  #pragma unroll
  for (int mt = 0; mt < 4; ++mt) {
    #pragma unroll
    for (int r = 0; r < 4; ++r) {
      const int rl = mt * 16 + kg * 4 + r;
      if (rl < valid) {
        const float inv = 1.0f / lsum[rl];
        #pragma unroll
        for (int nt2 = 0; nt2 < 2; ++nt2) {
          float ov = hswish(acc[mt][nt2][r] * inv);
          __hip_bfloat16 hv = __float2bfloat16(ov);
          O[(long)(b * 196 + qbase + rl) * 3072 + h * 256 + w * 32 + nt2 * 16 + cl] =
              *(unsigned short*)&hv;
        }
      }
    }
  }
}

// ---------------------------------------------------------------------------
extern "C" void kernel_launch(void* const* d_in, const int* in_sizes, int n_in,
                              void* d_out, int out_size, void* d_ws, size_t ws_size,
                              hipStream_t stream) {
  if (ws_size < WS_TOTAL) return;

  const float* x    = (const float*)d_in[0];
  const float* Wqkv = (const float*)d_in[1];
  const float* bn1s = (const float*)d_in[2];
  const float* Wq   = (const float*)d_in[3];
  const float* bn2s = (const float*)d_in[4];
  const float* bias = (const float*)d_in[5];
  const float* Wout = (const float*)d_in[6];

  char* ws = (char*)d_ws;
  unsigned short* kb   = (unsigned short*)(ws + OFF_K);
  unsigned short* xbT  = (unsigned short*)(ws + OFF_XBT);
  unsigned short* xqT  = (unsigned short*)(ws + OFF_XQT);
  float* t1            = (float*)(ws + OFF_T1);
  float* t2            = (float*)(ws + OFF_T2);
  unsigned short* sxb1 = (unsigned short*)(ws + OFF_SXB1);
  unsigned short* sxb2 = (unsigned short*)(ws + OFF_SXB2);
  unsigned short* vtb  = (unsigned short*)(ws + OFF_VT);
  unsigned short* qnb  = (unsigned short*)(ws + OFF_QN);
  unsigned short* xb   = (unsigned short*)(ws + OFF_XB);
  unsigned short* Ob   = (unsigned short*)(ws + OFF_O);
  unsigned short* wqkvt= (unsigned short*)(ws + OFF_WQKVT);
  unsigned short* wqt  = (unsigned short*)(ws + OFF_WQT);
  unsigned short* woutt= (unsigned short*)(ws + OFF_WOUTT);
  float* ps1  = (float*)(ws + OFF_PS1);
  float* ps2  = (float*)(ws + OFF_PS2);
  float* cs1  = (float*)(ws + OFF_CS1);
  float* cs2  = (float*)(ws + OFF_CS2);
  float* a1w  = (float*)(ws + OFF_A1);
  float* b1w  = (float*)(ws + OFF_B1);
  float* a2w  = (float*)(ws + OFF_A2);
  float* b2w  = (float*)(ws + OFF_B2);
  float* out  = (float*)d_out;

  // prep (merged): xb + xbT + xqT in one launch
  prep_x2<<<dim3(12, 980), 256, 0, stream>>>(x, xb, xbT, xqT);
  rowsum2_bf16<<<dim3(384, 2), 256, 0, stream>>>(xbT, xqT, cs1, cs2);

  // Sx via split-K MFMA (merged) + fused reduce/convert
  sx_mfma2<<<dim3(3, 3, CH1 + CH2), 256, 0, stream>>>(xbT, xqT, ps1, ps2);
  reduce_conv2<<<dim3(576, 2), 256, 0, stream>>>(ps1, ps2, sxb1, sxb2);

  // weight transposes (merged; overwrite ps1 region - dead after reduce)
  transpose3<<<dim3(3264), 256, 0, stream>>>(Wqkv, Wq, Wout, wqkvt, wqt, woutt);

  // BN coefficients
  gemm_mfma<0, 0><<<dim3(30, 3), 256, 0, stream>>>(sxb1, wqkvt, t1, nullptr, nullptr, N1, Kc);
  gemm_mfma<0, 0><<<dim3(6, 3),  256, 0, stream>>>(sxb2, wqt,   t2, nullptr, nullptr, Dq, Kc);
  bnfinal2<<<dim3(72), 256, 0, stream>>>(Wqkv, t1, cs1, bn1s, a1w, b1w,
                                         Wq,   t2, cs2, bn2s, a2w, b2w);

  // projections
  gemm_mfma<0, 1, 1><<<dim3(6, 196), 256, 0, stream>>>(xb, wqkvt, kb, a1w, b1w, 768, Kc);
  gemm_mfma<0, 2, 1><<<dim3(24, 196), 256, 0, stream>>>(
      xb, wqkvt + (long)768 * Kc, vtb, a1w + 768, b1w + 768, 3072, Kc);
  gemm_mfma<1, 1><<<dim3(6, 49), 256, 0, stream>>>(xb, wqt, qnb, a2w, b2w, Dq, Kc);

  // attention -> hswish(O)
  attn_mfma<<<dim3(4, 12, 32), 512, 0, stream>>>(kb, vtb, qnb, bias, Ob);

  // out = O @ Wout^T
  gemm_mfma<0, 0><<<dim3(4, 49), 256, 0, stream>>>(Ob, woutt, out, nullptr, nullptr, OUTD, 4 * Dq);
}

// Round 17
// 374.347 us; speedup vs baseline: 1.5353x; 1.1581x over previous
//
#include <hip/hip_runtime.h>
#include <hip/hip_bf16.h>

// ---------------------------------------------------------------------------
// LeViT subsample attention (round 16) = round 15 with the workspace-lifetime
// bug fixed: PS1 moved into the (then-dead) VT region so sx_mfma2 no longer
// clobbers the transposed weights written early by prep_all.
//   lifetimes: ps1 [sx_mfma2 .. reduce_conv2] nested inside VT-dead window
//   [start .. proj_merged]; weights written by prep_all live to the end.
// ---------------------------------------------------------------------------

static constexpr int M1 = 25088, N1 = 3840, Kc = 384;
static constexpr int M2 = 6272, Dq = 768, OUTD = 512;
static constexpr int CH1 = 14, CH2 = 7;

static constexpr size_t OFF_K    = 0;
static constexpr size_t OFF_XBT  = 0;
static constexpr size_t OFF_XQT  = 19267584;
static constexpr size_t OFF_T1   = 24084480;
static constexpr size_t OFF_T2   = 29982720;
static constexpr size_t OFF_SXB1 = 31162368;
static constexpr size_t OFF_SXB2 = 31457280;
static constexpr size_t OFF_VT   = 38535168;
static constexpr size_t OFF_PS1  = 38535168;     // inside VT region (dead until proj)
static constexpr size_t OFF_QN   = 192675840;
static constexpr size_t OFF_O    = 202309632;
static constexpr size_t OFF_XB   = OFF_O;
static constexpr size_t OFF_WQKVT= 240844800;    // written by prep_all, live to end
static constexpr size_t OFF_WQT  = 243793920;
static constexpr size_t OFF_WOUTT= 244383744;    // ends 247529472
static constexpr size_t OFF_PS2  = 249123840;    // ends 253252608 (no overlap)
static constexpr size_t OFF_CS1  = 253853184;
static constexpr size_t OFF_CS2  = 254444544;
static constexpr size_t OFF_A1   = 254446080;
static constexpr size_t OFF_B1   = 254461440;
static constexpr size_t OFF_A2   = 254476800;
static constexpr size_t OFF_B2   = 254479872;
static constexpr size_t WS_TOTAL = 254482944;

typedef __attribute__((ext_vector_type(8))) short bf16x8;
typedef __attribute__((ext_vector_type(4))) float f32x4;

static __device__ __forceinline__ f32x4 mfma16(bf16x8 a, bf16x8 b, f32x4 c) {
  return __builtin_amdgcn_mfma_f32_16x16x32_bf16(a, b, c, 0, 0, 0);
}

__device__ __forceinline__ void gload_lds16(const void* g, void* l) {
  __builtin_amdgcn_global_load_lds(
      (const __attribute__((address_space(1))) unsigned int*)g,
      (__attribute__((address_space(3))) unsigned int*)l, 16, 0, 0);
}

__device__ __forceinline__ float hswish(float x) {
  float t = fminf(fmaxf(x + 3.0f, 0.0f), 6.0f);
  return x * t * (1.0f / 6.0f);
}

// --------------------------- prep (all transposes) -------------------------
__global__ __launch_bounds__(256) void prep_all(
    const float* __restrict__ in, unsigned short* __restrict__ xb,
    unsigned short* __restrict__ xbT, unsigned short* __restrict__ xqT,
    const float* __restrict__ Wqkv, const float* __restrict__ Wq,
    const float* __restrict__ Wout, unsigned short* __restrict__ wqkvt,
    unsigned short* __restrict__ wqt, unsigned short* __restrict__ woutt) {
  __shared__ float t[32][33];
  const int x = threadIdx.x & 31, y = threadIdx.x >> 5;
  const int id = blockIdx.x;
  if (id < 11760) {
    const int c0 = (id % 12) * 32;
    const int by = id / 12;
    if (by < 784) {
      const int r0 = by * 32;
      #pragma unroll
      for (int i = y; i < 32; i += 8) {
        float v = in[(long)(r0 + i) * 384 + c0 + x];
        t[i][x] = v;
        __hip_bfloat16 hv = __float2bfloat16(v);
        xb[(long)(r0 + i) * 384 + c0 + x] = *(unsigned short*)&hv;
      }
      __syncthreads();
      #pragma unroll
      for (int i = y; i < 32; i += 8) {
        __hip_bfloat16 v = __float2bfloat16(t[x][i]);
        xbT[(long)(c0 + i) * 25088 + r0 + x] = *(unsigned short*)&v;
      }
    } else {
      const int r0 = (by - 784) * 32;
      #pragma unroll
      for (int i = y; i < 32; i += 8) {
        int m2 = r0 + i;
        int bb = m2 / 196, tt = m2 - bb * 196;
        int h2 = tt / 14, w2 = tt - h2 * 14;
        long grow = (long)(bb * 784 + h2 * 56 + w2 * 2);
        t[i][x] = in[grow * 384 + c0 + x];
      }
      __syncthreads();
      #pragma unroll
      for (int i = y; i < 32; i += 8) {
        __hip_bfloat16 v = __float2bfloat16(t[x][i]);
        xqT[(long)(c0 + i) * 6272 + r0 + x] = *(unsigned short*)&v;
      }
    }
  } else {
    const int wid = id - 11760;
    const float* win; unsigned short* wout; int R, C, c0, r0;
    if (wid < 1440)      { win = Wqkv; wout = wqkvt; R = 384;  C = 3840;
                           c0 = (wid % 120) * 32; r0 = (wid / 120) * 32; }
    else if (wid < 1728) { int i = wid - 1440; win = Wq; wout = wqt; R = 384; C = 768;
                           c0 = (i % 24) * 32; r0 = (i / 24) * 32; }
    else                 { int i = wid - 1728; win = Wout; wout = woutt; R = 3072; C = 512;
                           c0 = (i % 16) * 32; r0 = (i / 16) * 32; }
    #pragma unroll
    for (int i = y; i < 32; i += 8) t[i][x] = win[(long)(r0 + i) * C + c0 + x];
    __syncthreads();
    #pragma unroll
    for (int i = y; i < 32; i += 8) {
      __hip_bfloat16 v = __float2bfloat16(t[x][i]);
      wout[(long)(c0 + i) * R + r0 + x] = *(unsigned short*)&v;
    }
  }
}

__global__ __launch_bounds__(256) void rowsum2_bf16(
    const unsigned short* __restrict__ srcA, const unsigned short* __restrict__ srcB,
    float* __restrict__ dstA, float* __restrict__ dstB) {
  const int z = blockIdx.y;
  const unsigned short* src = z ? srcB : srcA;
  float* dst = z ? dstB : dstA;
  const int ncols = z ? M2 : M1;
  const long base = (long)blockIdx.x * ncols;
  float s = 0.f;
  for (int c = threadIdx.x * 8; c < ncols; c += 2048) {
    bf16x8 v = *(const bf16x8*)(src + base + c);
    #pragma unroll
    for (int j = 0; j < 8; ++j)
      s += __uint_as_float(((unsigned)(unsigned short)v[j]) << 16);
  }
  __shared__ float red[256];
  red[threadIdx.x] = s;
  __syncthreads();
  for (int st = 128; st > 0; st >>= 1) {
    if (threadIdx.x < st) red[threadIdx.x] += red[threadIdx.x + st];
    __syncthreads();
  }
  if (threadIdx.x == 0) dst[blockIdx.x] = red[0];
}

__global__ __launch_bounds__(256) void reduce_conv2(
    const float* __restrict__ srcA, const float* __restrict__ srcB,
    unsigned short* __restrict__ dstA, unsigned short* __restrict__ dstB) {
  const int z = blockIdx.y;
  const float* src = z ? srcB : srcA;
  unsigned short* dstb = z ? dstB : dstA;
  const int nchunks = z ? CH2 : CH1;
  int i = blockIdx.x * 256 + threadIdx.x;
  float s = 0.f;
  for (int c = 0; c < nchunks; ++c) s += src[(long)c * 147456 + i];
  __hip_bfloat16 hv = __float2bfloat16(s);
  dstb[i] = *(unsigned short*)&hv;
}

// --------------------------- BN finalize (merged) --------------------------
__global__ __launch_bounds__(256) void bnfinal2(
    const float* __restrict__ W1, const float* __restrict__ T1v,
    const float* __restrict__ cs1, const float* __restrict__ s1,
    float* __restrict__ a1, float* __restrict__ b1,
    const float* __restrict__ W2, const float* __restrict__ T2v,
    const float* __restrict__ cs2, const float* __restrict__ s2,
    float* __restrict__ a2, float* __restrict__ b2) {
  const int id = blockIdx.x;
  const float *W, *T, *cs, *scale; float *a, *b; int N; float invM; int jb;
  if (id < 60) { W = W1; T = T1v; cs = cs1; scale = s1; a = a1; b = b1;
                 N = N1; invM = 1.f / (float)M1; jb = id; }
  else         { W = W2; T = T2v; cs = cs2; scale = s2; a = a2; b = b2;
                 N = Dq; invM = 1.f / (float)M2; jb = id - 60; }
  const int j = jb * 64 + (threadIdx.x & 63);
  const int rq = threadIdx.x >> 6;
  float yy = 0.f, mu = 0.f;
  for (int k = rq * 96; k < rq * 96 + 96; ++k) {
    float w = W[(long)k * N + j];
    yy += w * T[(long)k * N + j];
    mu += cs[k] * w;
  }
  __shared__ float r1[256], r2[256];
  r1[threadIdx.x] = yy; r2[threadIdx.x] = mu;
  __syncthreads();
  if (threadIdx.x < 64) {
    int t = threadIdx.x;
    yy = r1[t] + r1[t + 64] + r1[t + 128] + r1[t + 192];
    mu = r2[t] + r2[t + 64] + r2[t + 128] + r2[t + 192];
    float mean = mu * invM;
    float var = yy * invM - mean * mean;
    float ai = rsqrtf(var + 1e-5f) * scale[j];
    a[j] = ai;
    b[j] = -mean * ai;
  }
}

// ---------------------------------------------------------------------------
// split-K MFMA X @ X^T (merged z ranges)
// ---------------------------------------------------------------------------
__global__ __launch_bounds__(256) void sx_mfma2(
    const unsigned short* __restrict__ XA, const unsigned short* __restrict__ XB,
    float* __restrict__ psA, float* __restrict__ psB) {
  const unsigned short* X; float* Cp; int Kfull, Kchunk, zi;
  if ((int)blockIdx.z < CH1) { X = XA; Cp = psA; Kfull = M1; Kchunk = M1 / CH1; zi = blockIdx.z; }
  else { X = XB; Cp = psB; Kfull = M2; Kchunk = M2 / CH2; zi = blockIdx.z - CH1; }

  __shared__ __align__(16) char As[16384];
  __shared__ __align__(16) char Bs[16384];
  const int tid = threadIdx.x;
  const int lane = tid & 63;
  const int wv = tid >> 6;
  const int wm = (wv >> 1) * 64, wn = (wv & 1) * 64;
  const int m0 = blockIdx.y * 128, n0 = blockIdx.x * 128;
  const int cl = lane & 15, kg = lane >> 4;
  const int srow = tid >> 3;
  const int swz = ((tid & 7) * 16) ^ ((srow & 7) << 4);
  const int ldsb = wv * 1024;
  const long zbase = (long)zi * Kchunk;

  long arow[4], brow[4];
  #pragma unroll
  for (int is = 0; is < 4; ++is) {
    arow[is] = (long)(m0 + is * 32 + srow) * Kfull + zbase;
    brow[is] = (long)(n0 + is * 32 + srow) * Kfull + zbase;
  }

  f32x4 acc[4][4];
  const f32x4 zf = {0.f, 0.f, 0.f, 0.f};
  #pragma unroll
  for (int i = 0; i < 4; ++i)
    #pragma unroll
    for (int j = 0; j < 4; ++j) acc[i][j] = zf;

  for (int k0 = 0; k0 < Kchunk; k0 += 64) {
    #pragma unroll
    for (int is = 0; is < 4; ++is) {
      gload_lds16((const char*)X + (arow[is] + k0) * 2 + swz, As + is * 4096 + ldsb);
      gload_lds16((const char*)X + (brow[is] + k0) * 2 + swz, Bs + is * 4096 + ldsb);
    }
    __syncthreads();
    bf16x8 afr[4][2], bfr[4][2];
    #pragma unroll
    for (int t = 0; t < 4; ++t) {
      const int ar = wm + t * 16 + cl;
      const int br = wn + t * 16 + cl;
      const int sa = (ar & 7) << 4, sb = (br & 7) << 4;
      afr[t][0] = *(const bf16x8*)(As + ar * 128 + ((kg * 16) ^ sa));
      afr[t][1] = *(const bf16x8*)(As + ar * 128 + ((64 + kg * 16) ^ sa));
      bfr[t][0] = *(const bf16x8*)(Bs + br * 128 + ((kg * 16) ^ sb));
      bfr[t][1] = *(const bf16x8*)(Bs + br * 128 + ((64 + kg * 16) ^ sb));
    }
    #pragma unroll
    for (int mt = 0; mt < 4; ++mt)
      #pragma unroll
      for (int nt = 0; nt < 4; ++nt) {
        acc[mt][nt] = mfma16(bfr[nt][0], afr[mt][0], acc[mt][nt]);
        acc[mt][nt] = mfma16(bfr[nt][1], afr[mt][1], acc[mt][nt]);
      }
    __syncthreads();
  }

  float* Cpz = Cp + (long)zi * 384 * 384;
  #pragma unroll
  for (int mt = 0; mt < 4; ++mt) {
    const int gm = m0 + wm + mt * 16 + cl;
    #pragma unroll
    for (int nt = 0; nt < 4; ++nt) {
      const int gn = n0 + wn + nt * 16 + kg * 4;
      *(float4*)(Cpz + (long)gm * 384 + gn) =
          make_float4(acc[mt][nt][0], acc[mt][nt][1], acc[mt][nt][2], acc[mt][nt][3]);
    }
  }
}

// ---------------------------------------------------------------------------
// Shared MFMA GEMM body: C = A[M,K] @ Bt[N,K]^T at tile (m0, n0).
// ---------------------------------------------------------------------------
template<int AMODE, int EPI>
__device__ __forceinline__ void gemm_body(
    char* smem, const unsigned short* __restrict__ A,
    const unsigned short* __restrict__ Bt, void* __restrict__ Cout,
    const float* __restrict__ ea, const float* __restrict__ eb,
    int N, int K, int m0, int n0) {
  char* As = smem;
  char* Bs = smem + 16384;
  const int tid = threadIdx.x;
  const int lane = tid & 63;
  const int wv = tid >> 6;
  const int wm = (wv >> 1) * 64, wn = (wv & 1) * 64;
  const int cl = lane & 15, kg = lane >> 4;

  const int srow = tid >> 3;
  const int swz = ((tid & 7) * 16) ^ ((srow & 7) << 4);
  const int ldsb = wv * 1024;

  long arow[4], brow[4];
  #pragma unroll
  for (int is = 0; is < 4; ++is) {
    int gm = m0 + is * 32 + srow;
    long grow;
    if constexpr (AMODE == 1) {
      int bb = gm / 196, t = gm - bb * 196;
      int h2 = t / 14, w2 = t - h2 * 14;
      grow = (long)(bb * 784 + h2 * 56 + w2 * 2);
    } else {
      grow = gm;
    }
    arow[is] = grow * (long)K;
    brow[is] = (long)(n0 + is * 32 + srow) * (long)K;
  }

  f32x4 acc[4][4];
  const f32x4 zf = {0.f, 0.f, 0.f, 0.f};
  #pragma unroll
  for (int i = 0; i < 4; ++i)
    #pragma unroll
    for (int j = 0; j < 4; ++j) acc[i][j] = zf;

  for (int k0 = 0; k0 < K; k0 += 64) {
    #pragma unroll
    for (int is = 0; is < 4; ++is) {
      gload_lds16((const char*)A  + (arow[is] + k0) * 2 + swz, As + is * 4096 + ldsb);
      gload_lds16((const char*)Bt + (brow[is] + k0) * 2 + swz, Bs + is * 4096 + ldsb);
    }
    __syncthreads();
    bf16x8 afr[4][2], bfr[4][2];
    #pragma unroll
    for (int t = 0; t < 4; ++t) {
      const int ar = wm + t * 16 + cl;
      const int br = wn + t * 16 + cl;
      const int sa = (ar & 7) << 4, sb = (br & 7) << 4;
      afr[t][0] = *(const bf16x8*)(As + ar * 128 + ((kg * 16) ^ sa));
      afr[t][1] = *(const bf16x8*)(As + ar * 128 + ((64 + kg * 16) ^ sa));
      bfr[t][0] = *(const bf16x8*)(Bs + br * 128 + ((kg * 16) ^ sb));
      bfr[t][1] = *(const bf16x8*)(Bs + br * 128 + ((64 + kg * 16) ^ sb));
    }
    #pragma unroll
    for (int mt = 0; mt < 4; ++mt)
      #pragma unroll
      for (int nt = 0; nt < 4; ++nt) {
        if constexpr (EPI == 2) {
          acc[mt][nt] = mfma16(afr[mt][0], bfr[nt][0], acc[mt][nt]);
          acc[mt][nt] = mfma16(afr[mt][1], bfr[nt][1], acc[mt][nt]);
        } else {
          acc[mt][nt] = mfma16(bfr[nt][0], afr[mt][0], acc[mt][nt]);
          acc[mt][nt] = mfma16(bfr[nt][1], afr[mt][1], acc[mt][nt]);
        }
      }
    __syncthreads();
  }

  if constexpr (EPI == 2) {
    char* Cs = smem;
    #pragma unroll
    for (int mt = 0; mt < 4; ++mt) {
      const int kl = wm + mt * 16 + kg * 4;
      #pragma unroll
      for (int nt = 0; nt < 4; ++nt) {
        const int dvl = wn + nt * 16 + cl;
        const int gn = n0 + dvl;
        const float av = ea[gn], bv = eb[gn];
        union { ushort4 u; __hip_bfloat16 h[4]; } pk;
        pk.h[0] = __float2bfloat16(acc[mt][nt][0] * av + bv);
        pk.h[1] = __float2bfloat16(acc[mt][nt][1] * av + bv);
        pk.h[2] = __float2bfloat16(acc[mt][nt][2] * av + bv);
        pk.h[3] = __float2bfloat16(acc[mt][nt][3] * av + bv);
        *(ushort4*)(Cs + dvl * 272 + kl * 2) = pk.u;
      }
    }
    __syncthreads();
    const int hh = n0 >> 8;
    #pragma unroll
    for (int l = 0; l < 8; ++l) {
      const int row = l * 16 + (tid >> 4);
      const int seg = tid & 15;
      const int gm = m0 + seg * 8;
      const int bb = gm / 784, kk = gm - bb * 784;
      const int dvl = (n0 + row) & 255;
      uint4 v = *(const uint4*)(Cs + row * 272 + seg * 16);
      *(uint4*)((unsigned short*)Cout + ((long)(bb * 12 + hh) * 256 + dvl) * 784 + kk) = v;
    }
  } else {
    #pragma unroll
    for (int mt = 0; mt < 4; ++mt) {
      #pragma unroll
      for (int nt = 0; nt < 4; ++nt) {
        const int gm = m0 + wm + mt * 16 + cl;
        const int gn = n0 + wn + nt * 16 + kg * 4;
        if constexpr (EPI == 1) {
          float4 a4 = *(const float4*)(ea + gn);
          float4 b4 = *(const float4*)(eb + gn);
          union { ushort4 u; __hip_bfloat16 h[4]; } pk;
          pk.h[0] = __float2bfloat16(acc[mt][nt][0] * a4.x + b4.x);
          pk.h[1] = __float2bfloat16(acc[mt][nt][1] * a4.y + b4.y);
          pk.h[2] = __float2bfloat16(acc[mt][nt][2] * a4.z + b4.z);
          pk.h[3] = __float2bfloat16(acc[mt][nt][3] * a4.w + b4.w);
          *(ushort4*)((unsigned short*)Cout + (long)gm * N + gn) = pk.u;
        } else {
          *(float4*)((float*)Cout + (long)gm * N + gn) =
              make_float4(acc[mt][nt][0], acc[mt][nt][1], acc[mt][nt][2], acc[mt][nt][3]);
        }
      }
    }
  }
}

__global__ __launch_bounds__(256) void bngemm2(
    const unsigned short* __restrict__ sxb1, const unsigned short* __restrict__ wqkvt,
    float* __restrict__ t1, const unsigned short* __restrict__ sxb2,
    const unsigned short* __restrict__ wqt, float* __restrict__ t2) {
  __shared__ __align__(16) char smem[32768];
  const int id = blockIdx.x;
  if (id < 90) {
    gemm_body<0, 0>(smem, sxb1, wqkvt, t1, nullptr, nullptr, N1, Kc,
                    (id / 30) * 128, (id % 30) * 128);
  } else {
    const int i = id - 90;
    gemm_body<0, 0>(smem, sxb2, wqt, t2, nullptr, nullptr, Dq, Kc,
                    (i / 6) * 128, (i % 6) * 128);
  }
}

__global__ __launch_bounds__(256) void outgemm(
    const unsigned short* __restrict__ Ob, const unsigned short* __restrict__ woutt,
    float* __restrict__ out) {
  __shared__ __align__(16) char smem[32768];
  gemm_body<0, 0>(smem, Ob, woutt, out, nullptr, nullptr, OUTD, 4 * Dq,
                  blockIdx.y * 128, blockIdx.x * 128);
}

__global__ __launch_bounds__(256) void proj_merged(
    const unsigned short* __restrict__ xb, const unsigned short* __restrict__ wqkvt,
    const unsigned short* __restrict__ wqt, unsigned short* __restrict__ kb,
    unsigned short* __restrict__ vtb, unsigned short* __restrict__ qnb,
    const float* __restrict__ a1w, const float* __restrict__ b1w,
    const float* __restrict__ a2w, const float* __restrict__ b2w) {
  __shared__ __align__(16) char smem[34816];
  const int id = blockIdx.x;
  if (id < 4704) {
    const int nl = (id & 7) * 588 + (id >> 3);
    gemm_body<0, 2>(smem, xb, wqkvt + (long)768 * Kc, vtb, a1w + 768, b1w + 768,
                    3072, Kc, (nl / 24) * 128, (nl % 24) * 128);
  } else if (id < 5880) {
    const int i = id - 4704;
    const int nl = (i & 7) * 147 + (i >> 3);
    gemm_body<0, 1>(smem, xb, wqkvt, kb, a1w, b1w, 768, Kc,
                    (nl / 6) * 128, (nl % 6) * 128);
  } else {
    const int i = id - 5880;
    gemm_body<1, 1>(smem, xb, wqt, qnb, a2w, b2w, Dq, Kc,
                    (i / 6) * 128, (i % 6) * 128);
  }
}

// ---------------------------------------------------------------------------
// Single-pass MFMA flash attention (round-14, unchanged).
// ---------------------------------------------------------------------------
#define RAW_BAR() { \
    asm volatile("s_waitcnt lgkmcnt(0)" ::: "memory"); \
    __builtin_amdgcn_sched_barrier(0); \
    __builtin_amdgcn_s_barrier(); \
    __builtin_amdgcn_sched_barrier(0); }

#define LOAD_VF(KT, V0, V1, V2, V3) { \
    const int kvo_ = (KT) * 64 + kb; \
    V0 = *(const bf16x8*)(vt + vr0 + kvo_); \
    V1 = *(const bf16x8*)(vt + vr0 + kvo_ + 32); \
    V2 = *(const bf16x8*)(vt + vr1 + kvo_); \
    V3 = *(const bf16x8*)(vt + vr1 + kvo_ + 32); }

#define ATTN_STEP(KT, CUR, VC0, VC1, VC2, VC3, VN0, VN1, VN2, VN3) { \
    const int k0_ = (KT) * 64; \
    const int key0_ = k0_ + snt * 16 + kg * 4; \
    const int rowl0_ = mt0 * 16 + cl; \
    const int rowl1_ = (mt0 + 2) * 16 + cl; \
    const bool ok0_ = (mt0 < nmt) && (rowl0_ < valid) && (key0_ < 784); \
    const bool ok1_ = (mt0 + 2 < nmt) && (rowl1_ < valid) && (key0_ < 784); \
    const long boff0_ = ok0_ ? ((long)(qbase + rowl0_) * 784 + key0_) : 0; \
    const long boff1_ = ok1_ ? ((long)(qbase + rowl1_) * 784 + key0_) : 0; \
    float4 b40_ = *(const float4*)(bias + boff0_); \
    float4 b41_ = *(const float4*)(bias + boff1_); \
    gload_lds16((const char*)kbuf + kbase + (long)(k0_ + 64) * 1536, \
                Kl[(CUR) ^ 1] + w * 1024); \
    LOAD_VF((KT) + 1, VN0, VN1, VN2, VN3); \
    asm volatile("s_waitcnt vmcnt(11)" ::: "memory"); \
    __builtin_amdgcn_sched_barrier(0); \
    const char* kr_ = Kl[CUR] + krow * 128; \
    bf16x8 kk0_ = *(const bf16x8*)(kr_ + ((kg * 16) ^ ksw)); \
    bf16x8 kk1_ = *(const bf16x8*)(kr_ + ((64 + kg * 16) ^ ksw)); \
    _Pragma("unroll") \
    for (int i_ = 0; i_ < 2; ++i_) { \
      int mt_ = mt0 + 2 * i_; \
      if (mt_ >= nmt) break; \
      const bool ok_ = i_ ? ok1_ : ok0_; \
      const float4 b4_ = i_ ? b41_ : b40_; \
      bf16x8 q0_ = *(const bf16x8*)&Qs[mt_ * 16 + cl][kb]; \
      bf16x8 q1_ = *(const bf16x8*)&Qs[mt_ * 16 + cl][32 + kb]; \
      f32x4 s_ = mfma16(kk1_, q1_, mfma16(kk0_, q0_, zerof)); \
      const int rowl_ = mt_ * 16 + cl; \
      float p0_ = ok_ ? __expf(s_[0] * 0.125f + b4_.x) : 0.f; \
      float p1_ = ok_ ? __expf(s_[1] * 0.125f + b4_.y) : 0.f; \
      float p2_ = ok_ ? __expf(s_[2] * 0.125f + b4_.z) : 0.f; \
      float p3_ = ok_ ? __expf(s_[3] * 0.125f + b4_.w) : 0.f; \
      lpart[i_] += (p0_ + p1_) + (p2_ + p3_); \
      union { ushort4 u; __hip_bfloat16 hh_[4]; } pk_; \
      pk_.hh_[0] = __float2bfloat16(p0_); pk_.hh_[1] = __float2bfloat16(p1_); \
      pk_.hh_[2] = __float2bfloat16(p2_); pk_.hh_[3] = __float2bfloat16(p3_); \
      *(ushort4*)&pPs[rowl_][snt * 16 + kg * 4] = pk_.u; \
    } \
    RAW_BAR(); \
    __builtin_amdgcn_s_setprio(1); \
    _Pragma("unroll") \
    for (int mt_ = 0; mt_ < 4; ++mt_) { \
      if (mt_ >= nmt) break; \
      bf16x8 pa0_ = *(const bf16x8*)&pPs[mt_ * 16 + cl][kb]; \
      bf16x8 pa1_ = *(const bf16x8*)&pPs[mt_ * 16 + cl][32 + kb]; \
      acc[mt_][0] = mfma16(pa0_, VC0, acc[mt_][0]); \
      acc[mt_][0] = mfma16(pa1_, VC1, acc[mt_][0]); \
      acc[mt_][1] = mfma16(pa0_, VC2, acc[mt_][1]); \
      acc[mt_][1] = mfma16(pa1_, VC3, acc[mt_][1]); \
    } \
    __builtin_amdgcn_s_setprio(0); \
    RAW_BAR(); }

__global__ __launch_bounds__(512, 4) void attn_mfma(
    const unsigned short* __restrict__ kbuf, const unsigned short* __restrict__ vt,
    const unsigned short* __restrict__ qn, const float* __restrict__ bias,
    unsigned short* __restrict__ O) {
  const int p = blockIdx.x + 4 * (blockIdx.y + 12 * blockIdx.z);
  const int wrk = ((p & 7) * 192) + (p >> 3);
  const int qt = wrk & 3;
  const int hb = wrk >> 2;
  const int h = hb % 12, b = hb / 12;

  const int tid = threadIdx.x;
  const int w = tid >> 6;
  const int lane = tid & 63;
  const int cl = lane & 15;
  const int kg = lane >> 4;
  const int kb = kg * 8;
  const int qbase = qt * 64;
  const int valid = (196 - qbase) > 64 ? 64 : (196 - qbase);
  const int nmt = (valid + 15) >> 4;
  const int bh = b * 12 + h;

  __shared__ __align__(16) short Qs[64][72];
  __shared__ __align__(16) char Kl[2][8192];
  __shared__ __align__(16) short pPs[64][72];
  __shared__ float pred[4][64];
  __shared__ float lsum[64];

  const bf16x8 zero8 = {0,0,0,0,0,0,0,0};
  const f32x4 zerof = {0.f,0.f,0.f,0.f};

  const int srow = tid >> 3;
  const int ssw = ((tid & 7) * 16) ^ ((srow & 7) << 4);
  const long kbase = ((long)(b * 784 + srow) * 768 + h * 64) * 2 + ssw;

  {
    int row = tid >> 3, d8 = tid & 7;
    bf16x8 v = zero8;
    if (row < valid)
      v = *(const bf16x8*)(qn + (long)(b * 196 + qbase + row) * 768 + h * 64 + d8 * 8);
    *(bf16x8*)&Qs[row][d8 * 8] = v;
  }
  gload_lds16((const char*)kbuf + kbase, Kl[0] + w * 1024);

  const int mt0 = w >> 2, snt = w & 3;
  const long vr0 = ((long)bh * 256 + w * 32 + cl) * 784;
  const long vr1 = vr0 + (long)16 * 784;

  bf16x8 vA0, vA1, vA2, vA3;
  bf16x8 vB0 = zero8, vB1 = zero8, vB2 = zero8, vB3 = zero8;
  LOAD_VF(0, vA0, vA1, vA2, vA3);
  __syncthreads();

  f32x4 acc[4][2];
  #pragma unroll
  for (int mt = 0; mt < 4; ++mt) { acc[mt][0] = zerof; acc[mt][1] = zerof; }
  float lpart[2] = {0.f, 0.f};

  const int krow = snt * 16 + cl;
  const int ksw = (krow & 7) << 4;

  for (int kt2 = 0; kt2 < 13; kt2 += 2) {
    ATTN_STEP(kt2, 0, vA0, vA1, vA2, vA3, vB0, vB1, vB2, vB3);
    if (kt2 + 1 < 13) {
      ATTN_STEP(kt2 + 1, 1, vB0, vB1, vB2, vB3, vA0, vA1, vA2, vA3);
    }
  }

  #pragma unroll
  for (int i = 0; i < 2; ++i) {
    int mt = mt0 + 2 * i;
    if (mt >= nmt) break;
    float v = lpart[i];
    v += __shfl_xor(v, 16);
    v += __shfl_xor(v, 32);
    if (kg == 0) pred[snt][mt * 16 + cl] = v;
  }
  __syncthreads();
  if (tid < 64 && tid < ((nmt * 16 < 64) ? nmt * 16 : 64))
    lsum[tid] = (pred[0][tid] + pred[1][tid]) + (pred[2][tid] + pred[3][tid]);
  else if (tid < 64)
    lsum[tid] = 1.f;
  __syncthreads();

  #pragma unroll
  for (int mt = 0; mt < 4; ++mt) {
    #pragma unroll
    for (int r = 0; r < 4; ++r) {
      const int rl = mt * 16 + kg * 4 + r;
      if (rl < valid) {
        const float inv = 1.0f / lsum[rl];
        #pragma unroll
        for (int nt2 = 0; nt2 < 2; ++nt2) {
          float ov = hswish(acc[mt][nt2][r] * inv);
          __hip_bfloat16 hv = __float2bfloat16(ov);
          O[(long)(b * 196 + qbase + rl) * 3072 + h * 256 + w * 32 + nt2 * 16 + cl] =
              *(unsigned short*)&hv;
        }
      }
    }
  }
}

// ---------------------------------------------------------------------------
extern "C" void kernel_launch(void* const* d_in, const int* in_sizes, int n_in,
                              void* d_out, int out_size, void* d_ws, size_t ws_size,
                              hipStream_t stream) {
  if (ws_size < WS_TOTAL) return;

  const float* x    = (const float*)d_in[0];
  const float* Wqkv = (const float*)d_in[1];
  const float* bn1s = (const float*)d_in[2];
  const float* Wq   = (const float*)d_in[3];
  const float* bn2s = (const float*)d_in[4];
  const float* bias = (const float*)d_in[5];
  const float* Wout = (const float*)d_in[6];

  char* ws = (char*)d_ws;
  unsigned short* kb   = (unsigned short*)(ws + OFF_K);
  unsigned short* xbT  = (unsigned short*)(ws + OFF_XBT);
  unsigned short* xqT  = (unsigned short*)(ws + OFF_XQT);
  float* t1            = (float*)(ws + OFF_T1);
  float* t2            = (float*)(ws + OFF_T2);
  unsigned short* sxb1 = (unsigned short*)(ws + OFF_SXB1);
  unsigned short* sxb2 = (unsigned short*)(ws + OFF_SXB2);
  unsigned short* vtb  = (unsigned short*)(ws + OFF_VT);
  unsigned short* qnb  = (unsigned short*)(ws + OFF_QN);
  unsigned short* xb   = (unsigned short*)(ws + OFF_XB);
  unsigned short* Ob   = (unsigned short*)(ws + OFF_O);
  unsigned short* wqkvt= (unsigned short*)(ws + OFF_WQKVT);
  unsigned short* wqt  = (unsigned short*)(ws + OFF_WQT);
  unsigned short* woutt= (unsigned short*)(ws + OFF_WOUTT);
  float* ps1  = (float*)(ws + OFF_PS1);     // aliases VT region (dead window)
  float* ps2  = (float*)(ws + OFF_PS2);
  float* cs1  = (float*)(ws + OFF_CS1);
  float* cs2  = (float*)(ws + OFF_CS2);
  float* a1w  = (float*)(ws + OFF_A1);
  float* b1w  = (float*)(ws + OFF_B1);
  float* a2w  = (float*)(ws + OFF_A2);
  float* b2w  = (float*)(ws + OFF_B2);
  float* out  = (float*)d_out;

  // 1. all prep transposes (x + weights) in one launch
  prep_all<<<dim3(15024), 256, 0, stream>>>(x, xb, xbT, xqT,
                                            Wqkv, Wq, Wout, wqkvt, wqt, woutt);
  // 2. colsums
  rowsum2_bf16<<<dim3(384, 2), 256, 0, stream>>>(xbT, xqT, cs1, cs2);
  // 3. Sx split-K MFMA (ps1 in VT dead window) ; 4. reduce+convert
  sx_mfma2<<<dim3(3, 3, CH1 + CH2), 256, 0, stream>>>(xbT, xqT, ps1, ps2);
  reduce_conv2<<<dim3(576, 2), 256, 0, stream>>>(ps1, ps2, sxb1, sxb2);
  // 5. BN T-gemms ; 6. finalize
  bngemm2<<<dim3(108), 256, 0, stream>>>(sxb1, wqkvt, t1, sxb2, wqt, t2);
  bnfinal2<<<dim3(72), 256, 0, stream>>>(Wqkv, t1, cs1, bn1s, a1w, b1w,
                                         Wq,   t2, cs2, bn2s, a2w, b2w);
  // 7. projections (merged V+K+Q; vtb overwrites dead ps1)
  proj_merged<<<dim3(6174), 256, 0, stream>>>(xb, wqkvt, wqt, kb, vtb, qnb,
                                              a1w, b1w, a2w, b2w);
  // 8. attention -> hswish(O)
  attn_mfma<<<dim3(4, 12, 32), 512, 0, stream>>>(kb, vtb, qnb, bias, Ob);
  // 9. out = O @ Wout^T
  outgemm<<<dim3(4, 49), 256, 0, stream>>>(Ob, woutt, out);
}